// Round 12
// baseline (1561.049 us; speedup 1.0000x reference)
//
#include <hip/hip_runtime.h>
#include <hip/hip_bf16.h>

typedef float f32x4 __attribute__((ext_vector_type(4)));
typedef __bf16 bf16x8 __attribute__((ext_vector_type(8)));

#define AS1 __attribute__((address_space(1)))
#define AS3 __attribute__((address_space(3)))

__device__ __forceinline__ void gload16(const void* g, void* l) {
    __builtin_amdgcn_global_load_lds((AS1 unsigned int*)g, (AS3 unsigned int*)l, 16, 0, 0);
}

__device__ __forceinline__ float bfu(unsigned short u) {
    return __uint_as_float((unsigned)u << 16);
}

// ---------------- weight prep: conv2/conv3 OIHW f32 -> [kyx][icg][nblk][oc128][ic32] bf16;
// block 1024 transposes c1w [256][81] -> c1wT [81][256] ----------------
__global__ __launch_bounds__(256) void prep_w_kernel(const float* __restrict__ wA,
                                                     const float* __restrict__ wB,
                                                     __hip_bfloat16* __restrict__ wpA,
                                                     __hip_bfloat16* __restrict__ wpB,
                                                     const float* __restrict__ c1w,
                                                     float* __restrict__ c1wT) {
    int bid = blockIdx.x;
    int t = threadIdx.x;
    if (bid == 1024) {
        float tmp[81];
#pragma unroll
        for (int k = 0; k < 81; ++k) tmp[k] = c1w[t * 81 + k];
#pragma unroll
        for (int k = 0; k < 81; ++k) c1wT[k * 256 + t] = tmp[k];
        return;
    }
    __shared__ float wl[4 * 32 * 81];  // [o][i][kyx]
    const float* w = (bid < 512) ? wA : wB;
    __hip_bfloat16* wp = (bid < 512) ? wpA : wpB;
    bid &= 511;
    int icg = bid & 7;
    int oc4 = (bid >> 3) & 31;
    int nblk = bid >> 8;
    int ocg0 = nblk * 128 + oc4 * 4;
    int ic0 = icg * 32;
    for (int f = t; f < 4 * 2592; f += 256) {
        int o = f / 2592;
        int rest = f - o * 2592;  // i*81 + kyx
        wl[f] = w[(ocg0 + o) * 20736 + ic0 * 81 + rest];
    }
    __syncthreads();
    for (int idx = t; idx < 81 * 128; idx += 256) {
        int kyx = idx >> 7;
        int o = (idx >> 5) & 3;
        int i = idx & 31;
        long dst = (long)(((kyx * 8 + icg) * 2 + nblk) * 128 + (oc4 * 4 + o)) * 32 + i;
        wp[dst] = __float2bfloat16(wl[o * 2592 + i * 81 + kyx]);
    }
}

// ---------------- conv1: 1->256ch 9x9 s1, f32 compute, coalesced weight preload ----------------
__global__ __launch_bounds__(256) void conv1_kernel(const float* __restrict__ x,
                                                    const float* __restrict__ wT,
                                                    const float* __restrict__ bias,
                                                    __hip_bfloat16* __restrict__ out) {
    __shared__ float rowb[504];  // 9 rows x 56
    int oy = blockIdx.x;  // 0..47
    int b = blockIdx.y;   // 0..127
    int t = threadIdx.x;  // = oc
    const float* src = x + b * 3136 + oy * 56;
    for (int i = t; i < 504; i += 256) rowb[i] = src[i];
    float w81[81];
#pragma unroll
    for (int k = 0; k < 81; ++k) w81[k] = wT[k * 256 + t];
    __syncthreads();
    float bs = bias[t];
    __hip_bfloat16* op = out + ((b * 48 + oy) * 48) * 256 + t;
    for (int p = 0; p < 3; ++p) {
        int ox0 = p * 16;
        float acc[16];
#pragma unroll
        for (int i = 0; i < 16; ++i) acc[i] = 0.f;
#pragma unroll
        for (int ky = 0; ky < 9; ++ky) {
            float r[24];
#pragma unroll
            for (int i = 0; i < 24; ++i) r[i] = rowb[ky * 56 + ox0 + i];
#pragma unroll
            for (int kx = 0; kx < 9; ++kx) {
                float wv = w81[ky * 9 + kx];
#pragma unroll
                for (int ox = 0; ox < 16; ++ox) acc[ox] = fmaf(wv, r[ox + kx], acc[ox]);
            }
        }
#pragma unroll
        for (int ox = 0; ox < 16; ++ox) {
            float v = acc[ox] + bs;
            v = v > 0.f ? v : 0.f;
            op[(ox0 + ox) * 256] = __float2bfloat16(v);
        }
    }
}

// ---------------- conv2 K-quarter: 2 icg per launch. mode bit0: add partial-in; bit1: bias+relu ----------------
__global__ __launch_bounds__(512, 2) void conv2_img_kernel(const __hip_bfloat16* __restrict__ in,
                                                           const __hip_bfloat16* __restrict__ wp,
                                                           const float* __restrict__ bias,
                                                           const __hip_bfloat16* __restrict__ pin,
                                                           __hip_bfloat16* __restrict__ pout,
                                                           int icgStart, int mode) {
    __shared__ __hip_bfloat16 Ald[73728];   // 147456 B = [48][48][32] swizzled
    int bid = blockIdx.x;
    int wg = (bid & 7) * 32 + (bid >> 3);   // XCD-chunk: nblk pair lands on same XCD
    int b = wg >> 1, nblk = wg & 1;
    int t = threadIdx.x;
    int lane = t & 63, wid = t >> 6;
    int wr = wid >> 1, wc = wid & 1;        // 4 (M) x 2 (N) wave grid
    int ch8 = lane >> 4;

    const __hip_bfloat16* imgbase = in + (long)b * (48 * 48 * 256);
    const __hip_bfloat16* wpn = wp + (long)nblk * 4096 + (wc * 64 + (lane & 15)) * 32 + ch8 * 8;

    int qbase[7];
#pragma unroll
    for (int mi = 0; mi < 7; ++mi) {
        int ml = wr * 96 + mi * 16 + (lane & 15);
        int oy = ml / 20, ox = ml - oy * 20;
        qbase[mi] = ((2 * oy) * 48 + 2 * ox) * 4 + ch8;
    }

    f32x4 acc[7][4];
#pragma unroll
    for (int i = 0; i < 7; ++i)
#pragma unroll
        for (int j = 0; j < 4; ++j) acc[i][j] = (f32x4){0.f, 0.f, 0.f, 0.f};

    auto stageA = [&](int icg) {
#pragma unroll
        for (int c = 0; c < 3; ++c) {
            uint4 v[6];
#pragma unroll
            for (int j = 0; j < 6; ++j) {
                int gi = t + (c * 6 + j) * 512;
                int lrow = gi >> 2;
                int iy = lrow / 48;
                int col = lrow - iy * 48;
                if (iy > 46) iy = 46;  // row 47 pad, never read
                v[j] = *(const uint4*)(imgbase + (iy * 48 + col) * 256 + icg * 32 + (gi & 3) * 8);
            }
#pragma unroll
            for (int j = 0; j < 6; ++j) {
                int gi = t + (c * 6 + j) * 512;
                int phys = gi ^ ((gi >> 3) & 7);
                *(uint4*)((char*)Ald + phys * 16) = v[j];
            }
        }
    };

    bf16x8 af_e[7], af_o[7], Be[4], Bo[4];
    int pf_kdelta = 0, pf_kx = 0, pf_ky = 0;
    auto prefA = [&](bf16x8* af) {
#pragma unroll
        for (int mi = 0; mi < 7; ++mi) {
            int q = qbase[mi] + pf_kdelta;
            int phys = q ^ ((q >> 3) & 7);
            af[mi] = *(const bf16x8*)((const char*)Ald + phys * 16);
        }
        ++pf_kx; pf_kdelta += 4;
        if (pf_kx == 9) { pf_kx = 0; ++pf_ky; pf_kdelta = pf_ky * 192; }
    };
    auto domfma = [&](bf16x8* af, bf16x8* bf) {
        __builtin_amdgcn_s_setprio(1);
#pragma unroll
        for (int mi = 0; mi < 7; ++mi)
#pragma unroll
            for (int ni = 0; ni < 4; ++ni)
                acc[mi][ni] = __builtin_amdgcn_mfma_f32_16x16x32_bf16(af[mi], bf[ni], acc[mi][ni], 0, 0, 0);
        __builtin_amdgcn_s_setprio(0);
    };

    for (int icg = icgStart; icg < icgStart + 2; ++icg) {
        const __hip_bfloat16* wpi = wpn + (long)icg * 8192;
        auto loadB = [&](bf16x8* dst, int kyx) {
            const __hip_bfloat16* p = wpi + (long)kyx * 65536;
#pragma unroll
            for (int ni = 0; ni < 4; ++ni) dst[ni] = *(const bf16x8*)(p + ni * 512);
        };
        if (icg != icgStart) __builtin_amdgcn_s_barrier();  // all waves done reading old A
        loadB(Be, 0);
        loadB(Bo, 1);
        stageA(icg);
        asm volatile("s_waitcnt lgkmcnt(0)" ::: "memory");
        __builtin_amdgcn_s_barrier();
        if (wid >= 4) asm volatile("s_sleep 4");   // de-phase co-resident waves

        pf_kx = 0; pf_ky = 0; pf_kdelta = 0;
        prefA(af_e);                                // step 0 fragments
        for (int it2 = 0; it2 < 40; ++it2) {
            prefA(af_o);
            domfma(af_e, Be);
            loadB(Be, 2 * it2 + 2);
            prefA(af_e);
            domfma(af_o, Bo);
            loadB(Bo, 2 * it2 + 3);   // kyx 81,82 read harmless garbage past tile (never used)
        }
        domfma(af_e, Be);                           // step 80
    }

    // epilogue: optional partial-in add, optional bias+relu, bf16 store
    int colbase = nblk * 128 + wc * 64 + (lane & 15);
#pragma unroll
    for (int mi = 0; mi < 7; ++mi) {
#pragma unroll
        for (int ni = 0; ni < 4; ++ni) {
            int col = colbase + ni * 16;
            float bs = (mode & 2) ? bias[col] : 0.f;
#pragma unroll
            for (int r = 0; r < 4; ++r) {
                int ml = wr * 96 + mi * 16 + (lane >> 4) * 4 + r;
                long oidx = ((long)b * 400 + ml) * 256 + col;
                float v = acc[mi][ni][r];
                if (mode & 1) v += __bfloat162float(pin[oidx]);
                if (mode & 2) { v += bs; v = v > 0.f ? v : 0.f; }
                pout[oidx] = __float2bfloat16(v);
            }
        }
    }
}

// ---------------- conv3: implicit-GEMM 128x128 (split-K), ring-3, counted vmcnt, bf16 partials ----------------
__global__ __launch_bounds__(256) void conv_mfma_kernel(const __hip_bfloat16* __restrict__ in,
                                                        const __hip_bfloat16* __restrict__ wp,
                                                        const float* __restrict__ bias,
                                                        __hip_bfloat16* __restrict__ out,
                                                        __hip_bfloat16* __restrict__ part,
                                                        int Win, int imgStride, int HWout, int Wout,
                                                        int nkyx, int Mtot, int mode) {
    __shared__ __hip_bfloat16 Ald[3 * 4096];
    __shared__ __hip_bfloat16 Bld[3 * 4096];
    int mblk = blockIdx.x, nblk = blockIdx.y;
    int kyx0 = blockIdx.z * nkyx;
    int t = threadIdx.x;
    int lane = t & 63, wid = t >> 6;
    int swz = ((t & 3) ^ ((t >> 3) & 3)) * 8;
    int icsrc = swz;
    long bsrc = (t >> 2) * 32 + swz;

    long base0, base1;
    {
        int m = mblk * 128 + (t >> 2);
        int b = m / HWout; int rem = m - b * HWout;
        int oyy = rem / Wout; int oxx = rem - oyy * Wout;
        base0 = (long)b * imgStride + (long)(2 * oyy * Win + 2 * oxx) * 256;
        m += 64;
        b = m / HWout; rem = m - b * HWout;
        oyy = rem / Wout; oxx = rem - oyy * Wout;
        base1 = (long)b * imgStride + (long)(2 * oyy * Win + 2 * oxx) * 256;
    }

    f32x4 acc[4][4];
#pragma unroll
    for (int i = 0; i < 4; ++i)
#pragma unroll
        for (int j2 = 0; j2 < 4; ++j2) acc[i][j2] = (f32x4){0.f, 0.f, 0.f, 0.f};

    int wr = wid >> 1, wc = wid & 1;
    int slot8 = (((lane >> 4) ^ ((lane >> 1) & 3))) * 8;
    int a_off = ((wr * 64 + (lane & 15)) * 32 + slot8) * 2;
    int b_off = ((wc * 64 + (lane & 15)) * 32 + slot8) * 2;

    auto stage = [&](int s, int buf) {
        int kyx = kyx0 + (s >> 3);
        int icg = s & 7;
        int ky = kyx / 9, kx = kyx - ky * 9;
        long offA = (long)(ky * Win + kx) * 256 + icg * 32 + icsrc;
        long btb = (long)((kyx * 8 + icg) * 2 + nblk) * 4096 + bsrc;
        char* a0 = (char*)Ald + buf * 8192 + wid * 1024;
        char* b0 = (char*)Bld + buf * 8192 + wid * 1024;
        gload16(in + base0 + offA, a0);
        gload16(in + base1 + offA, a0 + 4096);
        gload16(wp + btb, b0);
        gload16(wp + btb + 2048, b0 + 4096);
    };

    int nsteps = nkyx * 8;
    stage(0, 0);
    stage(1, 1);
    stage(2, 2);
    int cur = 0;
    for (int s = 0; s < nsteps; ++s) {
        int rem = nsteps - 1 - s;
        if (rem >= 2) {
            asm volatile("s_waitcnt vmcnt(8)" ::: "memory");
        } else if (rem == 1) {
            asm volatile("s_waitcnt vmcnt(4)" ::: "memory");
        } else {
            asm volatile("s_waitcnt vmcnt(0)" ::: "memory");
        }
        __builtin_amdgcn_s_barrier();
        __builtin_amdgcn_sched_barrier(0);
        const char* Ac = (const char*)Ald + cur * 8192;
        const char* Bc = (const char*)Bld + cur * 8192;
        bf16x8 af[4], bfr[4];
#pragma unroll
        for (int i = 0; i < 4; ++i) af[i] = *(const bf16x8*)(Ac + a_off + i * 1024);
#pragma unroll
        for (int i = 0; i < 4; ++i) bfr[i] = *(const bf16x8*)(Bc + b_off + i * 1024);
#pragma unroll
        for (int mi = 0; mi < 4; ++mi)
#pragma unroll
            for (int ni = 0; ni < 4; ++ni)
                acc[mi][ni] = __builtin_amdgcn_mfma_f32_16x16x32_bf16(af[mi], bfr[ni], acc[mi][ni], 0, 0, 0);
        if (s + 3 < nsteps) {
            asm volatile("s_waitcnt lgkmcnt(0)" ::: "memory");
            __builtin_amdgcn_s_barrier();
            stage(s + 3, cur);
        }
        cur = (cur == 2) ? 0 : cur + 1;
    }

    int colbase = nblk * 128 + wc * 64 + (lane & 15);
    long mrowbase = (long)mblk * 128 + wr * 64 + (lane >> 4) * 4;
    if (mode == 0) {
#pragma unroll
        for (int mi = 0; mi < 4; ++mi) {
#pragma unroll
            for (int ni = 0; ni < 4; ++ni) {
                int col = colbase + ni * 16;
                float bs = bias[col];
#pragma unroll
                for (int r = 0; r < 4; ++r) {
                    long mrow = mrowbase + mi * 16 + r;
                    float v = acc[mi][ni][r] + bs;
                    v = v > 0.f ? v : 0.f;
                    out[mrow * 256 + col] = __float2bfloat16(v);
                }
            }
        }
    } else {
        __hip_bfloat16* pp = part + (long)blockIdx.z * Mtot * 256;
#pragma unroll
        for (int mi = 0; mi < 4; ++mi) {
#pragma unroll
            for (int ni = 0; ni < 4; ++ni) {
                int col = colbase + ni * 16;
#pragma unroll
                for (int r = 0; r < 4; ++r) {
                    long mrow = mrowbase + mi * 16 + r;
                    pp[mrow * 256 + col] = __float2bfloat16(acc[mi][ni][r]);
                }
            }
        }
    }
}

// ---------------- split-K reduce: sum 9 bf16 partials + bias + relu -> bf16 NHWC ----------------
__global__ __launch_bounds__(256) void reduce_parts_kernel(const __hip_bfloat16* __restrict__ part,
                                                           const float* __restrict__ bias,
                                                           __hip_bfloat16* __restrict__ out) {
    int idx = blockIdx.x * 256 + threadIdx.x;  // 4608*256
    float s = 0.f;
#pragma unroll
    for (int p = 0; p < 9; ++p) s += __bfloat162float(part[(long)p * 1179648 + idx]);
    s += bias[idx & 255];
    s = s > 0.f ? s : 0.f;
    out[idx] = __float2bfloat16(s);
}

// ---------------- primary capsule squash: NHWC bf16 -> uT f32 [1152 i][128 b][8 d] ----------------
__global__ __launch_bounds__(256) void squash_caps_kernel(const __hip_bfloat16* __restrict__ c3,
                                                          float* __restrict__ uT) {
    int g = blockIdx.x * 256 + threadIdx.x;  // 147456 = 1152*128, i-major
    int i = g >> 7, b = g & 127;
    float val[8];
    float sn = 0.f;
#pragma unroll
    for (int d = 0; d < 8; ++d) {
        int flat = i * 8 + d;
        int c = flat / 36; int rem = flat - c * 36;
        int y = rem / 6; int xx = rem - y * 6;
        float vv = __bfloat162float(c3[((b * 6 + y) * 6 + xx) * 256 + c]);
        val[d] = vv;
        sn += vv * vv;
    }
    float sc = (sn / (1.f + sn)) / sqrtf(sn + 1e-8f);
#pragma unroll
    for (int d = 0; d < 8; ++d) uT[(long)g * 8 + d] = val[d] * sc;  // contiguous 32B/thread
}

// ---------------- u_hat[b,j,i,o] = sum_d uT[i,b,d] * W[j,i,d,o]  (vectorized LDS, no div in loop) ----------------
__global__ __launch_bounds__(256) void uhat_kernel(const float* __restrict__ uT,
                                                   const float* __restrict__ Wd,
                                                   __hip_bfloat16* __restrict__ uhat) {
    __shared__ float Wl2[1600];  // [jo=160][10]: 8 d-values + 2 pad (40B stride -> conflict-free b64)
    __shared__ float ul[1024];   // [b=128][8]   (32B stride -> b128 broadcast)
    int i = blockIdx.x, t = threadIdx.x;
    for (int idx = t; idx < 1280; idx += 256) {
        int j = idx >> 7, rest = idx & 127;
        int d = rest >> 4, o = rest & 15;
        Wl2[(j * 16 + o) * 10 + d] = Wd[((long)j * 1152 + i) * 128 + rest];
    }
    {
        const float4* usrc = (const float4*)(uT + (long)i * 1024);
        float4* ud = (float4*)ul;
        ud[t] = usrc[t];  // 256 float4 = whole [128][8]
    }
    __syncthreads();
    int b = (t >= 160) ? 1 : 0;
    int jo = (t >= 160) ? t - 160 : t;
    for (int rr = 0; rr < 80; ++rr) {
        const float* up = &ul[b * 8];
        const float* wq = &Wl2[jo * 10];
        float a = 0.f;
#pragma unroll
        for (int d = 0; d < 8; ++d) a += up[d] * wq[d];
        int j = jo >> 4, o = jo & 15;
        uhat[(((long)b * 10 + j) * 1152 + i) * 16 + o] = __float2bfloat16(a);
        jo += 96; b += 1;
        if (jo >= 160) { jo -= 160; b += 1; }
    }
}

// ---------------- fused dynamic routing per (b,j): 3 iterations in LDS ----------------
__global__ __launch_bounds__(256) void routing_kernel(const __hip_bfloat16* __restrict__ uhat,
                                                      const float* __restrict__ bdig,
                                                      float* __restrict__ vout,
                                                      float* __restrict__ vws) {
    __shared__ __hip_bfloat16 uh[1152 * 16];  // 36864B
    __shared__ float barr[1152];
    __shared__ float red[16];
    __shared__ float accb[16 * 256];          // 16KB
    __shared__ float svec[16];
    __shared__ float vsc[16];
    int bid = blockIdx.x;  // b*10 + j
    int j = bid % 10;
    int t = threadIdx.x;
    int wid = t >> 6;
    const uint4* srcp = (const uint4*)(uhat + (long)bid * 18432);
    uint4* dstp = (uint4*)uh;
    for (int idx = t; idx < 2304; idx += 256) dstp[idx] = srcp[idx];
    for (int idx = t; idx < 1152; idx += 256) barr[idx] = 0.f;
    __syncthreads();
    for (int it = 0; it < 3; ++it) {
        float lm = -1e30f;
        for (int i = t; i < 1152; i += 256) lm = fmaxf(lm, barr[i]);
#pragma unroll
        for (int m2 = 32; m2; m2 >>= 1) lm = fmaxf(lm, __shfl_xor(lm, m2));
        if ((t & 63) == 0) red[wid] = lm;
        __syncthreads();
        float mx = fmaxf(fmaxf(red[0], red[1]), fmaxf(red[2], red[3]));
        float le = 0.f;
        float a16[16];
#pragma unroll
        for (int o = 0; o < 16; ++o) a16[o] = 0.f;
        for (int i = t; i < 1152; i += 256) {
            float e = __expf(barr[i] - mx);
            le += e;
            const uint4* up = (const uint4*)(uh + i * 16);
            union { uint4 q; unsigned short s[8]; } U0, U1;
            U0.q = up[0]; U1.q = up[1];
#pragma unroll
            for (int o = 0; o < 8; ++o) a16[o] += e * bfu(U0.s[o]);
#pragma unroll
            for (int o = 0; o < 8; ++o) a16[8 + o] += e * bfu(U1.s[o]);
        }
#pragma unroll
        for (int m2 = 32; m2; m2 >>= 1) le += __shfl_xor(le, m2);
        if ((t & 63) == 0) red[4 + wid] = le;
#pragma unroll
        for (int o = 0; o < 16; ++o) accb[o * 256 + t] = a16[o];
        __syncthreads();
        float sume = red[4] + red[5] + red[6] + red[7];
        int g = t >> 4, tin = t & 15;
        float s = 0.f;
#pragma unroll
        for (int k = 0; k < 16; ++k) s += accb[g * 256 + tin + 16 * k];
#pragma unroll
        for (int m2 = 8; m2; m2 >>= 1) s += __shfl_xor(s, m2);
        if (tin == 0) svec[g] = s / sume + bdig[j * 16 + g];
        __syncthreads();
        if (t < 16) {
            float sv = svec[t];
            float sn = sv * sv;
#pragma unroll
            for (int m2 = 8; m2; m2 >>= 1) sn += __shfl_xor(sn, m2);
            float sc = (sn / (1.f + sn)) / sqrtf(sn + 1e-8f);
            float v = sv * sc;
            vsc[t] = v;
            if (it == 2) { vout[bid * 16 + t] = v; vws[bid * 16 + t] = v; }
        }
        __syncthreads();
        if (it < 2) {
            for (int i = t; i < 1152; i += 256) {
                const uint4* up = (const uint4*)(uh + i * 16);
                union { uint4 q; unsigned short s[8]; } U0, U1;
                U0.q = up[0]; U1.q = up[1];
                float dot = 0.f;
#pragma unroll
                for (int o = 0; o < 8; ++o) dot += vsc[o] * bfu(U0.s[o]);
#pragma unroll
                for (int o = 0; o < 8; ++o) dot += vsc[8 + o] * bfu(U1.s[o]);
                barr[i] += dot;
            }
            __syncthreads();
        }
    }
}

// ---------------- reconstruction GEMM: out[128,N] = act(A[128,K] x W[K,N] + bias) ----------------
__global__ __launch_bounds__(256) void rec_gemm_kernel(const float* __restrict__ A,
                                                       const float* __restrict__ W,
                                                       const float* __restrict__ bias,
                                                       float* __restrict__ out,
                                                       int K, int N, int act) {
    __shared__ float As[32 * 64];
    int n0 = blockIdx.x * 64;
    int bch = blockIdx.y * 32;
    int t = threadIdx.x;
    int n_l = t & 63, bh = t >> 6;
    float acc[8];
#pragma unroll
    for (int i = 0; i < 8; ++i) acc[i] = 0.f;
    for (int k0 = 0; k0 < K; k0 += 64) {
        int kc = K - k0;
        if (kc > 64) kc = 64;
        __syncthreads();
        for (int idx = t; idx < 2048; idx += 256) {
            int bb = idx >> 6, kk = idx & 63;
            if (kk < kc) As[idx] = A[(long)(bch + bb) * K + k0 + kk];
        }
        __syncthreads();
        const float* Wp = W + (long)k0 * N + n0 + n_l;
        if (kc == 64) {
#pragma unroll 8
            for (int kk = 0; kk < 64; ++kk) {
                float wv = Wp[(long)kk * N];
#pragma unroll
                for (int bb = 0; bb < 8; ++bb) acc[bb] += As[(bh * 8 + bb) * 64 + kk] * wv;
            }
        } else {
            for (int kk = 0; kk < kc; ++kk) {
                float wv = Wp[(long)kk * N];
#pragma unroll
                for (int bb = 0; bb < 8; ++bb) acc[bb] += As[(bh * 8 + bb) * 64 + kk] * wv;
            }
        }
    }
    float bs = bias[n0 + n_l];
    for (int bb = 0; bb < 8; ++bb) {
        float x = acc[bb] + bs;
        float r;
        if (act == 0) r = x > 0.f ? x : 0.f;
        else r = 1.f / (1.f + __expf(-x));
        out[(long)(bch + bh * 8 + bb) * N + n0 + n_l] = r;
    }
}

extern "C" void kernel_launch(void* const* d_in, const int* in_sizes, int n_in,
                              void* d_out, int out_size, void* d_ws, size_t ws_size,
                              hipStream_t stream) {
    const float* x   = (const float*)d_in[0];
    const float* c1w = (const float*)d_in[1];
    const float* c1b = (const float*)d_in[2];
    const float* c2w = (const float*)d_in[3];
    const float* c2b = (const float*)d_in[4];
    const float* pw  = (const float*)d_in[5];
    const float* pb  = (const float*)d_in[6];
    const float* Wd  = (const float*)d_in[7];
    const float* bd  = (const float*)d_in[8];
    const float* rw1 = (const float*)d_in[9];
    const float* rb1 = (const float*)d_in[10];
    const float* rw2 = (const float*)d_in[11];
    const float* rb2 = (const float*)d_in[12];
    const float* rw3 = (const float*)d_in[13];
    const float* rb3 = (const float*)d_in[14];
    float* outp = (float*)d_out;

    char* ws = (char*)d_ws;
    size_t off = 0;
    auto alloc = [&](size_t bytes) {
        char* p = ws + off;
        off += (bytes + 255) & ~(size_t)255;
        return p;
    };
    __hip_bfloat16* c1out = (__hip_bfloat16*)alloc(150994944UL);  // [128][48][48][256] bf16
    __hip_bfloat16* c2out = (__hip_bfloat16*)alloc(26214400UL);   // [128][20][20][256]
    __hip_bfloat16* c3out = (__hip_bfloat16*)alloc(2359296UL);    // [128][6][6][256]
    __hip_bfloat16* w2p   = (__hip_bfloat16*)alloc(10616832UL);
    __hip_bfloat16* w3p   = (__hip_bfloat16*)alloc(10616832UL);
    float* c1wT  = (float*)alloc(82944UL);      // [81][256] f32
    float* uT    = (float*)alloc(4718592UL);    // [1152][128][8] f32
    __hip_bfloat16* uhat = (__hip_bfloat16*)alloc(47185920UL);  // [128][10][1152][16] bf16
    float* vws   = (float*)alloc(81920UL);      // [128][160]
    float* rec1  = (float*)alloc(262144UL);     // [128][512]
    float* rec2  = (float*)alloc(524288UL);     // [128][1024]

    // time-multiplexed aliases of the uhat buffer (all dead before uhat is written):
    __hip_bfloat16* c2part = (__hip_bfloat16*)uhat;  // [128*400][256] bf16 = 26.2MB
    __hip_bfloat16* c3part = (__hip_bfloat16*)uhat;  // [9][4608][256] bf16 = 21.2MB

    prep_w_kernel<<<1025, 256, 0, stream>>>(c2w, pw, w2p, w3p, c1w, c1wT);
    conv1_kernel<<<dim3(48, 128), 256, 0, stream>>>(x, c1wT, c1b, c1out);
    conv2_img_kernel<<<256, 512, 0, stream>>>(c1out, w2p, c2b, nullptr, c2part, 0, 0);
    conv2_img_kernel<<<256, 512, 0, stream>>>(c1out, w2p, c2b, c2part, c2part, 2, 1);
    conv2_img_kernel<<<256, 512, 0, stream>>>(c1out, w2p, c2b, c2part, c2part, 4, 1);
    conv2_img_kernel<<<256, 512, 0, stream>>>(c1out, w2p, c2b, c2part, c2out, 6, 3);
    conv_mfma_kernel<<<dim3(36, 2, 9), 256, 0, stream>>>(c2out, w3p, pb, c3out, c3part,
                                                         20, 20 * 20 * 256, 36, 6, 9, 4608, 1);
    reduce_parts_kernel<<<4608, 256, 0, stream>>>(c3part, pb, c3out);
    squash_caps_kernel<<<576, 256, 0, stream>>>(c3out, uT);
    uhat_kernel<<<1152, 256, 0, stream>>>(uT, Wd, uhat);
    routing_kernel<<<1280, 256, 0, stream>>>(uhat, bd, outp, vws);
    rec_gemm_kernel<<<dim3(8, 4), 256, 0, stream>>>(vws, rw1, rb1, rec1, 160, 512, 0);
    rec_gemm_kernel<<<dim3(16, 4), 256, 0, stream>>>(rec1, rw2, rb2, rec2, 512, 1024, 0);
    rec_gemm_kernel<<<dim3(49, 4), 256, 0, stream>>>(rec2, rw3, rb3, outp + 20480, 1024, 3136, 1);
}

// Round 13
// 977.538 us; speedup vs baseline: 1.5969x; 1.5969x over previous
//
#include <hip/hip_runtime.h>
#include <hip/hip_bf16.h>

typedef float f32x4 __attribute__((ext_vector_type(4)));
typedef __bf16 bf16x8 __attribute__((ext_vector_type(8)));

#define AS1 __attribute__((address_space(1)))
#define AS3 __attribute__((address_space(3)))

__device__ __forceinline__ void gload16(const void* g, void* l) {
    __builtin_amdgcn_global_load_lds((AS1 unsigned int*)g, (AS3 unsigned int*)l, 16, 0, 0);
}

__device__ __forceinline__ float bfu(unsigned short u) {
    return __uint_as_float((unsigned)u << 16);
}

// ---------------- weight prep: conv2/conv3 OIHW f32 -> [kyx][icg][nblk][oc128][ic32] bf16;
// block 1024 transposes c1w [256][81] -> c1wT [81][256] ----------------
__global__ __launch_bounds__(256) void prep_w_kernel(const float* __restrict__ wA,
                                                     const float* __restrict__ wB,
                                                     __hip_bfloat16* __restrict__ wpA,
                                                     __hip_bfloat16* __restrict__ wpB,
                                                     const float* __restrict__ c1w,
                                                     float* __restrict__ c1wT) {
    int bid = blockIdx.x;
    int t = threadIdx.x;
    if (bid == 1024) {
        float tmp[81];
#pragma unroll
        for (int k = 0; k < 81; ++k) tmp[k] = c1w[t * 81 + k];
#pragma unroll
        for (int k = 0; k < 81; ++k) c1wT[k * 256 + t] = tmp[k];
        return;
    }
    __shared__ float wl[4 * 32 * 81];  // [o][i][kyx]
    const float* w = (bid < 512) ? wA : wB;
    __hip_bfloat16* wp = (bid < 512) ? wpA : wpB;
    bid &= 511;
    int icg = bid & 7;
    int oc4 = (bid >> 3) & 31;
    int nblk = bid >> 8;
    int ocg0 = nblk * 128 + oc4 * 4;
    int ic0 = icg * 32;
    for (int f = t; f < 4 * 2592; f += 256) {
        int o = f / 2592;
        int rest = f - o * 2592;  // i*81 + kyx
        wl[f] = w[(ocg0 + o) * 20736 + ic0 * 81 + rest];
    }
    __syncthreads();
    for (int idx = t; idx < 81 * 128; idx += 256) {
        int kyx = idx >> 7;
        int o = (idx >> 5) & 3;
        int i = idx & 31;
        long dst = (long)(((kyx * 8 + icg) * 2 + nblk) * 128 + (oc4 * 4 + o)) * 32 + i;
        wp[dst] = __float2bfloat16(wl[o * 2592 + i * 81 + kyx]);
    }
}

// ---------------- conv1: 1->256ch 9x9 s1, f32 compute, coalesced weight preload ----------------
__global__ __launch_bounds__(256) void conv1_kernel(const float* __restrict__ x,
                                                    const float* __restrict__ wT,
                                                    const float* __restrict__ bias,
                                                    __hip_bfloat16* __restrict__ out) {
    __shared__ float rowb[504];  // 9 rows x 56
    int oy = blockIdx.x;  // 0..47
    int b = blockIdx.y;   // 0..127
    int t = threadIdx.x;  // = oc
    const float* src = x + b * 3136 + oy * 56;
    for (int i = t; i < 504; i += 256) rowb[i] = src[i];
    float w81[81];
#pragma unroll
    for (int k = 0; k < 81; ++k) w81[k] = wT[k * 256 + t];
    __syncthreads();
    float bs = bias[t];
    __hip_bfloat16* op = out + ((b * 48 + oy) * 48) * 256 + t;
    for (int p = 0; p < 3; ++p) {
        int ox0 = p * 16;
        float acc[16];
#pragma unroll
        for (int i = 0; i < 16; ++i) acc[i] = 0.f;
#pragma unroll
        for (int ky = 0; ky < 9; ++ky) {
            float r[24];
#pragma unroll
            for (int i = 0; i < 24; ++i) r[i] = rowb[ky * 56 + ox0 + i];
#pragma unroll
            for (int kx = 0; kx < 9; ++kx) {
                float wv = w81[ky * 9 + kx];
#pragma unroll
                for (int ox = 0; ox < 16; ++ox) acc[ox] = fmaf(wv, r[ox + kx], acc[ox]);
            }
        }
#pragma unroll
        for (int ox = 0; ox < 16; ++ox) {
            float v = acc[ox] + bs;
            v = v > 0.f ? v : 0.f;
            op[(ox0 + ox) * 256] = __float2bfloat16(v);
        }
    }
}

// ---------------- conv2: one image/block, LDS-resident im2col slice, barrier-free K-loop,
// register-double-buffered A-fragments, B double-buffer, s_sleep wave skew ----------------
__global__ __launch_bounds__(512, 2) void conv2_img_kernel(const __hip_bfloat16* __restrict__ in,
                                                           const __hip_bfloat16* __restrict__ wp,
                                                           const float* __restrict__ bias,
                                                           __hip_bfloat16* __restrict__ out) {
    __shared__ __hip_bfloat16 Ald[73728];   // 147456 B = [48][48][32] swizzled
    int bid = blockIdx.x;
    int wg = (bid & 7) * 32 + (bid >> 3);   // XCD-chunk: nblk pair lands on same XCD
    int b = wg >> 1, nblk = wg & 1;
    int t = threadIdx.x;
    int lane = t & 63, wid = t >> 6;
    int wr = wid >> 1, wc = wid & 1;        // 4 (M) x 2 (N) wave grid
    int ch8 = lane >> 4;

    const __hip_bfloat16* imgbase = in + (long)b * (48 * 48 * 256);
    const __hip_bfloat16* wpn = wp + (long)nblk * 4096 + (wc * 64 + (lane & 15)) * 32 + ch8 * 8;

    int qbase[7];
#pragma unroll
    for (int mi = 0; mi < 7; ++mi) {
        int ml = wr * 96 + mi * 16 + (lane & 15);
        int oy = ml / 20, ox = ml - oy * 20;
        qbase[mi] = ((2 * oy) * 48 + 2 * ox) * 4 + ch8;
    }

    f32x4 acc[7][4];
#pragma unroll
    for (int i = 0; i < 7; ++i)
#pragma unroll
        for (int j = 0; j < 4; ++j) acc[i][j] = (f32x4){0.f, 0.f, 0.f, 0.f};

    auto stageA = [&](int icg) {
#pragma unroll
        for (int c = 0; c < 3; ++c) {
            uint4 v[6];
#pragma unroll
            for (int j = 0; j < 6; ++j) {
                int gi = t + (c * 6 + j) * 512;
                int lrow = gi >> 2;
                int iy = lrow / 48;
                int col = lrow - iy * 48;
                if (iy > 46) iy = 46;  // row 47 pad, never read
                v[j] = *(const uint4*)(imgbase + (iy * 48 + col) * 256 + icg * 32 + (gi & 3) * 8);
            }
#pragma unroll
            for (int j = 0; j < 6; ++j) {
                int gi = t + (c * 6 + j) * 512;
                int phys = gi ^ ((gi >> 3) & 7);
                *(uint4*)((char*)Ald + phys * 16) = v[j];
            }
        }
    };

    bf16x8 af_e[7], af_o[7], Be[4], Bo[4];
    int pf_kdelta = 0, pf_kx = 0, pf_ky = 0;
    auto prefA = [&](bf16x8* af) {
#pragma unroll
        for (int mi = 0; mi < 7; ++mi) {
            int q = qbase[mi] + pf_kdelta;
            int phys = q ^ ((q >> 3) & 7);
            af[mi] = *(const bf16x8*)((const char*)Ald + phys * 16);
        }
        ++pf_kx; pf_kdelta += 4;
        if (pf_kx == 9) { pf_kx = 0; ++pf_ky; pf_kdelta = pf_ky * 192; }
    };
    auto domfma = [&](bf16x8* af, bf16x8* bf) {
        __builtin_amdgcn_s_setprio(1);
#pragma unroll
        for (int mi = 0; mi < 7; ++mi)
#pragma unroll
            for (int ni = 0; ni < 4; ++ni)
                acc[mi][ni] = __builtin_amdgcn_mfma_f32_16x16x32_bf16(af[mi], bf[ni], acc[mi][ni], 0, 0, 0);
        __builtin_amdgcn_s_setprio(0);
    };

    for (int icg = 0; icg < 8; ++icg) {
        const __hip_bfloat16* wpi = wpn + (long)icg * 8192;
        auto loadB = [&](bf16x8* dst, int kyx) {
            const __hip_bfloat16* p = wpi + (long)kyx * 65536;
#pragma unroll
            for (int ni = 0; ni < 4; ++ni) dst[ni] = *(const bf16x8*)(p + ni * 512);
        };
        if (icg) __builtin_amdgcn_s_barrier();   // all waves done reading old A
        loadB(Be, 0);
        loadB(Bo, 1);
        stageA(icg);
        asm volatile("s_waitcnt lgkmcnt(0)" ::: "memory");
        __builtin_amdgcn_s_barrier();
        if (wid >= 4) asm volatile("s_sleep 4");   // de-phase co-resident waves

        pf_kx = 0; pf_ky = 0; pf_kdelta = 0;
        prefA(af_e);                                // step 0 fragments
        for (int it2 = 0; it2 < 40; ++it2) {
            prefA(af_o);
            domfma(af_e, Be);
            loadB(Be, 2 * it2 + 2);
            prefA(af_e);
            domfma(af_o, Bo);
            loadB(Bo, 2 * it2 + 3);   // kyx 81,82 read harmless garbage past tile (never used)
        }
        domfma(af_e, Be);                           // step 80
    }

    int colbase = nblk * 128 + wc * 64 + (lane & 15);
#pragma unroll
    for (int mi = 0; mi < 7; ++mi) {
#pragma unroll
        for (int ni = 0; ni < 4; ++ni) {
            int col = colbase + ni * 16;
            float bs = bias[col];
#pragma unroll
            for (int r = 0; r < 4; ++r) {
                int ml = wr * 96 + mi * 16 + (lane >> 4) * 4 + r;
                float v = acc[mi][ni][r] + bs;
                v = v > 0.f ? v : 0.f;
                out[((long)b * 400 + ml) * 256 + col] = __float2bfloat16(v);
            }
        }
    }
}

// ---------------- conv3: implicit-GEMM 128x128 (split-K), ring-3, counted vmcnt, bf16 partials ----------------
__global__ __launch_bounds__(256) void conv_mfma_kernel(const __hip_bfloat16* __restrict__ in,
                                                        const __hip_bfloat16* __restrict__ wp,
                                                        const float* __restrict__ bias,
                                                        __hip_bfloat16* __restrict__ out,
                                                        __hip_bfloat16* __restrict__ part,
                                                        int Win, int imgStride, int HWout, int Wout,
                                                        int nkyx, int Mtot, int mode) {
    __shared__ __hip_bfloat16 Ald[3 * 4096];
    __shared__ __hip_bfloat16 Bld[3 * 4096];
    int mblk = blockIdx.x, nblk = blockIdx.y;
    int kyx0 = blockIdx.z * nkyx;
    int t = threadIdx.x;
    int lane = t & 63, wid = t >> 6;
    int swz = ((t & 3) ^ ((t >> 3) & 3)) * 8;
    int icsrc = swz;
    long bsrc = (t >> 2) * 32 + swz;

    long base0, base1;
    {
        int m = mblk * 128 + (t >> 2);
        int b = m / HWout; int rem = m - b * HWout;
        int oyy = rem / Wout; int oxx = rem - oyy * Wout;
        base0 = (long)b * imgStride + (long)(2 * oyy * Win + 2 * oxx) * 256;
        m += 64;
        b = m / HWout; rem = m - b * HWout;
        oyy = rem / Wout; oxx = rem - oyy * Wout;
        base1 = (long)b * imgStride + (long)(2 * oyy * Win + 2 * oxx) * 256;
    }

    f32x4 acc[4][4];
#pragma unroll
    for (int i = 0; i < 4; ++i)
#pragma unroll
        for (int j2 = 0; j2 < 4; ++j2) acc[i][j2] = (f32x4){0.f, 0.f, 0.f, 0.f};

    int wr = wid >> 1, wc = wid & 1;
    int slot8 = (((lane >> 4) ^ ((lane >> 1) & 3))) * 8;
    int a_off = ((wr * 64 + (lane & 15)) * 32 + slot8) * 2;
    int b_off = ((wc * 64 + (lane & 15)) * 32 + slot8) * 2;

    auto stage = [&](int s, int buf) {
        int kyx = kyx0 + (s >> 3);
        int icg = s & 7;
        int ky = kyx / 9, kx = kyx - ky * 9;
        long offA = (long)(ky * Win + kx) * 256 + icg * 32 + icsrc;
        long btb = (long)((kyx * 8 + icg) * 2 + nblk) * 4096 + bsrc;
        char* a0 = (char*)Ald + buf * 8192 + wid * 1024;
        char* b0 = (char*)Bld + buf * 8192 + wid * 1024;
        gload16(in + base0 + offA, a0);
        gload16(in + base1 + offA, a0 + 4096);
        gload16(wp + btb, b0);
        gload16(wp + btb + 2048, b0 + 4096);
    };

    int nsteps = nkyx * 8;
    stage(0, 0);
    stage(1, 1);
    stage(2, 2);
    int cur = 0;
    for (int s = 0; s < nsteps; ++s) {
        int rem = nsteps - 1 - s;
        if (rem >= 2) {
            asm volatile("s_waitcnt vmcnt(8)" ::: "memory");
        } else if (rem == 1) {
            asm volatile("s_waitcnt vmcnt(4)" ::: "memory");
        } else {
            asm volatile("s_waitcnt vmcnt(0)" ::: "memory");
        }
        __builtin_amdgcn_s_barrier();
        __builtin_amdgcn_sched_barrier(0);
        const char* Ac = (const char*)Ald + cur * 8192;
        const char* Bc = (const char*)Bld + cur * 8192;
        bf16x8 af[4], bfr[4];
#pragma unroll
        for (int i = 0; i < 4; ++i) af[i] = *(const bf16x8*)(Ac + a_off + i * 1024);
#pragma unroll
        for (int i = 0; i < 4; ++i) bfr[i] = *(const bf16x8*)(Bc + b_off + i * 1024);
#pragma unroll
        for (int mi = 0; mi < 4; ++mi)
#pragma unroll
            for (int ni = 0; ni < 4; ++ni)
                acc[mi][ni] = __builtin_amdgcn_mfma_f32_16x16x32_bf16(af[mi], bfr[ni], acc[mi][ni], 0, 0, 0);
        if (s + 3 < nsteps) {
            asm volatile("s_waitcnt lgkmcnt(0)" ::: "memory");
            __builtin_amdgcn_s_barrier();
            stage(s + 3, cur);
        }
        cur = (cur == 2) ? 0 : cur + 1;
    }

    int colbase = nblk * 128 + wc * 64 + (lane & 15);
    long mrowbase = (long)mblk * 128 + wr * 64 + (lane >> 4) * 4;
    if (mode == 0) {
#pragma unroll
        for (int mi = 0; mi < 4; ++mi) {
#pragma unroll
            for (int ni = 0; ni < 4; ++ni) {
                int col = colbase + ni * 16;
                float bs = bias[col];
#pragma unroll
                for (int r = 0; r < 4; ++r) {
                    long mrow = mrowbase + mi * 16 + r;
                    float v = acc[mi][ni][r] + bs;
                    v = v > 0.f ? v : 0.f;
                    out[mrow * 256 + col] = __float2bfloat16(v);
                }
            }
        }
    } else {
        __hip_bfloat16* pp = part + (long)blockIdx.z * Mtot * 256;
#pragma unroll
        for (int mi = 0; mi < 4; ++mi) {
#pragma unroll
            for (int ni = 0; ni < 4; ++ni) {
                int col = colbase + ni * 16;
#pragma unroll
                for (int r = 0; r < 4; ++r) {
                    long mrow = mrowbase + mi * 16 + r;
                    pp[mrow * 256 + col] = __float2bfloat16(acc[mi][ni][r]);
                }
            }
        }
    }
}

// ---------------- split-K reduce: sum 9 bf16 partials + bias + relu -> bf16 NHWC ----------------
__global__ __launch_bounds__(256) void reduce_parts_kernel(const __hip_bfloat16* __restrict__ part,
                                                           const float* __restrict__ bias,
                                                           __hip_bfloat16* __restrict__ out) {
    int idx = blockIdx.x * 256 + threadIdx.x;  // 4608*256
    float s = 0.f;
#pragma unroll
    for (int p = 0; p < 9; ++p) s += __bfloat162float(part[(long)p * 1179648 + idx]);
    s += bias[idx & 255];
    s = s > 0.f ? s : 0.f;
    out[idx] = __float2bfloat16(s);
}

// ---------------- primary capsule squash: NHWC bf16 -> uT f32 [1152 i][128 b][8 d] ----------------
__global__ __launch_bounds__(256) void squash_caps_kernel(const __hip_bfloat16* __restrict__ c3,
                                                          float* __restrict__ uT) {
    int g = blockIdx.x * 256 + threadIdx.x;  // 147456 = 1152*128, i-major
    int i = g >> 7, b = g & 127;
    float val[8];
    float sn = 0.f;
#pragma unroll
    for (int d = 0; d < 8; ++d) {
        int flat = i * 8 + d;
        int c = flat / 36; int rem = flat - c * 36;
        int y = rem / 6; int xx = rem - y * 6;
        float vv = __bfloat162float(c3[((b * 6 + y) * 6 + xx) * 256 + c]);
        val[d] = vv;
        sn += vv * vv;
    }
    float sc = (sn / (1.f + sn)) / sqrtf(sn + 1e-8f);
#pragma unroll
    for (int d = 0; d < 8; ++d) uT[(long)g * 8 + d] = val[d] * sc;  // contiguous 32B/thread
}

// ---------------- u_hat[b,j,i,o] = sum_d uT[i,b,d] * W[j,i,d,o]  (vectorized LDS, no div in loop) ----------------
__global__ __launch_bounds__(256) void uhat_kernel(const float* __restrict__ uT,
                                                   const float* __restrict__ Wd,
                                                   __hip_bfloat16* __restrict__ uhat) {
    __shared__ float Wl2[1600];  // [jo=160][10]: 8 d-values + 2 pad (40B stride -> conflict-free b64)
    __shared__ float ul[1024];   // [b=128][8]   (32B stride -> b128 broadcast)
    int i = blockIdx.x, t = threadIdx.x;
    for (int idx = t; idx < 1280; idx += 256) {
        int j = idx >> 7, rest = idx & 127;
        int d = rest >> 4, o = rest & 15;
        Wl2[(j * 16 + o) * 10 + d] = Wd[((long)j * 1152 + i) * 128 + rest];
    }
    {
        const float4* usrc = (const float4*)(uT + (long)i * 1024);
        float4* ud = (float4*)ul;
        ud[t] = usrc[t];  // 256 float4 = whole [128][8]
    }
    __syncthreads();
    int b = (t >= 160) ? 1 : 0;
    int jo = (t >= 160) ? t - 160 : t;
    for (int rr = 0; rr < 80; ++rr) {
        const float* up = &ul[b * 8];
        const float* wq = &Wl2[jo * 10];
        float a = 0.f;
#pragma unroll
        for (int d = 0; d < 8; ++d) a += up[d] * wq[d];
        int j = jo >> 4, o = jo & 15;
        uhat[(((long)b * 10 + j) * 1152 + i) * 16 + o] = __float2bfloat16(a);
        jo += 96; b += 1;
        if (jo >= 160) { jo -= 160; b += 1; }
    }
}

// ---------------- fused dynamic routing per (b,j): 3 iterations in LDS ----------------
__global__ __launch_bounds__(256) void routing_kernel(const __hip_bfloat16* __restrict__ uhat,
                                                      const float* __restrict__ bdig,
                                                      float* __restrict__ vout,
                                                      float* __restrict__ vws) {
    __shared__ __hip_bfloat16 uh[1152 * 16];  // 36864B
    __shared__ float barr[1152];
    __shared__ float red[16];
    __shared__ float accb[16 * 256];          // 16KB
    __shared__ float svec[16];
    __shared__ float vsc[16];
    int bid = blockIdx.x;  // b*10 + j
    int j = bid % 10;
    int t = threadIdx.x;
    int wid = t >> 6;
    const uint4* srcp = (const uint4*)(uhat + (long)bid * 18432);
    uint4* dstp = (uint4*)uh;
    for (int idx = t; idx < 2304; idx += 256) dstp[idx] = srcp[idx];
    for (int idx = t; idx < 1152; idx += 256) barr[idx] = 0.f;
    __syncthreads();
    for (int it = 0; it < 3; ++it) {
        float lm = -1e30f;
        for (int i = t; i < 1152; i += 256) lm = fmaxf(lm, barr[i]);
#pragma unroll
        for (int m2 = 32; m2; m2 >>= 1) lm = fmaxf(lm, __shfl_xor(lm, m2));
        if ((t & 63) == 0) red[wid] = lm;
        __syncthreads();
        float mx = fmaxf(fmaxf(red[0], red[1]), fmaxf(red[2], red[3]));
        float le = 0.f;
        float a16[16];
#pragma unroll
        for (int o = 0; o < 16; ++o) a16[o] = 0.f;
        for (int i = t; i < 1152; i += 256) {
            float e = __expf(barr[i] - mx);
            le += e;
            const uint4* up = (const uint4*)(uh + i * 16);
            union { uint4 q; unsigned short s[8]; } U0, U1;
            U0.q = up[0]; U1.q = up[1];
#pragma unroll
            for (int o = 0; o < 8; ++o) a16[o] += e * bfu(U0.s[o]);
#pragma unroll
            for (int o = 0; o < 8; ++o) a16[8 + o] += e * bfu(U1.s[o]);
        }
#pragma unroll
        for (int m2 = 32; m2; m2 >>= 1) le += __shfl_xor(le, m2);
        if ((t & 63) == 0) red[4 + wid] = le;
#pragma unroll
        for (int o = 0; o < 16; ++o) accb[o * 256 + t] = a16[o];
        __syncthreads();
        float sume = red[4] + red[5] + red[6] + red[7];
        int g = t >> 4, tin = t & 15;
        float s = 0.f;
#pragma unroll
        for (int k = 0; k < 16; ++k) s += accb[g * 256 + tin + 16 * k];
#pragma unroll
        for (int m2 = 8; m2; m2 >>= 1) s += __shfl_xor(s, m2);
        if (tin == 0) svec[g] = s / sume + bdig[j * 16 + g];
        __syncthreads();
        if (t < 16) {
            float sv = svec[t];
            float sn = sv * sv;
#pragma unroll
            for (int m2 = 8; m2; m2 >>= 1) sn += __shfl_xor(sn, m2);
            float sc = (sn / (1.f + sn)) / sqrtf(sn + 1e-8f);
            float v = sv * sc;
            vsc[t] = v;
            if (it == 2) { vout[bid * 16 + t] = v; vws[bid * 16 + t] = v; }
        }
        __syncthreads();
        if (it < 2) {
            for (int i = t; i < 1152; i += 256) {
                const uint4* up = (const uint4*)(uh + i * 16);
                union { uint4 q; unsigned short s[8]; } U0, U1;
                U0.q = up[0]; U1.q = up[1];
                float dot = 0.f;
#pragma unroll
                for (int o = 0; o < 8; ++o) dot += vsc[o] * bfu(U0.s[o]);
#pragma unroll
                for (int o = 0; o < 8; ++o) dot += vsc[8 + o] * bfu(U1.s[o]);
                barr[i] += dot;
            }
            __syncthreads();
        }
    }
}

// ---------------- reconstruction GEMM, latency-proof: W tile preloaded to regs 1 tile ahead,
// A double-buffered in LDS with float4 broadcast reads ----------------
__global__ __launch_bounds__(256) void rec_gemm_kernel(const float* __restrict__ A,
                                                       const float* __restrict__ W,
                                                       const float* __restrict__ bias,
                                                       float* __restrict__ out,
                                                       int K, int N, int act) {
    __shared__ __align__(16) float As[2][2048];  // 2 x [32 rows][64 k]
    int n0 = blockIdx.x * 64;
    int bch = blockIdx.y * 32;
    int t = threadIdx.x;
    int n_l = t & 63, bh = t >> 6;
    const float* Wc = W + n0 + n_l;
    float acc[8];
#pragma unroll
    for (int i = 0; i < 8; ++i) acc[i] = 0.f;
    int T = (K + 63) >> 6;

    auto stageA = [&](int tile, int buf) {
        int k0 = tile << 6;
        for (int idx = t; idx < 2048; idx += 256) {
            int bb = idx >> 6, kk = idx & 63;
            As[buf][idx] = (k0 + kk < K) ? A[(long)(bch + bb) * K + k0 + kk] : 0.f;
        }
    };
    auto ldW = [&](int tile, float* w) {
        int k0 = tile << 6;
#pragma unroll
        for (int j = 0; j < 64; ++j) {
            int kr = k0 + j;
            if (kr >= K) kr = K - 1;          // clamped row x zero-padded A = harmless
            w[j] = Wc[(long)kr * N];
        }
    };
    auto compute = [&](const float* w, int buf) {
#pragma unroll
        for (int bb = 0; bb < 8; ++bb) {
            const float4* ap = (const float4*)&As[buf][(bh * 8 + bb) * 64];
            float s = 0.f;
#pragma unroll
            for (int q = 0; q < 16; ++q) {
                float4 a = ap[q];
                s += a.x * w[q * 4] + a.y * w[q * 4 + 1] + a.z * w[q * 4 + 2] + a.w * w[q * 4 + 3];
            }
            acc[bb] += s;
        }
    };

    float wA[64], wB[64];
    ldW(0, wA);
    stageA(0, 0);
    __syncthreads();
    for (int tile = 0; tile < T; tile += 2) {
        if (tile + 1 < T) { ldW(tile + 1, wB); stageA(tile + 1, 1); }
        compute(wA, 0);
        __syncthreads();
        if (tile + 1 < T) {
            if (tile + 2 < T) { ldW(tile + 2, wA); stageA(tile + 2, 0); }
            compute(wB, 1);
            __syncthreads();
        }
    }

    float bs = bias[n0 + n_l];
#pragma unroll
    for (int bb = 0; bb < 8; ++bb) {
        float x = acc[bb] + bs;
        float r;
        if (act == 0) r = x > 0.f ? x : 0.f;
        else r = 1.f / (1.f + __expf(-x));
        out[(long)(bch + bh * 8 + bb) * N + n0 + n_l] = r;
    }
}

extern "C" void kernel_launch(void* const* d_in, const int* in_sizes, int n_in,
                              void* d_out, int out_size, void* d_ws, size_t ws_size,
                              hipStream_t stream) {
    const float* x   = (const float*)d_in[0];
    const float* c1w = (const float*)d_in[1];
    const float* c1b = (const float*)d_in[2];
    const float* c2w = (const float*)d_in[3];
    const float* c2b = (const float*)d_in[4];
    const float* pw  = (const float*)d_in[5];
    const float* pb  = (const float*)d_in[6];
    const float* Wd  = (const float*)d_in[7];
    const float* bd  = (const float*)d_in[8];
    const float* rw1 = (const float*)d_in[9];
    const float* rb1 = (const float*)d_in[10];
    const float* rw2 = (const float*)d_in[11];
    const float* rb2 = (const float*)d_in[12];
    const float* rw3 = (const float*)d_in[13];
    const float* rb3 = (const float*)d_in[14];
    float* outp = (float*)d_out;

    char* ws = (char*)d_ws;
    size_t off = 0;
    auto alloc = [&](size_t bytes) {
        char* p = ws + off;
        off += (bytes + 255) & ~(size_t)255;
        return p;
    };
    __hip_bfloat16* c1out = (__hip_bfloat16*)alloc(150994944UL);  // [128][48][48][256] bf16
    __hip_bfloat16* c2out = (__hip_bfloat16*)alloc(26214400UL);   // [128][20][20][256]
    __hip_bfloat16* c3out = (__hip_bfloat16*)alloc(2359296UL);    // [128][6][6][256]
    __hip_bfloat16* w2p   = (__hip_bfloat16*)alloc(10616832UL);
    __hip_bfloat16* w3p   = (__hip_bfloat16*)alloc(10616832UL);
    float* c1wT  = (float*)alloc(82944UL);      // [81][256] f32
    float* uT    = (float*)alloc(4718592UL);    // [1152][128][8] f32
    __hip_bfloat16* uhat = (__hip_bfloat16*)alloc(47185920UL);  // [128][10][1152][16] bf16
    float* vws   = (float*)alloc(81920UL);      // [128][160]
    float* rec1  = (float*)alloc(262144UL);     // [128][512]
    float* rec2  = (float*)alloc(524288UL);     // [128][1024]

    // conv3 split-K bf16 partials [9][4608][256] alias the (later-written) uhat buffer
    __hip_bfloat16* c3part = (__hip_bfloat16*)uhat;

    prep_w_kernel<<<1025, 256, 0, stream>>>(c2w, pw, w2p, w3p, c1w, c1wT);
    conv1_kernel<<<dim3(48, 128), 256, 0, stream>>>(x, c1wT, c1b, c1out);
    conv2_img_kernel<<<256, 512, 0, stream>>>(c1out, w2p, c2b, c2out);
    conv_mfma_kernel<<<dim3(36, 2, 9), 256, 0, stream>>>(c2out, w3p, pb, c3out, c3part,
                                                         20, 20 * 20 * 256, 36, 6, 9, 4608, 1);
    reduce_parts_kernel<<<4608, 256, 0, stream>>>(c3part, pb, c3out);
    squash_caps_kernel<<<576, 256, 0, stream>>>(c3out, uT);
    uhat_kernel<<<1152, 256, 0, stream>>>(uT, Wd, uhat);
    routing_kernel<<<1280, 256, 0, stream>>>(uhat, bd, outp, vws);
    rec_gemm_kernel<<<dim3(8, 4), 256, 0, stream>>>(vws, rw1, rb1, rec1, 160, 512, 0);
    rec_gemm_kernel<<<dim3(16, 4), 256, 0, stream>>>(rec1, rw2, rb2, rec2, 512, 1024, 0);
    rec_gemm_kernel<<<dim3(49, 4), 256, 0, stream>>>(rec2, rw3, rb3, outp + 20480, 1024, 3136, 1);
}

// Round 15
// 807.129 us; speedup vs baseline: 1.9341x; 1.2111x over previous
//
#include <hip/hip_runtime.h>
#include <hip/hip_bf16.h>

typedef float f32x4 __attribute__((ext_vector_type(4)));
typedef __bf16 bf16x8 __attribute__((ext_vector_type(8)));
typedef __bf16 bf16x4 __attribute__((ext_vector_type(4)));

#define AS1 __attribute__((address_space(1)))
#define AS3 __attribute__((address_space(3)))

__device__ __forceinline__ void gload16(const void* g, void* l) {
    __builtin_amdgcn_global_load_lds((AS1 unsigned int*)g, (AS3 unsigned int*)l, 16, 0, 0);
}

__device__ __forceinline__ float bfu(unsigned short u) {
    return __uint_as_float((unsigned)u << 16);
}

// ---------------- weight prep: conv2/conv3 OIHW f32 -> [kyx][icg][nblk][oc128][ic32] bf16;
// block 1024: conv1 W -> wb[12 kslots][256 oc][8] bf16 (zero-padded); blocks 1025+: x f32 -> bf16 ----------------
__global__ __launch_bounds__(256) void prep_w_kernel(const float* __restrict__ wA,
                                                     const float* __restrict__ wB,
                                                     __hip_bfloat16* __restrict__ wpA,
                                                     __hip_bfloat16* __restrict__ wpB,
                                                     const float* __restrict__ c1w,
                                                     __hip_bfloat16* __restrict__ wb,
                                                     const float* __restrict__ x,
                                                     __hip_bfloat16* __restrict__ xb) {
    int bid = blockIdx.x;
    int t = threadIdx.x;
    if (bid == 1024) {  // conv1 weight table: kslot 0-8: (ky=ks, kx=e); 9: (ky=e, kx=8); 10: e0=(8,8); 11: zero
        float tmp[81];
#pragma unroll
        for (int k = 0; k < 81; ++k) tmp[k] = c1w[t * 81 + k];
#pragma unroll
        for (int ks = 0; ks < 9; ++ks)
#pragma unroll
            for (int e = 0; e < 8; ++e)
                wb[(ks * 256 + t) * 8 + e] = __float2bfloat16(tmp[ks * 9 + e]);
#pragma unroll
        for (int e = 0; e < 8; ++e)
            wb[(9 * 256 + t) * 8 + e] = __float2bfloat16(tmp[e * 9 + 8]);
        wb[(10 * 256 + t) * 8 + 0] = __float2bfloat16(tmp[80]);
#pragma unroll
        for (int e = 1; e < 8; ++e) wb[(10 * 256 + t) * 8 + e] = __float2bfloat16(0.f);
#pragma unroll
        for (int e = 0; e < 8; ++e) wb[(11 * 256 + t) * 8 + e] = __float2bfloat16(0.f);
        return;
    }
    if (bid >= 1025) {  // x -> bf16 (392 blocks x 1024 elems = 401408 exact)
        long i4 = (long)(bid - 1025) * 1024 + t * 4;
        float4 v = *(const float4*)(x + i4);
        bf16x4 o = {(__bf16)v.x, (__bf16)v.y, (__bf16)v.z, (__bf16)v.w};
        *(bf16x4*)((__bf16*)xb + i4) = o;
        return;
    }
    __shared__ float wl[4 * 32 * 81];  // [o][i][kyx]
    const float* w = (bid < 512) ? wA : wB;
    __hip_bfloat16* wp = (bid < 512) ? wpA : wpB;
    bid &= 511;
    int icg = bid & 7;
    int oc4 = (bid >> 3) & 31;
    int nblk = bid >> 8;
    int ocg0 = nblk * 128 + oc4 * 4;
    int ic0 = icg * 32;
    for (int f = t; f < 4 * 2592; f += 256) {
        int o = f / 2592;
        int rest = f - o * 2592;  // i*81 + kyx
        wl[f] = w[(ocg0 + o) * 20736 + ic0 * 81 + rest];
    }
    __syncthreads();
    for (int idx = t; idx < 81 * 128; idx += 256) {
        int kyx = idx >> 7;
        int o = (idx >> 5) & 3;
        int i = idx & 31;
        long dst = (long)(((kyx * 8 + icg) * 2 + nblk) * 128 + (oc4 * 4 + o)) * 32 + i;
        wp[dst] = __float2bfloat16(wl[o * 2592 + i * 81 + kyx]);
    }
}

// ---------------- conv1 as bf16 MFMA implicit-GEMM: 96 rows (2 oy) x 256 oc per block ----------------
// K = 96 (3 steps of 32), k = kslot*8+e per the wb table. B-zeros make unused A slots harmless.
__global__ __launch_bounds__(256) void conv1_mfma_kernel(const __hip_bfloat16* __restrict__ xb,
                                                         const __hip_bfloat16* __restrict__ wb,
                                                         const float* __restrict__ bias,
                                                         __hip_bfloat16* __restrict__ out) {
    __shared__ __bf16 Asl[640];  // [10 rows][64 cols]
    int bid = blockIdx.x;
    int b = bid / 24, mb2 = bid - b * 24;
    int oy0 = mb2 * 2;
    int t = threadIdx.x;
    int lane = t & 63, wc = t >> 6;
    int q = lane >> 4;

    const __bf16* src = (const __bf16*)xb + b * 3136 + oy0 * 56;
    for (int idx = t; idx < 640; idx += 256) {
        int iy = idx >> 6, col = idx & 63;
        Asl[idx] = (col < 56) ? src[iy * 56 + col] : (__bf16)0.f;
    }

    bf16x8 Bf[3][4];
#pragma unroll
    for (int s = 0; s < 3; ++s)
#pragma unroll
        for (int ni = 0; ni < 4; ++ni) {
            int col = wc * 64 + ni * 16 + (lane & 15);
            Bf[s][ni] = *(const bf16x8*)(wb + ((s * 4 + q) * 256 + col) * 8);
        }

    f32x4 acc[6][4];
#pragma unroll
    for (int i = 0; i < 6; ++i)
#pragma unroll
        for (int j = 0; j < 4; ++j) acc[i][j] = (f32x4){0.f, 0.f, 0.f, 0.f};

    __syncthreads();

#pragma unroll
    for (int s = 0; s < 3; ++s) {
        int ks = s * 4 + q;
        bf16x8 af[6];
#pragma unroll
        for (int mi = 0; mi < 6; ++mi) {
            int r = mi * 16 + (lane & 15);
            int oyl = (r >= 48) ? 1 : 0;
            int ox = r - 48 * oyl;
            bf16x8 v;
            if (ks < 9) {
                __builtin_memcpy(&v, &Asl[(oyl + ks) * 64 + ox], 16);
            } else if (ks == 9) {
#pragma unroll
                for (int e = 0; e < 8; ++e) v[e] = Asl[(oyl + e) * 64 + ox + 8];
            } else if (ks == 10) {
#pragma unroll
                for (int e = 0; e < 8; ++e) v[e] = (__bf16)0.f;
                v[0] = Asl[(oyl + 8) * 64 + ox + 8];
            } else {
#pragma unroll
                for (int e = 0; e < 8; ++e) v[e] = (__bf16)0.f;
            }
            af[mi] = v;
        }
#pragma unroll
        for (int mi = 0; mi < 6; ++mi)
#pragma unroll
            for (int ni = 0; ni < 4; ++ni)
                acc[mi][ni] = __builtin_amdgcn_mfma_f32_16x16x32_bf16(af[mi], Bf[s][ni], acc[mi][ni], 0, 0, 0);
    }

    long m0 = (long)b * 2304 + mb2 * 96;
#pragma unroll
    for (int mi = 0; mi < 6; ++mi)
#pragma unroll
        for (int ni = 0; ni < 4; ++ni) {
            int col = wc * 64 + ni * 16 + (lane & 15);
            float bs = bias[col];
#pragma unroll
            for (int r2 = 0; r2 < 4; ++r2) {
                int row = mi * 16 + q * 4 + r2;
                float vv = acc[mi][ni][r2] + bs;
                vv = vv > 0.f ? vv : 0.f;
                out[(m0 + row) * 256 + col] = __float2bfloat16(vv);
            }
        }
}

// ---------------- conv2: one image/block, LDS-resident im2col slice (row stride 49 cols -> de-aliased
// banks), barrier-free K-loop, reg-double-buffered A-frags, B double-buffer, s_sleep skew ----------------
__global__ __launch_bounds__(512, 2) void conv2_img_kernel(const __hip_bfloat16* __restrict__ in,
                                                           const __hip_bfloat16* __restrict__ wp,
                                                           const float* __restrict__ bias,
                                                           __hip_bfloat16* __restrict__ out) {
    __shared__ __hip_bfloat16 Ald[75264];   // 150528 B = [48 iy][49 cols][32 ch] swizzled (col 48 pad)
    int bid = blockIdx.x;
    int wg = (bid & 7) * 32 + (bid >> 3);   // XCD-chunk: nblk pair lands on same XCD
    int b = wg >> 1, nblk = wg & 1;
    int t = threadIdx.x;
    int lane = t & 63, wid = t >> 6;
    int wr = wid >> 1, wc = wid & 1;        // 4 (M) x 2 (N) wave grid
    int ch8 = lane >> 4;

    const __hip_bfloat16* imgbase = in + (long)b * (48 * 48 * 256);
    const __hip_bfloat16* wpn = wp + (long)nblk * 4096 + (wc * 64 + (lane & 15)) * 32 + ch8 * 8;

    int qbase[7];
#pragma unroll
    for (int mi = 0; mi < 7; ++mi) {
        int ml = wr * 96 + mi * 16 + (lane & 15);
        int oy = ml / 20, ox = ml - oy * 20;
        qbase[mi] = ((2 * oy) * 49 + 2 * ox) * 4 + ch8;
    }

    f32x4 acc[7][4];
#pragma unroll
    for (int i = 0; i < 7; ++i)
#pragma unroll
        for (int j = 0; j < 4; ++j) acc[i][j] = (f32x4){0.f, 0.f, 0.f, 0.f};

    auto stageA = [&](int icg) {
#pragma unroll
        for (int c = 0; c < 3; ++c) {
            uint4 v[6];
#pragma unroll
            for (int j = 0; j < 6; ++j) {
                int gi = t + (c * 6 + j) * 512;
                int lrow = gi >> 2;
                int iy = lrow / 48;
                int col = lrow - iy * 48;
                if (iy > 46) iy = 46;  // row 47 pad, never read
                v[j] = *(const uint4*)(imgbase + (iy * 48 + col) * 256 + icg * 32 + (gi & 3) * 8);
            }
#pragma unroll
            for (int j = 0; j < 6; ++j) {
                int gi = t + (c * 6 + j) * 512;
                int lrow = gi >> 2;
                int iy = lrow / 48;
                int col = lrow - iy * 48;
                int dst = (iy * 49 + col) * 4 + (gi & 3);
                int phys = dst ^ ((dst >> 3) & 7);
                *(uint4*)((char*)Ald + phys * 16) = v[j];
            }
        }
    };

    bf16x8 af_e[7], af_o[7], Be[4], Bo[4];
    int pf_kdelta = 0, pf_kx = 0, pf_ky = 0;
    auto prefA = [&](bf16x8* af) {
#pragma unroll
        for (int mi = 0; mi < 7; ++mi) {
            int qg = qbase[mi] + pf_kdelta;
            int phys = qg ^ ((qg >> 3) & 7);
            af[mi] = *(const bf16x8*)((const char*)Ald + phys * 16);
        }
        ++pf_kx; pf_kdelta += 4;
        if (pf_kx == 9) { pf_kx = 0; ++pf_ky; pf_kdelta = pf_ky * 196; }
    };
    auto domfma = [&](bf16x8* af, bf16x8* bf) {
        __builtin_amdgcn_s_setprio(1);
#pragma unroll
        for (int mi = 0; mi < 7; ++mi)
#pragma unroll
            for (int ni = 0; ni < 4; ++ni)
                acc[mi][ni] = __builtin_amdgcn_mfma_f32_16x16x32_bf16(af[mi], bf[ni], acc[mi][ni], 0, 0, 0);
        __builtin_amdgcn_s_setprio(0);
    };

    for (int icg = 0; icg < 8; ++icg) {
        const __hip_bfloat16* wpi = wpn + (long)icg * 8192;
        auto loadB = [&](bf16x8* dst, int kyx) {
            const __hip_bfloat16* p = wpi + (long)kyx * 65536;
#pragma unroll
            for (int ni = 0; ni < 4; ++ni) dst[ni] = *(const bf16x8*)(p + ni * 512);
        };
        if (icg) __builtin_amdgcn_s_barrier();   // all waves done reading old A
        loadB(Be, 0);
        loadB(Bo, 1);
        stageA(icg);
        asm volatile("s_waitcnt lgkmcnt(0)" ::: "memory");
        __builtin_amdgcn_s_barrier();
        if (wid >= 4) asm volatile("s_sleep 4");   // de-phase co-resident waves

        pf_kx = 0; pf_ky = 0; pf_kdelta = 0;
        prefA(af_e);                                // step 0 fragments
        for (int it2 = 0; it2 < 40; ++it2) {
            prefA(af_o);
            domfma(af_e, Be);
            loadB(Be, 2 * it2 + 2);
            prefA(af_e);
            domfma(af_o, Bo);
            loadB(Bo, 2 * it2 + 3);   // kyx 81,82 read harmless garbage past tile (never used)
        }
        domfma(af_e, Be);                           // step 80
    }

    int colbase = nblk * 128 + wc * 64 + (lane & 15);
#pragma unroll
    for (int mi = 0; mi < 7; ++mi) {
#pragma unroll
        for (int ni = 0; ni < 4; ++ni) {
            int col = colbase + ni * 16;
            float bs = bias[col];
#pragma unroll
            for (int r = 0; r < 4; ++r) {
                int ml = wr * 96 + mi * 16 + (lane >> 4) * 4 + r;
                float v = acc[mi][ni][r] + bs;
                v = v > 0.f ? v : 0.f;
                out[((long)b * 400 + ml) * 256 + col] = __float2bfloat16(v);
            }
        }
    }
}

// ---------------- conv3: implicit-GEMM 128x128 (split-K), ring-3, counted vmcnt, bf16 partials ----------------
__global__ __launch_bounds__(256) void conv_mfma_kernel(const __hip_bfloat16* __restrict__ in,
                                                        const __hip_bfloat16* __restrict__ wp,
                                                        const float* __restrict__ bias,
                                                        __hip_bfloat16* __restrict__ out,
                                                        __hip_bfloat16* __restrict__ part,
                                                        int Win, int imgStride, int HWout, int Wout,
                                                        int nkyx, int Mtot, int mode) {
    __shared__ __hip_bfloat16 Ald[3 * 4096];
    __shared__ __hip_bfloat16 Bld[3 * 4096];
    int mblk = blockIdx.x, nblk = blockIdx.y;
    int kyx0 = blockIdx.z * nkyx;
    int t = threadIdx.x;
    int lane = t & 63, wid = t >> 6;
    int swz = ((t & 3) ^ ((t >> 3) & 3)) * 8;
    int icsrc = swz;
    long bsrc = (t >> 2) * 32 + swz;

    long base0, base1;
    {
        int m = mblk * 128 + (t >> 2);
        int b = m / HWout; int rem = m - b * HWout;
        int oyy = rem / Wout; int oxx = rem - oyy * Wout;
        base0 = (long)b * imgStride + (long)(2 * oyy * Win + 2 * oxx) * 256;
        m += 64;
        b = m / HWout; rem = m - b * HWout;
        oyy = rem / Wout; oxx = rem - oyy * Wout;
        base1 = (long)b * imgStride + (long)(2 * oyy * Win + 2 * oxx) * 256;
    }

    f32x4 acc[4][4];
#pragma unroll
    for (int i = 0; i < 4; ++i)
#pragma unroll
        for (int j2 = 0; j2 < 4; ++j2) acc[i][j2] = (f32x4){0.f, 0.f, 0.f, 0.f};

    int wr = wid >> 1, wc = wid & 1;
    int slot8 = (((lane >> 4) ^ ((lane >> 1) & 3))) * 8;
    int a_off = ((wr * 64 + (lane & 15)) * 32 + slot8) * 2;
    int b_off = ((wc * 64 + (lane & 15)) * 32 + slot8) * 2;

    auto stage = [&](int s, int buf) {
        int kyx = kyx0 + (s >> 3);
        int icg = s & 7;
        int ky = kyx / 9, kx = kyx - ky * 9;
        long offA = (long)(ky * Win + kx) * 256 + icg * 32 + icsrc;
        long btb = (long)((kyx * 8 + icg) * 2 + nblk) * 4096 + bsrc;
        char* a0 = (char*)Ald + buf * 8192 + wid * 1024;
        char* b0 = (char*)Bld + buf * 8192 + wid * 1024;
        gload16(in + base0 + offA, a0);
        gload16(in + base1 + offA, a0 + 4096);
        gload16(wp + btb, b0);
        gload16(wp + btb + 2048, b0 + 4096);
    };

    int nsteps = nkyx * 8;
    stage(0, 0);
    stage(1, 1);
    stage(2, 2);
    int cur = 0;
    for (int s = 0; s < nsteps; ++s) {
        int rem = nsteps - 1 - s;
        if (rem >= 2) {
            asm volatile("s_waitcnt vmcnt(8)" ::: "memory");
        } else if (rem == 1) {
            asm volatile("s_waitcnt vmcnt(4)" ::: "memory");
        } else {
            asm volatile("s_waitcnt vmcnt(0)" ::: "memory");
        }
        __builtin_amdgcn_s_barrier();
        __builtin_amdgcn_sched_barrier(0);
        const char* Ac = (const char*)Ald + cur * 8192;
        const char* Bc = (const char*)Bld + cur * 8192;
        bf16x8 af[4], bfr[4];
#pragma unroll
        for (int i = 0; i < 4; ++i) af[i] = *(const bf16x8*)(Ac + a_off + i * 1024);
#pragma unroll
        for (int i = 0; i < 4; ++i) bfr[i] = *(const bf16x8*)(Bc + b_off + i * 1024);
#pragma unroll
        for (int mi = 0; mi < 4; ++mi)
#pragma unroll
            for (int ni = 0; ni < 4; ++ni)
                acc[mi][ni] = __builtin_amdgcn_mfma_f32_16x16x32_bf16(af[mi], bfr[ni], acc[mi][ni], 0, 0, 0);
        if (s + 3 < nsteps) {
            asm volatile("s_waitcnt lgkmcnt(0)" ::: "memory");
            __builtin_amdgcn_s_barrier();
            stage(s + 3, cur);
        }
        cur = (cur == 2) ? 0 : cur + 1;
    }

    int colbase = nblk * 128 + wc * 64 + (lane & 15);
    long mrowbase = (long)mblk * 128 + wr * 64 + (lane >> 4) * 4;
    if (mode == 0) {
#pragma unroll
        for (int mi = 0; mi < 4; ++mi) {
#pragma unroll
            for (int ni = 0; ni < 4; ++ni) {
                int col = colbase + ni * 16;
                float bs = bias[col];
#pragma unroll
                for (int r = 0; r < 4; ++r) {
                    long mrow = mrowbase + mi * 16 + r;
                    float v = acc[mi][ni][r] + bs;
                    v = v > 0.f ? v : 0.f;
                    out[mrow * 256 + col] = __float2bfloat16(v);
                }
            }
        }
    } else {
        __hip_bfloat16* pp = part + (long)blockIdx.z * Mtot * 256;
#pragma unroll
        for (int mi = 0; mi < 4; ++mi) {
#pragma unroll
            for (int ni = 0; ni < 4; ++ni) {
                int col = colbase + ni * 16;
#pragma unroll
                for (int r = 0; r < 4; ++r) {
                    long mrow = mrowbase + mi * 16 + r;
                    pp[mrow * 256 + col] = __float2bfloat16(acc[mi][ni][r]);
                }
            }
        }
    }
}

// ---------------- split-K reduce: sum 9 bf16 partials + bias + relu -> bf16 NHWC ----------------
__global__ __launch_bounds__(256) void reduce_parts_kernel(const __hip_bfloat16* __restrict__ part,
                                                           const float* __restrict__ bias,
                                                           __hip_bfloat16* __restrict__ out) {
    int idx = blockIdx.x * 256 + threadIdx.x;  // 4608*256
    float s = 0.f;
#pragma unroll
    for (int p = 0; p < 9; ++p) s += __bfloat162float(part[(long)p * 1179648 + idx]);
    s += bias[idx & 255];
    s = s > 0.f ? s : 0.f;
    out[idx] = __float2bfloat16(s);
}

// ---------------- primary capsule squash: NHWC bf16 -> uT f32 [1152 i][128 b][8 d] ----------------
__global__ __launch_bounds__(256) void squash_caps_kernel(const __hip_bfloat16* __restrict__ c3,
                                                          float* __restrict__ uT) {
    int g = blockIdx.x * 256 + threadIdx.x;  // 147456 = 1152*128, i-major
    int i = g >> 7, b = g & 127;
    float val[8];
    float sn = 0.f;
#pragma unroll
    for (int d = 0; d < 8; ++d) {
        int flat = i * 8 + d;
        int c = flat / 36; int rem = flat - c * 36;
        int y = rem / 6; int xx = rem - y * 6;
        float vv = __bfloat162float(c3[((b * 6 + y) * 6 + xx) * 256 + c]);
        val[d] = vv;
        sn += vv * vv;
    }
    float sc = (sn / (1.f + sn)) / sqrtf(sn + 1e-8f);
#pragma unroll
    for (int d = 0; d < 8; ++d) uT[(long)g * 8 + d] = val[d] * sc;  // contiguous 32B/thread
}

// ---------------- u_hat[b,j,i,o] = sum_d uT[i,b,d] * W[j,i,d,o]  (vectorized LDS, no div in loop) ----------------
__global__ __launch_bounds__(256) void uhat_kernel(const float* __restrict__ uT,
                                                   const float* __restrict__ Wd,
                                                   __hip_bfloat16* __restrict__ uhat) {
    __shared__ float Wl2[1600];  // [jo=160][10]: 8 d-values + 2 pad (40B stride -> conflict-free b64)
    __shared__ float ul[1024];   // [b=128][8]   (32B stride -> b128 broadcast)
    int i = blockIdx.x, t = threadIdx.x;
    for (int idx = t; idx < 1280; idx += 256) {
        int j = idx >> 7, rest = idx & 127;
        int d = rest >> 4, o = rest & 15;
        Wl2[(j * 16 + o) * 10 + d] = Wd[((long)j * 1152 + i) * 128 + rest];
    }
    {
        const float4* usrc = (const float4*)(uT + (long)i * 1024);
        float4* ud = (float4*)ul;
        ud[t] = usrc[t];  // 256 float4 = whole [128][8]
    }
    __syncthreads();
    int b = (t >= 160) ? 1 : 0;
    int jo = (t >= 160) ? t - 160 : t;
    for (int rr = 0; rr < 80; ++rr) {
        const float* up = &ul[b * 8];
        const float* wq = &Wl2[jo * 10];
        float a = 0.f;
#pragma unroll
        for (int d = 0; d < 8; ++d) a += up[d] * wq[d];
        int j = jo >> 4, o = jo & 15;
        uhat[(((long)b * 10 + j) * 1152 + i) * 16 + o] = __float2bfloat16(a);
        jo += 96; b += 1;
        if (jo >= 160) { jo -= 160; b += 1; }
    }
}

// ---------------- fused dynamic routing per (b,j): 3 iterations in LDS ----------------
__global__ __launch_bounds__(256) void routing_kernel(const __hip_bfloat16* __restrict__ uhat,
                                                      const float* __restrict__ bdig,
                                                      float* __restrict__ vout,
                                                      float* __restrict__ vws) {
    __shared__ __hip_bfloat16 uh[1152 * 16];  // 36864B
    __shared__ float barr[1152];
    __shared__ float red[16];
    __shared__ float accb[16 * 256];          // 16KB
    __shared__ float svec[16];
    __shared__ float vsc[16];
    int bid = blockIdx.x;  // b*10 + j
    int j = bid % 10;
    int t = threadIdx.x;
    int wid = t >> 6;
    const uint4* srcp = (const uint4*)(uhat + (long)bid * 18432);
    uint4* dstp = (uint4*)uh;
    for (int idx = t; idx < 2304; idx += 256) dstp[idx] = srcp[idx];
    for (int idx = t; idx < 1152; idx += 256) barr[idx] = 0.f;
    __syncthreads();
    for (int it = 0; it < 3; ++it) {
        float lm = -1e30f;
        for (int i = t; i < 1152; i += 256) lm = fmaxf(lm, barr[i]);
#pragma unroll
        for (int m2 = 32; m2; m2 >>= 1) lm = fmaxf(lm, __shfl_xor(lm, m2));
        if ((t & 63) == 0) red[wid] = lm;
        __syncthreads();
        float mx = fmaxf(fmaxf(red[0], red[1]), fmaxf(red[2], red[3]));
        float le = 0.f;
        float a16[16];
#pragma unroll
        for (int o = 0; o < 16; ++o) a16[o] = 0.f;
        for (int i = t; i < 1152; i += 256) {
            float e = __expf(barr[i] - mx);
            le += e;
            const uint4* up = (const uint4*)(uh + i * 16);
            union { uint4 q; unsigned short s[8]; } U0, U1;
            U0.q = up[0]; U1.q = up[1];
#pragma unroll
            for (int o = 0; o < 8; ++o) a16[o] += e * bfu(U0.s[o]);
#pragma unroll
            for (int o = 0; o < 8; ++o) a16[8 + o] += e * bfu(U1.s[o]);
        }
#pragma unroll
        for (int m2 = 32; m2; m2 >>= 1) le += __shfl_xor(le, m2);
        if ((t & 63) == 0) red[4 + wid] = le;
#pragma unroll
        for (int o = 0; o < 16; ++o) accb[o * 256 + t] = a16[o];
        __syncthreads();
        float sume = red[4] + red[5] + red[6] + red[7];
        int g = t >> 4, tin = t & 15;
        float s = 0.f;
#pragma unroll
        for (int k = 0; k < 16; ++k) s += accb[g * 256 + tin + 16 * k];
#pragma unroll
        for (int m2 = 8; m2; m2 >>= 1) s += __shfl_xor(s, m2);
        if (tin == 0) svec[g] = s / sume + bdig[j * 16 + g];
        __syncthreads();
        if (t < 16) {
            float sv = svec[t];
            float sn = sv * sv;
#pragma unroll
            for (int m2 = 8; m2; m2 >>= 1) sn += __shfl_xor(sn, m2);
            float sc = (sn / (1.f + sn)) / sqrtf(sn + 1e-8f);
            float v = sv * sc;
            vsc[t] = v;
            if (it == 2) { vout[bid * 16 + t] = v; vws[bid * 16 + t] = v; }
        }
        __syncthreads();
        if (it < 2) {
            for (int i = t; i < 1152; i += 256) {
                const uint4* up = (const uint4*)(uh + i * 16);
                union { uint4 q; unsigned short s[8]; } U0, U1;
                U0.q = up[0]; U1.q = up[1];
                float dot = 0.f;
#pragma unroll
                for (int o = 0; o < 8; ++o) dot += vsc[o] * bfu(U0.s[o]);
#pragma unroll
                for (int o = 0; o < 8; ++o) dot += vsc[8 + o] * bfu(U1.s[o]);
                barr[i] += dot;
            }
            __syncthreads();
        }
    }
}

// ---------------- reconstruction GEMM, latency-proof: W tile preloaded to regs 1 tile ahead,
// A double-buffered in LDS with float4 broadcast reads ----------------
__global__ __launch_bounds__(256) void rec_gemm_kernel(const float* __restrict__ A,
                                                       const float* __restrict__ W,
                                                       const float* __restrict__ bias,
                                                       float* __restrict__ out,
                                                       int K, int N, int act) {
    __shared__ __align__(16) float As[2][2048];  // 2 x [32 rows][64 k]
    int n0 = blockIdx.x * 64;
    int bch = blockIdx.y * 32;
    int t = threadIdx.x;
    int n_l = t & 63, bh = t >> 6;
    const float* Wc = W + n0 + n_l;
    float acc[8];
#pragma unroll
    for (int i = 0; i < 8; ++i) acc[i] = 0.f;
    int T = (K + 63) >> 6;

    auto stageA = [&](int tile, int buf) {
        int k0 = tile << 6;
        for (int idx = t; idx < 2048; idx += 256) {
            int bb = idx >> 6, kk = idx & 63;
            As[buf][idx] = (k0 + kk < K) ? A[(long)(bch + bb) * K + k0 + kk] : 0.f;
        }
    };
    auto ldW = [&](int tile, float* w) {
        int k0 = tile << 6;
#pragma unroll
        for (int j = 0; j < 64; ++j) {
            int kr = k0 + j;
            if (kr >= K) kr = K - 1;          // clamped row x zero-padded A = harmless
            w[j] = Wc[(long)kr * N];
        }
    };
    auto compute = [&](const float* w, int buf) {
#pragma unroll
        for (int bb = 0; bb < 8; ++bb) {
            const float4* ap = (const float4*)&As[buf][(bh * 8 + bb) * 64];
            float s = 0.f;
#pragma unroll
            for (int q = 0; q < 16; ++q) {
                float4 a = ap[q];
                s += a.x * w[q * 4] + a.y * w[q * 4 + 1] + a.z * w[q * 4 + 2] + a.w * w[q * 4 + 3];
            }
            acc[bb] += s;
        }
    };

    float wA[64], wB[64];
    ldW(0, wA);
    stageA(0, 0);
    __syncthreads();
    for (int tile = 0; tile < T; tile += 2) {
        if (tile + 1 < T) { ldW(tile + 1, wB); stageA(tile + 1, 1); }
        compute(wA, 0);
        __syncthreads();
        if (tile + 1 < T) {
            if (tile + 2 < T) { ldW(tile + 2, wA); stageA(tile + 2, 0); }
            compute(wB, 1);
            __syncthreads();
        }
    }

    float bs = bias[n0 + n_l];
#pragma unroll
    for (int bb = 0; bb < 8; ++bb) {
        float x = acc[bb] + bs;
        float r;
        if (act == 0) r = x > 0.f ? x : 0.f;
        else r = 1.f / (1.f + __expf(-x));
        out[(long)(bch + bh * 8 + bb) * N + n0 + n_l] = r;
    }
}

extern "C" void kernel_launch(void* const* d_in, const int* in_sizes, int n_in,
                              void* d_out, int out_size, void* d_ws, size_t ws_size,
                              hipStream_t stream) {
    const float* x   = (const float*)d_in[0];
    const float* c1w = (const float*)d_in[1];
    const float* c1b = (const float*)d_in[2];
    const float* c2w = (const float*)d_in[3];
    const float* c2b = (const float*)d_in[4];
    const float* pw  = (const float*)d_in[5];
    const float* pb  = (const float*)d_in[6];
    const float* Wd  = (const float*)d_in[7];
    const float* bd  = (const float*)d_in[8];
    const float* rw1 = (const float*)d_in[9];
    const float* rb1 = (const float*)d_in[10];
    const float* rw2 = (const float*)d_in[11];
    const float* rb2 = (const float*)d_in[12];
    const float* rw3 = (const float*)d_in[13];
    const float* rb3 = (const float*)d_in[14];
    float* outp = (float*)d_out;

    char* ws = (char*)d_ws;
    size_t off = 0;
    auto alloc = [&](size_t bytes) {
        char* p = ws + off;
        off += (bytes + 255) & ~(size_t)255;
        return p;
    };
    __hip_bfloat16* c1out = (__hip_bfloat16*)alloc(150994944UL);  // [128][48][48][256] bf16
    __hip_bfloat16* c2out = (__hip_bfloat16*)alloc(26214400UL);   // [128][20][20][256]
    __hip_bfloat16* c3out = (__hip_bfloat16*)alloc(2359296UL);    // [128][6][6][256]
    __hip_bfloat16* w2p   = (__hip_bfloat16*)alloc(10616832UL);
    __hip_bfloat16* w3p   = (__hip_bfloat16*)alloc(10616832UL);
    __hip_bfloat16* xb    = (__hip_bfloat16*)alloc(802816UL);   // [128][56][56] bf16
    __hip_bfloat16* wb    = (__hip_bfloat16*)alloc(49152UL);    // [12][256][8] bf16
    float* uT    = (float*)alloc(4718592UL);    // [1152][128][8] f32
    __hip_bfloat16* uhat = (__hip_bfloat16*)alloc(47185920UL);  // [128][10][1152][16] bf16
    float* vws   = (float*)alloc(81920UL);      // [128][160]
    float* rec1  = (float*)alloc(262144UL);     // [128][512]
    float* rec2  = (float*)alloc(524288UL);     // [128][1024]

    // conv3 split-K bf16 partials [9][4608][256] alias the (later-written) uhat buffer
    __hip_bfloat16* c3part = (__hip_bfloat16*)uhat;

    prep_w_kernel<<<1417, 256, 0, stream>>>(c2w, pw, w2p, w3p, c1w, wb, x, xb);
    conv1_mfma_kernel<<<3072, 256, 0, stream>>>(xb, wb, c1b, c1out);
    conv2_img_kernel<<<256, 512, 0, stream>>>(c1out, w2p, c2b, c2out);
    conv_mfma_kernel<<<dim3(36, 2, 9), 256, 0, stream>>>(c2out, w3p, pb, c3out, c3part,
                                                         20, 20 * 20 * 256, 36, 6, 9, 4608, 1);
    reduce_parts_kernel<<<4608, 256, 0, stream>>>(c3part, pb, c3out);
    squash_caps_kernel<<<576, 256, 0, stream>>>(c3out, uT);
    uhat_kernel<<<1152, 256, 0, stream>>>(uT, Wd, uhat);
    routing_kernel<<<1280, 256, 0, stream>>>(uhat, bd, outp, vws);
    rec_gemm_kernel<<<dim3(8, 4), 256, 0, stream>>>(vws, rw1, rb1, rec1, 160, 512, 0);
    rec_gemm_kernel<<<dim3(16, 4), 256, 0, stream>>>(rec1, rw2, rb2, rec2, 512, 1024, 0);
    rec_gemm_kernel<<<dim3(49, 4), 256, 0, stream>>>(rec2, rw3, rb3, outp + 20480, 1024, 3136, 1);
}

// Round 17
// 785.166 us; speedup vs baseline: 1.9882x; 1.0280x over previous
//
#include <hip/hip_runtime.h>
#include <hip/hip_bf16.h>

typedef float f32x4 __attribute__((ext_vector_type(4)));
typedef __bf16 bf16x8 __attribute__((ext_vector_type(8)));
typedef __bf16 bf16x4 __attribute__((ext_vector_type(4)));
typedef int i32x8 __attribute__((ext_vector_type(8)));

#define AS1 __attribute__((address_space(1)))
#define AS3 __attribute__((address_space(3)))

__device__ __forceinline__ void gload16(const void* g, void* l) {
    __builtin_amdgcn_global_load_lds((AS1 unsigned int*)g, (AS3 unsigned int*)l, 16, 0, 0);
}

__device__ __forceinline__ float bfu(unsigned short u) {
    return __uint_as_float((unsigned)u << 16);
}

// float -> fp8 e4m3 (OCP), truncating, signed, flush-to-zero below 2^-6, clamp 448
__device__ __forceinline__ unsigned char f2e4m3s(float f) {
    unsigned u = __float_as_uint(f);
    unsigned s = (u >> 24) & 0x80;
    unsigned ua = u & 0x7fffffffu;
    int e = (int)(ua >> 23) - 127;
    unsigned m = (ua >> 20) & 7;
    if (e < -6) return (unsigned char)s;
    if (e > 8 || (e == 8 && m > 6)) return (unsigned char)(s | 0x7e);
    return (unsigned char)(s | ((unsigned)(e + 7) << 3) | m);
}

// ---------------- prep: [0,512) conv3 w -> bf16 table; 512: conv1 wb; [513,905) x->bf16;
// [905,1241) conv2 w -> fp8 table [icg][21 ks][nblk][128 oc][128 kb] (x64, zero pad kyx>=81) ----------------
__global__ __launch_bounds__(256) void prep_w_kernel(const float* __restrict__ pw,
                                                     __hip_bfloat16* __restrict__ w3p,
                                                     const float* __restrict__ c1w,
                                                     __hip_bfloat16* __restrict__ wb,
                                                     const float* __restrict__ x,
                                                     __hip_bfloat16* __restrict__ xb,
                                                     const float* __restrict__ c2w,
                                                     unsigned char* __restrict__ wq2) {
    int bid = blockIdx.x;
    int t = threadIdx.x;
    if (bid == 512) {  // conv1 weight table: kslot 0-8: (ky=ks, kx=e); 9: (ky=e, kx=8); 10: e0=(8,8); 11: zero
        float tmp[81];
#pragma unroll
        for (int k = 0; k < 81; ++k) tmp[k] = c1w[t * 81 + k];
#pragma unroll
        for (int ks = 0; ks < 9; ++ks)
#pragma unroll
            for (int e = 0; e < 8; ++e)
                wb[(ks * 256 + t) * 8 + e] = __float2bfloat16(tmp[ks * 9 + e]);
#pragma unroll
        for (int e = 0; e < 8; ++e)
            wb[(9 * 256 + t) * 8 + e] = __float2bfloat16(tmp[e * 9 + 8]);
        wb[(10 * 256 + t) * 8 + 0] = __float2bfloat16(tmp[80]);
#pragma unroll
        for (int e = 1; e < 8; ++e) wb[(10 * 256 + t) * 8 + e] = __float2bfloat16(0.f);
#pragma unroll
        for (int e = 0; e < 8; ++e) wb[(11 * 256 + t) * 8 + e] = __float2bfloat16(0.f);
        return;
    }
    if (bid >= 513 && bid < 905) {  // x -> bf16 (392 blocks x 1024 elems)
        long i4 = (long)(bid - 513) * 1024 + t * 4;
        float4 v = *(const float4*)(x + i4);
        bf16x4 o = {(__bf16)v.x, (__bf16)v.y, (__bf16)v.z, (__bf16)v.w};
        *(bf16x4*)((__bf16*)xb + i4) = o;
        return;
    }
    if (bid >= 905) {  // conv2 fp8 table
        int b2 = bid - 905;               // icg*42 + ks*2 + nblk
        int icg = b2 / 42; int rem = b2 - icg * 42;
        int ks = rem >> 1, nblk = rem & 1;
        long base = (long)icg * 688128 + (long)ks * 32768 + (long)nblk * 16384;
#pragma unroll
        for (int u = 0; u < 64; ++u) {
            int flat = t * 64 + u;
            int ocl = flat >> 7, kb = flat & 127;
            int kq = kb >> 5, icl = kb & 31;
            int kyx = ks * 4 + kq;
            float v = 0.f;
            if (kyx < 81)
                v = c2w[(long)(nblk * 128 + ocl) * 20736 + (icg * 32 + icl) * 81 + kyx] * 64.f;
            wq2[base + flat] = f2e4m3s(v);
        }
        return;
    }
    // conv3 weights -> bf16 [kyx][icg][nblk][oc128][ic32]
    __shared__ float wl[4 * 32 * 81];  // [o][i][kyx]
    int icg = bid & 7;
    int oc4 = (bid >> 3) & 31;
    int nblk = bid >> 8;
    int ocg0 = nblk * 128 + oc4 * 4;
    int ic0 = icg * 32;
    for (int f = t; f < 4 * 2592; f += 256) {
        int o = f / 2592;
        int rest = f - o * 2592;
        wl[f] = pw[(ocg0 + o) * 20736 + ic0 * 81 + rest];
    }
    __syncthreads();
    for (int idx = t; idx < 81 * 128; idx += 256) {
        int kyx = idx >> 7;
        int o = (idx >> 5) & 3;
        int i = idx & 31;
        long dst = (long)(((kyx * 8 + icg) * 2 + nblk) * 128 + (oc4 * 4 + o)) * 32 + i;
        w3p[dst] = __float2bfloat16(wl[o * 2592 + i * 81 + kyx]);
    }
}

// ---------------- conv1 as bf16 MFMA implicit-GEMM, writes fp8 (x16 pre-scale) ----------------
__global__ __launch_bounds__(256) void conv1_mfma_kernel(const __hip_bfloat16* __restrict__ xb,
                                                         const __hip_bfloat16* __restrict__ wb,
                                                         const float* __restrict__ bias,
                                                         unsigned char* __restrict__ out) {
    __shared__ __bf16 Asl[640];  // [10 rows][64 cols]
    int bid = blockIdx.x;
    int b = bid / 24, mb2 = bid - b * 24;
    int oy0 = mb2 * 2;
    int t = threadIdx.x;
    int lane = t & 63, wc = t >> 6;
    int q = lane >> 4;

    const __bf16* src = (const __bf16*)xb + b * 3136 + oy0 * 56;
    for (int idx = t; idx < 640; idx += 256) {
        int iy = idx >> 6, col = idx & 63;
        Asl[idx] = (col < 56) ? src[iy * 56 + col] : (__bf16)0.f;
    }

    bf16x8 Bf[3][4];
#pragma unroll
    for (int s = 0; s < 3; ++s)
#pragma unroll
        for (int ni = 0; ni < 4; ++ni) {
            int col = wc * 64 + ni * 16 + (lane & 15);
            Bf[s][ni] = *(const bf16x8*)(wb + ((s * 4 + q) * 256 + col) * 8);
        }

    f32x4 acc[6][4];
#pragma unroll
    for (int i = 0; i < 6; ++i)
#pragma unroll
        for (int j = 0; j < 4; ++j) acc[i][j] = (f32x4){0.f, 0.f, 0.f, 0.f};

    __syncthreads();

#pragma unroll
    for (int s = 0; s < 3; ++s) {
        int ks = s * 4 + q;
        bf16x8 af[6];
#pragma unroll
        for (int mi = 0; mi < 6; ++mi) {
            int r = mi * 16 + (lane & 15);
            int oyl = (r >= 48) ? 1 : 0;
            int ox = r - 48 * oyl;
            bf16x8 v;
            if (ks < 9) {
                __builtin_memcpy(&v, &Asl[(oyl + ks) * 64 + ox], 16);
            } else if (ks == 9) {
#pragma unroll
                for (int e = 0; e < 8; ++e) v[e] = Asl[(oyl + e) * 64 + ox + 8];
            } else if (ks == 10) {
#pragma unroll
                for (int e = 0; e < 8; ++e) v[e] = (__bf16)0.f;
                v[0] = Asl[(oyl + 8) * 64 + ox + 8];
            } else {
#pragma unroll
                for (int e = 0; e < 8; ++e) v[e] = (__bf16)0.f;
            }
            af[mi] = v;
        }
#pragma unroll
        for (int mi = 0; mi < 6; ++mi)
#pragma unroll
            for (int ni = 0; ni < 4; ++ni)
                acc[mi][ni] = __builtin_amdgcn_mfma_f32_16x16x32_bf16(af[mi], Bf[s][ni], acc[mi][ni], 0, 0, 0);
    }

    long m0 = (long)b * 2304 + mb2 * 96;
#pragma unroll
    for (int mi = 0; mi < 6; ++mi)
#pragma unroll
        for (int ni = 0; ni < 4; ++ni) {
            int col = wc * 64 + ni * 16 + (lane & 15);
            float bs = bias[col];
#pragma unroll
            for (int r2 = 0; r2 < 4; ++r2) {
                int row = mi * 16 + q * 4 + r2;
                float vv = acc[mi][ni][r2] + bs;
                vv = vv > 0.f ? vv : 0.f;
                out[(m0 + row) * 256 + col] = f2e4m3s(vv * 16.f);
            }
        }
}

// ---------------- conv2: MX-fp8 (K=128), LDS-resident fp8 im2col slice [48][49][32ch] (75KB),
// barrier-free K-loop, B fp8 table -> reg double-buffer, neutral scale bytes (127 -> 2^0) ----------------
__global__ __launch_bounds__(512, 2) void conv2_fp8_kernel(const unsigned char* __restrict__ in,
                                                           const unsigned char* __restrict__ wq,
                                                           const float* __restrict__ bias,
                                                           __hip_bfloat16* __restrict__ out) {
    __shared__ unsigned char Ald[75264];   // [48 iy][49 col][32 ch] fp8 (col 48 pad)
    int bid = blockIdx.x;
    int wg = (bid & 7) * 32 + (bid >> 3);  // XCD-chunk
    int b = wg >> 1, nblk = wg & 1;
    int t = threadIdx.x;
    int lane = t & 63, wid = t >> 6;
    int wr = wid >> 1, wc = wid & 1;       // 4 M x 2 N waves
    int kq = lane >> 4;

    const unsigned char* imgbase = in + (long)b * (48 * 48 * 256);
    const unsigned char* wqn = wq + ((long)(nblk * 128 + wc * 64 + (lane & 15))) * 128 + kq * 32;

    int qrow[7];
#pragma unroll
    for (int mi = 0; mi < 7; ++mi) {
        int ml = wr * 96 + mi * 16 + (lane & 15);
        int oy = ml / 20, ox = ml - oy * 20;
        qrow[mi] = ((2 * oy) * 49 + 2 * ox) * 32;  // bytes
    }

    f32x4 acc[7][4];
#pragma unroll
    for (int i = 0; i < 7; ++i)
#pragma unroll
        for (int j = 0; j < 4; ++j) acc[i][j] = (f32x4){0.f, 0.f, 0.f, 0.f};

    auto stageA = [&](int icg) {
#pragma unroll 3
        for (int j = 0; j < 9; ++j) {
            int gi = t + j * 512;
            int row32 = gi >> 1, half = gi & 1;
            int iy = row32 / 48, col = row32 - iy * 48;
            uint4 v = *(const uint4*)(imgbase + ((long)(iy * 48 + col) * 256 + icg * 32 + half * 16));
            *(uint4*)(Ald + (iy * 49 + col) * 32 + half * 16) = v;
        }
    };

    union U8 { uint4 q[2]; i32x8 v; };
    i32x8 Be[4], Bo[4];
    auto loadB = [&](i32x8* dst, int icg, int ks) {
        const unsigned char* p = wqn + (long)icg * 688128 + (long)ks * 32768;
        uint4* d = (uint4*)dst;
#pragma unroll
        for (int ni = 0; ni < 4; ++ni) {
            d[ni * 2]     = *(const uint4*)(p + ni * 2048);
            d[ni * 2 + 1] = *(const uint4*)(p + ni * 2048 + 16);
        }
    };

    auto step = [&](int icg, int ks, i32x8* Bcur, i32x8* Bnxt) {
        if (ks + 1 < 21) loadB(Bnxt, icg, ks + 1);
        int kyx = ks * 4 + kq;
        int ky = kyx / 9;
        int kdel = (kyx + 40 * ky) * 32;   // (ky*49 + kx)*32 bytes
        __builtin_amdgcn_s_setprio(1);
#pragma unroll
        for (int mi = 0; mi < 7; ++mi) {
            const unsigned char* ap = Ald + qrow[mi] + kdel;
            U8 a;
            a.q[0] = *(const uint4*)ap;
            a.q[1] = *(const uint4*)(ap + 16);
#pragma unroll
            for (int ni = 0; ni < 4; ++ni)
                acc[mi][ni] = __builtin_amdgcn_mfma_scale_f32_16x16x128_f8f6f4(
                    a.v, Bcur[ni], acc[mi][ni],
                    0, 0,                      // cbsz=fp8-e4m3 (A), blgp=fp8-e4m3 (B)
                    0, 0x7F7F7F7F,             // opsel_a (imm), scale_a (byte0=127 -> 2^0)
                    0, 0x7F7F7F7F);            // opsel_b (imm), scale_b
        }
        __builtin_amdgcn_s_setprio(0);
    };

    for (int icg = 0; icg < 8; ++icg) {
        if (icg) __builtin_amdgcn_s_barrier();   // all waves done reading old A
        loadB(Be, icg, 0);
        stageA(icg);
        asm volatile("s_waitcnt lgkmcnt(0)" ::: "memory");
        __builtin_amdgcn_s_barrier();
        if (wid >= 4) asm volatile("s_sleep 4");  // de-phase co-resident waves
        for (int kk = 0; kk < 10; ++kk) {
            step(icg, 2 * kk, Be, Bo);
            step(icg, 2 * kk + 1, Bo, Be);
        }
        step(icg, 20, Be, Bo);
    }

    int colbase = nblk * 128 + wc * 64 + (lane & 15);
    const float inv = 1.f / 1024.f;  // A stored x16, B stored x64
#pragma unroll
    for (int mi = 0; mi < 7; ++mi) {
#pragma unroll
        for (int ni = 0; ni < 4; ++ni) {
            int col = colbase + ni * 16;
            float bs = bias[col];
#pragma unroll
            for (int r = 0; r < 4; ++r) {
                int ml = wr * 96 + mi * 16 + (lane >> 4) * 4 + r;
                float v = acc[mi][ni][r] * inv + bs;
                v = v > 0.f ? v : 0.f;
                out[((long)b * 400 + ml) * 256 + col] = __float2bfloat16(v);
            }
        }
    }
}

// ---------------- conv3: implicit-GEMM 128x128 (split-K), ring-3, counted vmcnt, bf16 partials ----------------
__global__ __launch_bounds__(256) void conv_mfma_kernel(const __hip_bfloat16* __restrict__ in,
                                                        const __hip_bfloat16* __restrict__ wp,
                                                        const float* __restrict__ bias,
                                                        __hip_bfloat16* __restrict__ out,
                                                        __hip_bfloat16* __restrict__ part,
                                                        int Win, int imgStride, int HWout, int Wout,
                                                        int nkyx, int Mtot, int mode) {
    __shared__ __hip_bfloat16 Ald[3 * 4096];
    __shared__ __hip_bfloat16 Bld[3 * 4096];
    int mblk = blockIdx.x, nblk = blockIdx.y;
    int kyx0 = blockIdx.z * nkyx;
    int t = threadIdx.x;
    int lane = t & 63, wid = t >> 6;
    int swz = ((t & 3) ^ ((t >> 3) & 3)) * 8;
    int icsrc = swz;
    long bsrc = (t >> 2) * 32 + swz;

    long base0, base1;
    {
        int m = mblk * 128 + (t >> 2);
        int b = m / HWout; int rem = m - b * HWout;
        int oyy = rem / Wout; int oxx = rem - oyy * Wout;
        base0 = (long)b * imgStride + (long)(2 * oyy * Win + 2 * oxx) * 256;
        m += 64;
        b = m / HWout; rem = m - b * HWout;
        oyy = rem / Wout; oxx = rem - oyy * Wout;
        base1 = (long)b * imgStride + (long)(2 * oyy * Win + 2 * oxx) * 256;
    }

    f32x4 acc[4][4];
#pragma unroll
    for (int i = 0; i < 4; ++i)
#pragma unroll
        for (int j2 = 0; j2 < 4; ++j2) acc[i][j2] = (f32x4){0.f, 0.f, 0.f, 0.f};

    int wr = wid >> 1, wc = wid & 1;
    int slot8 = (((lane >> 4) ^ ((lane >> 1) & 3))) * 8;
    int a_off = ((wr * 64 + (lane & 15)) * 32 + slot8) * 2;
    int b_off = ((wc * 64 + (lane & 15)) * 32 + slot8) * 2;

    auto stage = [&](int s, int buf) {
        int kyx = kyx0 + (s >> 3);
        int icg = s & 7;
        int ky = kyx / 9, kx = kyx - ky * 9;
        long offA = (long)(ky * Win + kx) * 256 + icg * 32 + icsrc;
        long btb = (long)((kyx * 8 + icg) * 2 + nblk) * 4096 + bsrc;
        char* a0 = (char*)Ald + buf * 8192 + wid * 1024;
        char* b0 = (char*)Bld + buf * 8192 + wid * 1024;
        gload16(in + base0 + offA, a0);
        gload16(in + base1 + offA, a0 + 4096);
        gload16(wp + btb, b0);
        gload16(wp + btb + 2048, b0 + 4096);
    };

    int nsteps = nkyx * 8;
    stage(0, 0);
    stage(1, 1);
    stage(2, 2);
    int cur = 0;
    for (int s = 0; s < nsteps; ++s) {
        int rem = nsteps - 1 - s;
        if (rem >= 2) {
            asm volatile("s_waitcnt vmcnt(8)" ::: "memory");
        } else if (rem == 1) {
            asm volatile("s_waitcnt vmcnt(4)" ::: "memory");
        } else {
            asm volatile("s_waitcnt vmcnt(0)" ::: "memory");
        }
        __builtin_amdgcn_s_barrier();
        __builtin_amdgcn_sched_barrier(0);
        const char* Ac = (const char*)Ald + cur * 8192;
        const char* Bc = (const char*)Bld + cur * 8192;
        bf16x8 af[4], bfr[4];
#pragma unroll
        for (int i = 0; i < 4; ++i) af[i] = *(const bf16x8*)(Ac + a_off + i * 1024);
#pragma unroll
        for (int i = 0; i < 4; ++i) bfr[i] = *(const bf16x8*)(Bc + b_off + i * 1024);
#pragma unroll
        for (int mi = 0; mi < 4; ++mi)
#pragma unroll
            for (int ni = 0; ni < 4; ++ni)
                acc[mi][ni] = __builtin_amdgcn_mfma_f32_16x16x32_bf16(af[mi], bfr[ni], acc[mi][ni], 0, 0, 0);
        if (s + 3 < nsteps) {
            asm volatile("s_waitcnt lgkmcnt(0)" ::: "memory");
            __builtin_amdgcn_s_barrier();
            stage(s + 3, cur);
        }
        cur = (cur == 2) ? 0 : cur + 1;
    }

    int colbase = nblk * 128 + wc * 64 + (lane & 15);
    long mrowbase = (long)mblk * 128 + wr * 64 + (lane >> 4) * 4;
    if (mode == 0) {
#pragma unroll
        for (int mi = 0; mi < 4; ++mi) {
#pragma unroll
            for (int ni = 0; ni < 4; ++ni) {
                int col = colbase + ni * 16;
                float bs = bias[col];
#pragma unroll
                for (int r = 0; r < 4; ++r) {
                    long mrow = mrowbase + mi * 16 + r;
                    float v = acc[mi][ni][r] + bs;
                    v = v > 0.f ? v : 0.f;
                    out[mrow * 256 + col] = __float2bfloat16(v);
                }
            }
        }
    } else {
        __hip_bfloat16* pp = part + (long)blockIdx.z * Mtot * 256;
#pragma unroll
        for (int mi = 0; mi < 4; ++mi) {
#pragma unroll
            for (int ni = 0; ni < 4; ++ni) {
                int col = colbase + ni * 16;
#pragma unroll
                for (int r = 0; r < 4; ++r) {
                    long mrow = mrowbase + mi * 16 + r;
                    pp[mrow * 256 + col] = __float2bfloat16(acc[mi][ni][r]);
                }
            }
        }
    }
}

// ---------------- split-K reduce: sum 9 bf16 partials + bias + relu -> bf16 NHWC ----------------
__global__ __launch_bounds__(256) void reduce_parts_kernel(const __hip_bfloat16* __restrict__ part,
                                                           const float* __restrict__ bias,
                                                           __hip_bfloat16* __restrict__ out) {
    int idx = blockIdx.x * 256 + threadIdx.x;  // 4608*256
    float s = 0.f;
#pragma unroll
    for (int p = 0; p < 9; ++p) s += __bfloat162float(part[(long)p * 1179648 + idx]);
    s += bias[idx & 255];
    s = s > 0.f ? s : 0.f;
    out[idx] = __float2bfloat16(s);
}

// ---------------- primary capsule squash: NHWC bf16 -> uT f32 [1152 i][128 b][8 d] ----------------
__global__ __launch_bounds__(256) void squash_caps_kernel(const __hip_bfloat16* __restrict__ c3,
                                                          float* __restrict__ uT) {
    int g = blockIdx.x * 256 + threadIdx.x;  // 147456 = 1152*128, i-major
    int i = g >> 7, b = g & 127;
    float val[8];
    float sn = 0.f;
#pragma unroll
    for (int d = 0; d < 8; ++d) {
        int flat = i * 8 + d;
        int c = flat / 36; int rem = flat - c * 36;
        int y = rem / 6; int xx = rem - y * 6;
        float vv = __bfloat162float(c3[((b * 6 + y) * 6 + xx) * 256 + c]);
        val[d] = vv;
        sn += vv * vv;
    }
    float sc = (sn / (1.f + sn)) / sqrtf(sn + 1e-8f);
#pragma unroll
    for (int d = 0; d < 8; ++d) uT[(long)g * 8 + d] = val[d] * sc;
}

// ---------------- u_hat[b,j,i,o] = sum_d uT[i,b,d] * W[j,i,d,o] ----------------
__global__ __launch_bounds__(256) void uhat_kernel(const float* __restrict__ uT,
                                                   const float* __restrict__ Wd,
                                                   __hip_bfloat16* __restrict__ uhat) {
    __shared__ float Wl2[1600];  // [jo=160][10]
    __shared__ float ul[1024];   // [b=128][8]
    int i = blockIdx.x, t = threadIdx.x;
    for (int idx = t; idx < 1280; idx += 256) {
        int j = idx >> 7, rest = idx & 127;
        int d = rest >> 4, o = rest & 15;
        Wl2[(j * 16 + o) * 10 + d] = Wd[((long)j * 1152 + i) * 128 + rest];
    }
    {
        const float4* usrc = (const float4*)(uT + (long)i * 1024);
        float4* ud = (float4*)ul;
        ud[t] = usrc[t];
    }
    __syncthreads();
    int b = (t >= 160) ? 1 : 0;
    int jo = (t >= 160) ? t - 160 : t;
    for (int rr = 0; rr < 80; ++rr) {
        const float* up = &ul[b * 8];
        const float* wq = &Wl2[jo * 10];
        float a = 0.f;
#pragma unroll
        for (int d = 0; d < 8; ++d) a += up[d] * wq[d];
        int j = jo >> 4, o = jo & 15;
        uhat[(((long)b * 10 + j) * 1152 + i) * 16 + o] = __float2bfloat16(a);
        jo += 96; b += 1;
        if (jo >= 160) { jo -= 160; b += 1; }
    }
}

// ---------------- fused dynamic routing per (b,j): 3 iterations in LDS ----------------
__global__ __launch_bounds__(256) void routing_kernel(const __hip_bfloat16* __restrict__ uhat,
                                                      const float* __restrict__ bdig,
                                                      float* __restrict__ vout,
                                                      float* __restrict__ vws) {
    __shared__ __hip_bfloat16 uh[1152 * 16];
    __shared__ float barr[1152];
    __shared__ float red[16];
    __shared__ float accb[16 * 256];
    __shared__ float svec[16];
    __shared__ float vsc[16];
    int bid = blockIdx.x;  // b*10 + j
    int j = bid % 10;
    int t = threadIdx.x;
    int wid = t >> 6;
    const uint4* srcp = (const uint4*)(uhat + (long)bid * 18432);
    uint4* dstp = (uint4*)uh;
    for (int idx = t; idx < 2304; idx += 256) dstp[idx] = srcp[idx];
    for (int idx = t; idx < 1152; idx += 256) barr[idx] = 0.f;
    __syncthreads();
    for (int it = 0; it < 3; ++it) {
        float lm = -1e30f;
        for (int i = t; i < 1152; i += 256) lm = fmaxf(lm, barr[i]);
#pragma unroll
        for (int m2 = 32; m2; m2 >>= 1) lm = fmaxf(lm, __shfl_xor(lm, m2));
        if ((t & 63) == 0) red[wid] = lm;
        __syncthreads();
        float mx = fmaxf(fmaxf(red[0], red[1]), fmaxf(red[2], red[3]));
        float le = 0.f;
        float a16[16];
#pragma unroll
        for (int o = 0; o < 16; ++o) a16[o] = 0.f;
        for (int i = t; i < 1152; i += 256) {
            float e = __expf(barr[i] - mx);
            le += e;
            const uint4* up = (const uint4*)(uh + i * 16);
            union { uint4 q; unsigned short s[8]; } U0, U1;
            U0.q = up[0]; U1.q = up[1];
#pragma unroll
            for (int o = 0; o < 8; ++o) a16[o] += e * bfu(U0.s[o]);
#pragma unroll
            for (int o = 0; o < 8; ++o) a16[8 + o] += e * bfu(U1.s[o]);
        }
#pragma unroll
        for (int m2 = 32; m2; m2 >>= 1) le += __shfl_xor(le, m2);
        if ((t & 63) == 0) red[4 + wid] = le;
#pragma unroll
        for (int o = 0; o < 16; ++o) accb[o * 256 + t] = a16[o];
        __syncthreads();
        float sume = red[4] + red[5] + red[6] + red[7];
        int g = t >> 4, tin = t & 15;
        float s = 0.f;
#pragma unroll
        for (int k = 0; k < 16; ++k) s += accb[g * 256 + tin + 16 * k];
#pragma unroll
        for (int m2 = 8; m2; m2 >>= 1) s += __shfl_xor(s, m2);
        if (tin == 0) svec[g] = s / sume + bdig[j * 16 + g];
        __syncthreads();
        if (t < 16) {
            float sv = svec[t];
            float sn = sv * sv;
#pragma unroll
            for (int m2 = 8; m2; m2 >>= 1) sn += __shfl_xor(sn, m2);
            float sc = (sn / (1.f + sn)) / sqrtf(sn + 1e-8f);
            float v = sv * sc;
            vsc[t] = v;
            if (it == 2) { vout[bid * 16 + t] = v; vws[bid * 16 + t] = v; }
        }
        __syncthreads();
        if (it < 2) {
            for (int i = t; i < 1152; i += 256) {
                const uint4* up = (const uint4*)(uh + i * 16);
                union { uint4 q; unsigned short s[8]; } U0, U1;
                U0.q = up[0]; U1.q = up[1];
                float dot = 0.f;
#pragma unroll
                for (int o = 0; o < 8; ++o) dot += vsc[o] * bfu(U0.s[o]);
#pragma unroll
                for (int o = 0; o < 8; ++o) dot += vsc[8 + o] * bfu(U1.s[o]);
                barr[i] += dot;
            }
            __syncthreads();
        }
    }
}

// ---------------- reconstruction GEMM, latency-proof ----------------
__global__ __launch_bounds__(256) void rec_gemm_kernel(const float* __restrict__ A,
                                                       const float* __restrict__ W,
                                                       const float* __restrict__ bias,
                                                       float* __restrict__ out,
                                                       int K, int N, int act) {
    __shared__ __align__(16) float As[2][2048];
    int n0 = blockIdx.x * 64;
    int bch = blockIdx.y * 32;
    int t = threadIdx.x;
    int n_l = t & 63, bh = t >> 6;
    const float* Wc = W + n0 + n_l;
    float acc[8];
#pragma unroll
    for (int i = 0; i < 8; ++i) acc[i] = 0.f;
    int T = (K + 63) >> 6;

    auto stageA = [&](int tile, int buf) {
        int k0 = tile << 6;
        for (int idx = t; idx < 2048; idx += 256) {
            int bb = idx >> 6, kk = idx & 63;
            As[buf][idx] = (k0 + kk < K) ? A[(long)(bch + bb) * K + k0 + kk] : 0.f;
        }
    };
    auto ldW = [&](int tile, float* w) {
        int k0 = tile << 6;
#pragma unroll
        for (int j = 0; j < 64; ++j) {
            int kr = k0 + j;
            if (kr >= K) kr = K - 1;
            w[j] = Wc[(long)kr * N];
        }
    };
    auto compute = [&](const float* w, int buf) {
#pragma unroll
        for (int bb = 0; bb < 8; ++bb) {
            const float4* ap = (const float4*)&As[buf][(bh * 8 + bb) * 64];
            float s = 0.f;
#pragma unroll
            for (int q = 0; q < 16; ++q) {
                float4 a = ap[q];
                s += a.x * w[q * 4] + a.y * w[q * 4 + 1] + a.z * w[q * 4 + 2] + a.w * w[q * 4 + 3];
            }
            acc[bb] += s;
        }
    };

    float wA[64], wB[64];
    ldW(0, wA);
    stageA(0, 0);
    __syncthreads();
    for (int tile = 0; tile < T; tile += 2) {
        if (tile + 1 < T) { ldW(tile + 1, wB); stageA(tile + 1, 1); }
        compute(wA, 0);
        __syncthreads();
        if (tile + 1 < T) {
            if (tile + 2 < T) { ldW(tile + 2, wA); stageA(tile + 2, 0); }
            compute(wB, 1);
            __syncthreads();
        }
    }

    float bs = bias[n0 + n_l];
#pragma unroll
    for (int bb = 0; bb < 8; ++bb) {
        float x = acc[bb] + bs;
        float r;
        if (act == 0) r = x > 0.f ? x : 0.f;
        else r = 1.f / (1.f + __expf(-x));
        out[(long)(bch + bh * 8 + bb) * N + n0 + n_l] = r;
    }
}

extern "C" void kernel_launch(void* const* d_in, const int* in_sizes, int n_in,
                              void* d_out, int out_size, void* d_ws, size_t ws_size,
                              hipStream_t stream) {
    const float* x   = (const float*)d_in[0];
    const float* c1w = (const float*)d_in[1];
    const float* c1b = (const float*)d_in[2];
    const float* c2w = (const float*)d_in[3];
    const float* c2b = (const float*)d_in[4];
    const float* pw  = (const float*)d_in[5];
    const float* pb  = (const float*)d_in[6];
    const float* Wd  = (const float*)d_in[7];
    const float* bd  = (const float*)d_in[8];
    const float* rw1 = (const float*)d_in[9];
    const float* rb1 = (const float*)d_in[10];
    const float* rw2 = (const float*)d_in[11];
    const float* rb2 = (const float*)d_in[12];
    const float* rw3 = (const float*)d_in[13];
    const float* rb3 = (const float*)d_in[14];
    float* outp = (float*)d_out;

    char* ws = (char*)d_ws;
    size_t off = 0;
    auto alloc = [&](size_t bytes) {
        char* p = ws + off;
        off += (bytes + 255) & ~(size_t)255;
        return p;
    };
    unsigned char* c1f8  = (unsigned char*)alloc(75497472UL);   // [128][48][48][256] fp8 (x16)
    __hip_bfloat16* c2out = (__hip_bfloat16*)alloc(26214400UL); // [128][20][20][256] bf16
    __hip_bfloat16* c3out = (__hip_bfloat16*)alloc(2359296UL);  // [128][6][6][256]
    __hip_bfloat16* w3p   = (__hip_bfloat16*)alloc(10616832UL);
    unsigned char* wq2    = (unsigned char*)alloc(5505024UL);   // [8][21][2][128][128] fp8 (x64)
    __hip_bfloat16* xb    = (__hip_bfloat16*)alloc(802816UL);   // [128][56][56] bf16
    __hip_bfloat16* wb    = (__hip_bfloat16*)alloc(49152UL);    // [12][256][8] bf16
    float* uT    = (float*)alloc(4718592UL);    // [1152][128][8] f32
    __hip_bfloat16* uhat = (__hip_bfloat16*)alloc(47185920UL);  // [128][10][1152][16] bf16
    float* vws   = (float*)alloc(81920UL);      // [128][160]
    float* rec1  = (float*)alloc(262144UL);     // [128][512]
    float* rec2  = (float*)alloc(524288UL);     // [128][1024]

    // conv3 split-K bf16 partials [9][4608][256] alias the (later-written) uhat buffer
    __hip_bfloat16* c3part = (__hip_bfloat16*)uhat;

    prep_w_kernel<<<1241, 256, 0, stream>>>(pw, w3p, c1w, wb, x, xb, c2w, wq2);
    conv1_mfma_kernel<<<3072, 256, 0, stream>>>(xb, wb, c1b, c1f8);
    conv2_fp8_kernel<<<256, 512, 0, stream>>>(c1f8, wq2, c2b, c2out);
    conv_mfma_kernel<<<dim3(36, 2, 9), 256, 0, stream>>>(c2out, w3p, pb, c3out, c3part,
                                                         20, 20 * 20 * 256, 36, 6, 9, 4608, 1);
    reduce_parts_kernel<<<4608, 256, 0, stream>>>(c3part, pb, c3out);
    squash_caps_kernel<<<576, 256, 0, stream>>>(c3out, uT);
    uhat_kernel<<<1152, 256, 0, stream>>>(uT, Wd, uhat);
    routing_kernel<<<1280, 256, 0, stream>>>(uhat, bd, outp, vws);
    rec_gemm_kernel<<<dim3(8, 4), 256, 0, stream>>>(vws, rw1, rb1, rec1, 160, 512, 0);
    rec_gemm_kernel<<<dim3(16, 4), 256, 0, stream>>>(rec1, rw2, rb2, rec2, 512, 1024, 0);
    rec_gemm_kernel<<<dim3(49, 4), 256, 0, stream>>>(rec2, rw3, rb3, outp + 20480, 1024, 3136, 1);
}

// Round 18
// 775.913 us; speedup vs baseline: 2.0119x; 1.0119x over previous
//
#include <hip/hip_runtime.h>
#include <hip/hip_bf16.h>

typedef float f32x4 __attribute__((ext_vector_type(4)));
typedef __bf16 bf16x8 __attribute__((ext_vector_type(8)));
typedef __bf16 bf16x4 __attribute__((ext_vector_type(4)));
typedef int i32x8 __attribute__((ext_vector_type(8)));

#define AS1 __attribute__((address_space(1)))
#define AS3 __attribute__((address_space(3)))

__device__ __forceinline__ void gload16(const void* g, void* l) {
    __builtin_amdgcn_global_load_lds((AS1 unsigned int*)g, (AS3 unsigned int*)l, 16, 0, 0);
}

__device__ __forceinline__ float bfu(unsigned short u) {
    return __uint_as_float((unsigned)u << 16);
}

// float -> fp8 e4m3 (OCP), truncating, signed, flush-to-zero below 2^-6, clamp 448
__device__ __forceinline__ unsigned char f2e4m3s(float f) {
    unsigned u = __float_as_uint(f);
    unsigned s = (u >> 24) & 0x80;
    unsigned ua = u & 0x7fffffffu;
    int e = (int)(ua >> 23) - 127;
    unsigned m = (ua >> 20) & 7;
    if (e < -6) return (unsigned char)s;
    if (e > 8 || (e == 8 && m > 6)) return (unsigned char)(s | 0x7e);
    return (unsigned char)(s | ((unsigned)(e + 7) << 3) | m);
}

// ---------------- prep: [0,512) conv3 w -> bf16 table; 512: conv1 wb; [513,905) x->bf16;
// [905,1417) conv2 w -> fp8 table [icg][21 ks][nblk][128 oc][128 kb] (x64, coalesced via LDS) ----------------
__global__ __launch_bounds__(256) void prep_w_kernel(const float* __restrict__ pw,
                                                     __hip_bfloat16* __restrict__ w3p,
                                                     const float* __restrict__ c1w,
                                                     __hip_bfloat16* __restrict__ wb,
                                                     const float* __restrict__ x,
                                                     __hip_bfloat16* __restrict__ xb,
                                                     const float* __restrict__ c2w,
                                                     unsigned char* __restrict__ wq2) {
    int bid = blockIdx.x;
    int t = threadIdx.x;
    if (bid == 512) {  // conv1 weight table
        float tmp[81];
#pragma unroll
        for (int k = 0; k < 81; ++k) tmp[k] = c1w[t * 81 + k];
#pragma unroll
        for (int ks = 0; ks < 9; ++ks)
#pragma unroll
            for (int e = 0; e < 8; ++e)
                wb[(ks * 256 + t) * 8 + e] = __float2bfloat16(tmp[ks * 9 + e]);
#pragma unroll
        for (int e = 0; e < 8; ++e)
            wb[(9 * 256 + t) * 8 + e] = __float2bfloat16(tmp[e * 9 + 8]);
        wb[(10 * 256 + t) * 8 + 0] = __float2bfloat16(tmp[80]);
#pragma unroll
        for (int e = 1; e < 8; ++e) wb[(10 * 256 + t) * 8 + e] = __float2bfloat16(0.f);
#pragma unroll
        for (int e = 0; e < 8; ++e) wb[(11 * 256 + t) * 8 + e] = __float2bfloat16(0.f);
        return;
    }
    if (bid >= 513 && bid < 905) {  // x -> bf16
        long i4 = (long)(bid - 513) * 1024 + t * 4;
        float4 v = *(const float4*)(x + i4);
        bf16x4 o = {(__bf16)v.x, (__bf16)v.y, (__bf16)v.z, (__bf16)v.w};
        *(bf16x4*)((__bf16*)xb + i4) = o;
        return;
    }
    if (bid >= 905) {  // conv2 fp8 table, coalesced via LDS
        __shared__ float wl[4 * 2592];  // [4 oc][32 ic][81 kyx]
        int b2 = bid - 905;
        int icg = b2 & 7;
        int oc4 = (b2 >> 3) & 31;
        int nblk = b2 >> 8;
        for (int f = t; f < 4 * 2592; f += 256) {
            int o = f / 2592;
            int rest = f - o * 2592;
            wl[f] = c2w[(long)(nblk * 128 + oc4 * 4 + o) * 20736 + icg * 2592 + rest];
        }
        __syncthreads();
        long base = (long)icg * 688128 + (long)nblk * 16384 + (oc4 * 4) * 128;
        for (int idx = t; idx < 4 * 21 * 128; idx += 256) {
            int o = idx / 2688;
            int rem = idx - o * 2688;
            int ks = rem >> 7, kb = rem & 127;
            int kq = kb >> 5, icl = kb & 31;
            int kyx = ks * 4 + kq;
            float v = (kyx < 81) ? wl[o * 2592 + icl * 81 + kyx] * 64.f : 0.f;
            wq2[base + (long)ks * 32768 + o * 128 + kb] = f2e4m3s(v);
        }
        return;
    }
    // conv3 weights -> bf16 [kyx][icg][nblk][oc128][ic32]
    __shared__ float wl3[4 * 32 * 81];
    int icg = bid & 7;
    int oc4 = (bid >> 3) & 31;
    int nblk = bid >> 8;
    int ocg0 = nblk * 128 + oc4 * 4;
    int ic0 = icg * 32;
    for (int f = t; f < 4 * 2592; f += 256) {
        int o = f / 2592;
        int rest = f - o * 2592;
        wl3[f] = pw[(ocg0 + o) * 20736 + ic0 * 81 + rest];
    }
    __syncthreads();
    for (int idx = t; idx < 81 * 128; idx += 256) {
        int kyx = idx >> 7;
        int o = (idx >> 5) & 3;
        int i = idx & 31;
        long dst = (long)(((kyx * 8 + icg) * 2 + nblk) * 128 + (oc4 * 4 + o)) * 32 + i;
        w3p[dst] = __float2bfloat16(wl3[o * 2592 + i * 81 + kyx]);
    }
}

// ---------------- conv1 as bf16 MFMA implicit-GEMM, writes fp8 (x16 pre-scale) ----------------
__global__ __launch_bounds__(256) void conv1_mfma_kernel(const __hip_bfloat16* __restrict__ xb,
                                                         const __hip_bfloat16* __restrict__ wb,
                                                         const float* __restrict__ bias,
                                                         unsigned char* __restrict__ out) {
    __shared__ __bf16 Asl[640];  // [10 rows][64 cols]
    int bid = blockIdx.x;
    int b = bid / 24, mb2 = bid - b * 24;
    int oy0 = mb2 * 2;
    int t = threadIdx.x;
    int lane = t & 63, wc = t >> 6;
    int q = lane >> 4;

    const __bf16* src = (const __bf16*)xb + b * 3136 + oy0 * 56;
    for (int idx = t; idx < 640; idx += 256) {
        int iy = idx >> 6, col = idx & 63;
        Asl[idx] = (col < 56) ? src[iy * 56 + col] : (__bf16)0.f;
    }

    bf16x8 Bf[3][4];
#pragma unroll
    for (int s = 0; s < 3; ++s)
#pragma unroll
        for (int ni = 0; ni < 4; ++ni) {
            int col = wc * 64 + ni * 16 + (lane & 15);
            Bf[s][ni] = *(const bf16x8*)(wb + ((s * 4 + q) * 256 + col) * 8);
        }

    f32x4 acc[6][4];
#pragma unroll
    for (int i = 0; i < 6; ++i)
#pragma unroll
        for (int j = 0; j < 4; ++j) acc[i][j] = (f32x4){0.f, 0.f, 0.f, 0.f};

    __syncthreads();

#pragma unroll
    for (int s = 0; s < 3; ++s) {
        int ks = s * 4 + q;
        bf16x8 af[6];
#pragma unroll
        for (int mi = 0; mi < 6; ++mi) {
            int r = mi * 16 + (lane & 15);
            int oyl = (r >= 48) ? 1 : 0;
            int ox = r - 48 * oyl;
            bf16x8 v;
            if (ks < 9) {
                __builtin_memcpy(&v, &Asl[(oyl + ks) * 64 + ox], 16);
            } else if (ks == 9) {
#pragma unroll
                for (int e = 0; e < 8; ++e) v[e] = Asl[(oyl + e) * 64 + ox + 8];
            } else if (ks == 10) {
#pragma unroll
                for (int e = 0; e < 8; ++e) v[e] = (__bf16)0.f;
                v[0] = Asl[(oyl + 8) * 64 + ox + 8];
            } else {
#pragma unroll
                for (int e = 0; e < 8; ++e) v[e] = (__bf16)0.f;
            }
            af[mi] = v;
        }
#pragma unroll
        for (int mi = 0; mi < 6; ++mi)
#pragma unroll
            for (int ni = 0; ni < 4; ++ni)
                acc[mi][ni] = __builtin_amdgcn_mfma_f32_16x16x32_bf16(af[mi], Bf[s][ni], acc[mi][ni], 0, 0, 0);
    }

    long m0 = (long)b * 2304 + mb2 * 96;
#pragma unroll
    for (int mi = 0; mi < 6; ++mi)
#pragma unroll
        for (int ni = 0; ni < 4; ++ni) {
            int col = wc * 64 + ni * 16 + (lane & 15);
            float bs = bias[col];
#pragma unroll
            for (int r2 = 0; r2 < 4; ++r2) {
                int row = mi * 16 + q * 4 + r2;
                float vv = acc[mi][ni][r2] + bs;
                vv = vv > 0.f ? vv : 0.f;
                out[(m0 + row) * 256 + col] = f2e4m3s(vv * 16.f);
            }
        }
}

// ---------------- conv2: MX-fp8 (K=128), LDS fp8 im2col [48][49][32ch] with 16B-slot XOR swizzle
// (slot' = slot ^ ((slot>>3)&7), conflict-free), barrier-free K-loop, B table -> reg dbuf ----------------
__global__ __launch_bounds__(512, 2) void conv2_fp8_kernel(const unsigned char* __restrict__ in,
                                                           const unsigned char* __restrict__ wq,
                                                           const float* __restrict__ bias,
                                                           __hip_bfloat16* __restrict__ out) {
    __shared__ unsigned char Ald[75264];   // 4704 16B-slots, swizzled
    int bid = blockIdx.x;
    int wg = (bid & 7) * 32 + (bid >> 3);  // XCD-chunk
    int b = wg >> 1, nblk = wg & 1;
    int t = threadIdx.x;
    int lane = t & 63, wid = t >> 6;
    int wr = wid >> 1, wc = wid & 1;       // 4 M x 2 N waves
    int kq = lane >> 4;

    const unsigned char* imgbase = in + (long)b * (48 * 48 * 256);
    const unsigned char* wqn = wq + ((long)(nblk * 128 + wc * 64 + (lane & 15))) * 128 + kq * 32;

    int qslot[7];  // base 16B-slot of each mi's output pixel
#pragma unroll
    for (int mi = 0; mi < 7; ++mi) {
        int ml = wr * 96 + mi * 16 + (lane & 15);
        int oy = ml / 20, ox = ml - oy * 20;
        qslot[mi] = ((2 * oy) * 49 + 2 * ox) * 2;
    }

    f32x4 acc[7][4];
#pragma unroll
    for (int i = 0; i < 7; ++i)
#pragma unroll
        for (int j = 0; j < 4; ++j) acc[i][j] = (f32x4){0.f, 0.f, 0.f, 0.f};

    auto stageA = [&](int icg) {
#pragma unroll 3
        for (int j = 0; j < 9; ++j) {
            int gi = t + j * 512;                 // 16B-slot in [48][48][2] linear order
            int row32 = gi >> 1, half = gi & 1;
            int iy = row32 / 48, col = row32 - iy * 48;
            uint4 v = *(const uint4*)(imgbase + ((long)(iy * 48 + col) * 256 + icg * 32 + half * 16));
            int slot = (iy * 49 + col) * 2 + half;
            int phys = slot ^ ((slot >> 3) & 7);
            *(uint4*)(Ald + phys * 16) = v;
        }
    };

    union U8 { uint4 q[2]; i32x8 v; };
    i32x8 Be[4], Bo[4];
    auto loadB = [&](i32x8* dst, int icg, int ks) {
        const unsigned char* p = wqn + (long)icg * 688128 + (long)ks * 32768;
        uint4* d = (uint4*)dst;
#pragma unroll
        for (int ni = 0; ni < 4; ++ni) {
            d[ni * 2]     = *(const uint4*)(p + ni * 2048);
            d[ni * 2 + 1] = *(const uint4*)(p + ni * 2048 + 16);
        }
    };

    auto step = [&](int icg, int ks, i32x8* Bcur, i32x8* Bnxt) {
        if (ks + 1 < 21) loadB(Bnxt, icg, ks + 1);
        int kyx = ks * 4 + kq;
        int ky = kyx / 9;
        int sdel = (kyx + 40 * ky) * 2;   // slot offset: (ky*49+kx)*2
        __builtin_amdgcn_s_setprio(1);
#pragma unroll
        for (int mi = 0; mi < 7; ++mi) {
            int s0 = qslot[mi] + sdel;
            int p0 = s0 ^ ((s0 >> 3) & 7);
            int s1 = s0 + 1;
            int p1 = s1 ^ ((s1 >> 3) & 7);
            U8 a;
            a.q[0] = *(const uint4*)(Ald + p0 * 16);
            a.q[1] = *(const uint4*)(Ald + p1 * 16);
#pragma unroll
            for (int ni = 0; ni < 4; ++ni)
                acc[mi][ni] = __builtin_amdgcn_mfma_scale_f32_16x16x128_f8f6f4(
                    a.v, Bcur[ni], acc[mi][ni],
                    0, 0,                      // cbsz, blgp = fp8-e4m3
                    0, 0x7F7F7F7F,             // opsel_a, scale_a (127 -> 2^0)
                    0, 0x7F7F7F7F);            // opsel_b, scale_b
        }
        __builtin_amdgcn_s_setprio(0);
    };

    for (int icg = 0; icg < 8; ++icg) {
        if (icg) __builtin_amdgcn_s_barrier();   // all waves done reading old A
        loadB(Be, icg, 0);
        stageA(icg);
        asm volatile("s_waitcnt lgkmcnt(0)" ::: "memory");
        __builtin_amdgcn_s_barrier();
        if (wid >= 4) asm volatile("s_sleep 4");  // de-phase co-resident waves
        for (int kk = 0; kk < 10; ++kk) {
            step(icg, 2 * kk, Be, Bo);
            step(icg, 2 * kk + 1, Bo, Be);
        }
        step(icg, 20, Be, Bo);
    }

    int colbase = nblk * 128 + wc * 64 + (lane & 15);
    const float inv = 1.f / 1024.f;  // A x16, B x64
#pragma unroll
    for (int mi = 0; mi < 7; ++mi) {
#pragma unroll
        for (int ni = 0; ni < 4; ++ni) {
            int col = colbase + ni * 16;
            float bs = bias[col];
#pragma unroll
            for (int r = 0; r < 4; ++r) {
                int ml = wr * 96 + mi * 16 + (lane >> 4) * 4 + r;
                float v = acc[mi][ni][r] * inv + bs;
                v = v > 0.f ? v : 0.f;
                out[((long)b * 400 + ml) * 256 + col] = __float2bfloat16(v);
            }
        }
    }
}

// ---------------- conv3: implicit-GEMM 128x128 (split-K), ring-3, counted vmcnt, bf16 partials ----------------
__global__ __launch_bounds__(256) void conv_mfma_kernel(const __hip_bfloat16* __restrict__ in,
                                                        const __hip_bfloat16* __restrict__ wp,
                                                        const float* __restrict__ bias,
                                                        __hip_bfloat16* __restrict__ out,
                                                        __hip_bfloat16* __restrict__ part,
                                                        int Win, int imgStride, int HWout, int Wout,
                                                        int nkyx, int Mtot, int mode) {
    __shared__ __hip_bfloat16 Ald[3 * 4096];
    __shared__ __hip_bfloat16 Bld[3 * 4096];
    int mblk = blockIdx.x, nblk = blockIdx.y;
    int kyx0 = blockIdx.z * nkyx;
    int t = threadIdx.x;
    int lane = t & 63, wid = t >> 6;
    int swz = ((t & 3) ^ ((t >> 3) & 3)) * 8;
    int icsrc = swz;
    long bsrc = (t >> 2) * 32 + swz;

    long base0, base1;
    {
        int m = mblk * 128 + (t >> 2);
        int b = m / HWout; int rem = m - b * HWout;
        int oyy = rem / Wout; int oxx = rem - oyy * Wout;
        base0 = (long)b * imgStride + (long)(2 * oyy * Win + 2 * oxx) * 256;
        m += 64;
        b = m / HWout; rem = m - b * HWout;
        oyy = rem / Wout; oxx = rem - oyy * Wout;
        base1 = (long)b * imgStride + (long)(2 * oyy * Win + 2 * oxx) * 256;
    }

    f32x4 acc[4][4];
#pragma unroll
    for (int i = 0; i < 4; ++i)
#pragma unroll
        for (int j2 = 0; j2 < 4; ++j2) acc[i][j2] = (f32x4){0.f, 0.f, 0.f, 0.f};

    int wr = wid >> 1, wc = wid & 1;
    int slot8 = (((lane >> 4) ^ ((lane >> 1) & 3))) * 8;
    int a_off = ((wr * 64 + (lane & 15)) * 32 + slot8) * 2;
    int b_off = ((wc * 64 + (lane & 15)) * 32 + slot8) * 2;

    auto stage = [&](int s, int buf) {
        int kyx = kyx0 + (s >> 3);
        int icg = s & 7;
        int ky = kyx / 9, kx = kyx - ky * 9;
        long offA = (long)(ky * Win + kx) * 256 + icg * 32 + icsrc;
        long btb = (long)((kyx * 8 + icg) * 2 + nblk) * 4096 + bsrc;
        char* a0 = (char*)Ald + buf * 8192 + wid * 1024;
        char* b0 = (char*)Bld + buf * 8192 + wid * 1024;
        gload16(in + base0 + offA, a0);
        gload16(in + base1 + offA, a0 + 4096);
        gload16(wp + btb, b0);
        gload16(wp + btb + 2048, b0 + 4096);
    };

    int nsteps = nkyx * 8;
    stage(0, 0);
    stage(1, 1);
    stage(2, 2);
    int cur = 0;
    for (int s = 0; s < nsteps; ++s) {
        int rem = nsteps - 1 - s;
        if (rem >= 2) {
            asm volatile("s_waitcnt vmcnt(8)" ::: "memory");
        } else if (rem == 1) {
            asm volatile("s_waitcnt vmcnt(4)" ::: "memory");
        } else {
            asm volatile("s_waitcnt vmcnt(0)" ::: "memory");
        }
        __builtin_amdgcn_s_barrier();
        __builtin_amdgcn_sched_barrier(0);
        const char* Ac = (const char*)Ald + cur * 8192;
        const char* Bc = (const char*)Bld + cur * 8192;
        bf16x8 af[4], bfr[4];
#pragma unroll
        for (int i = 0; i < 4; ++i) af[i] = *(const bf16x8*)(Ac + a_off + i * 1024);
#pragma unroll
        for (int i = 0; i < 4; ++i) bfr[i] = *(const bf16x8*)(Bc + b_off + i * 1024);
#pragma unroll
        for (int mi = 0; mi < 4; ++mi)
#pragma unroll
            for (int ni = 0; ni < 4; ++ni)
                acc[mi][ni] = __builtin_amdgcn_mfma_f32_16x16x32_bf16(af[mi], bfr[ni], acc[mi][ni], 0, 0, 0);
        if (s + 3 < nsteps) {
            asm volatile("s_waitcnt lgkmcnt(0)" ::: "memory");
            __builtin_amdgcn_s_barrier();
            stage(s + 3, cur);
        }
        cur = (cur == 2) ? 0 : cur + 1;
    }

    int colbase = nblk * 128 + wc * 64 + (lane & 15);
    long mrowbase = (long)mblk * 128 + wr * 64 + (lane >> 4) * 4;
    if (mode == 0) {
#pragma unroll
        for (int mi = 0; mi < 4; ++mi) {
#pragma unroll
            for (int ni = 0; ni < 4; ++ni) {
                int col = colbase + ni * 16;
                float bs = bias[col];
#pragma unroll
                for (int r = 0; r < 4; ++r) {
                    long mrow = mrowbase + mi * 16 + r;
                    float v = acc[mi][ni][r] + bs;
                    v = v > 0.f ? v : 0.f;
                    out[mrow * 256 + col] = __float2bfloat16(v);
                }
            }
        }
    } else {
        __hip_bfloat16* pp = part + (long)blockIdx.z * Mtot * 256;
#pragma unroll
        for (int mi = 0; mi < 4; ++mi) {
#pragma unroll
            for (int ni = 0; ni < 4; ++ni) {
                int col = colbase + ni * 16;
#pragma unroll
                for (int r = 0; r < 4; ++r) {
                    long mrow = mrowbase + mi * 16 + r;
                    pp[mrow * 256 + col] = __float2bfloat16(acc[mi][ni][r]);
                }
            }
        }
    }
}

// ---------------- split-K reduce ----------------
__global__ __launch_bounds__(256) void reduce_parts_kernel(const __hip_bfloat16* __restrict__ part,
                                                           const float* __restrict__ bias,
                                                           __hip_bfloat16* __restrict__ out) {
    int idx = blockIdx.x * 256 + threadIdx.x;
    float s = 0.f;
#pragma unroll
    for (int p = 0; p < 9; ++p) s += __bfloat162float(part[(long)p * 1179648 + idx]);
    s += bias[idx & 255];
    s = s > 0.f ? s : 0.f;
    out[idx] = __float2bfloat16(s);
}

// ---------------- primary capsule squash ----------------
__global__ __launch_bounds__(256) void squash_caps_kernel(const __hip_bfloat16* __restrict__ c3,
                                                          float* __restrict__ uT) {
    int g = blockIdx.x * 256 + threadIdx.x;
    int i = g >> 7, b = g & 127;
    float val[8];
    float sn = 0.f;
#pragma unroll
    for (int d = 0; d < 8; ++d) {
        int flat = i * 8 + d;
        int c = flat / 36; int rem = flat - c * 36;
        int y = rem / 6; int xx = rem - y * 6;
        float vv = __bfloat162float(c3[((b * 6 + y) * 6 + xx) * 256 + c]);
        val[d] = vv;
        sn += vv * vv;
    }
    float sc = (sn / (1.f + sn)) / sqrtf(sn + 1e-8f);
#pragma unroll
    for (int d = 0; d < 8; ++d) uT[(long)g * 8 + d] = val[d] * sc;
}

// ---------------- u_hat ----------------
__global__ __launch_bounds__(256) void uhat_kernel(const float* __restrict__ uT,
                                                   const float* __restrict__ Wd,
                                                   __hip_bfloat16* __restrict__ uhat) {
    __shared__ float Wl2[1600];
    __shared__ float ul[1024];
    int i = blockIdx.x, t = threadIdx.x;
    for (int idx = t; idx < 1280; idx += 256) {
        int j = idx >> 7, rest = idx & 127;
        int d = rest >> 4, o = rest & 15;
        Wl2[(j * 16 + o) * 10 + d] = Wd[((long)j * 1152 + i) * 128 + rest];
    }
    {
        const float4* usrc = (const float4*)(uT + (long)i * 1024);
        float4* ud = (float4*)ul;
        ud[t] = usrc[t];
    }
    __syncthreads();
    int b = (t >= 160) ? 1 : 0;
    int jo = (t >= 160) ? t - 160 : t;
    for (int rr = 0; rr < 80; ++rr) {
        const float* up = &ul[b * 8];
        const float* wq = &Wl2[jo * 10];
        float a = 0.f;
#pragma unroll
        for (int d = 0; d < 8; ++d) a += up[d] * wq[d];
        int j = jo >> 4, o = jo & 15;
        uhat[(((long)b * 10 + j) * 1152 + i) * 16 + o] = __float2bfloat16(a);
        jo += 96; b += 1;
        if (jo >= 160) { jo -= 160; b += 1; }
    }
}

// ---------------- fused dynamic routing ----------------
__global__ __launch_bounds__(256) void routing_kernel(const __hip_bfloat16* __restrict__ uhat,
                                                      const float* __restrict__ bdig,
                                                      float* __restrict__ vout,
                                                      float* __restrict__ vws) {
    __shared__ __hip_bfloat16 uh[1152 * 16];
    __shared__ float barr[1152];
    __shared__ float red[16];
    __shared__ float accb[16 * 256];
    __shared__ float svec[16];
    __shared__ float vsc[16];
    int bid = blockIdx.x;
    int j = bid % 10;
    int t = threadIdx.x;
    int wid = t >> 6;
    const uint4* srcp = (const uint4*)(uhat + (long)bid * 18432);
    uint4* dstp = (uint4*)uh;
    for (int idx = t; idx < 2304; idx += 256) dstp[idx] = srcp[idx];
    for (int idx = t; idx < 1152; idx += 256) barr[idx] = 0.f;
    __syncthreads();
    for (int it = 0; it < 3; ++it) {
        float lm = -1e30f;
        for (int i = t; i < 1152; i += 256) lm = fmaxf(lm, barr[i]);
#pragma unroll
        for (int m2 = 32; m2; m2 >>= 1) lm = fmaxf(lm, __shfl_xor(lm, m2));
        if ((t & 63) == 0) red[wid] = lm;
        __syncthreads();
        float mx = fmaxf(fmaxf(red[0], red[1]), fmaxf(red[2], red[3]));
        float le = 0.f;
        float a16[16];
#pragma unroll
        for (int o = 0; o < 16; ++o) a16[o] = 0.f;
        for (int i = t; i < 1152; i += 256) {
            float e = __expf(barr[i] - mx);
            le += e;
            const uint4* up = (const uint4*)(uh + i * 16);
            union { uint4 q; unsigned short s[8]; } U0, U1;
            U0.q = up[0]; U1.q = up[1];
#pragma unroll
            for (int o = 0; o < 8; ++o) a16[o] += e * bfu(U0.s[o]);
#pragma unroll
            for (int o = 0; o < 8; ++o) a16[8 + o] += e * bfu(U1.s[o]);
        }
#pragma unroll
        for (int m2 = 32; m2; m2 >>= 1) le += __shfl_xor(le, m2);
        if ((t & 63) == 0) red[4 + wid] = le;
#pragma unroll
        for (int o = 0; o < 16; ++o) accb[o * 256 + t] = a16[o];
        __syncthreads();
        float sume = red[4] + red[5] + red[6] + red[7];
        int g = t >> 4, tin = t & 15;
        float s = 0.f;
#pragma unroll
        for (int k = 0; k < 16; ++k) s += accb[g * 256 + tin + 16 * k];
#pragma unroll
        for (int m2 = 8; m2; m2 >>= 1) s += __shfl_xor(s, m2);
        if (tin == 0) svec[g] = s / sume + bdig[j * 16 + g];
        __syncthreads();
        if (t < 16) {
            float sv = svec[t];
            float sn = sv * sv;
#pragma unroll
            for (int m2 = 8; m2; m2 >>= 1) sn += __shfl_xor(sn, m2);
            float sc = (sn / (1.f + sn)) / sqrtf(sn + 1e-8f);
            float v = sv * sc;
            vsc[t] = v;
            if (it == 2) { vout[bid * 16 + t] = v; vws[bid * 16 + t] = v; }
        }
        __syncthreads();
        if (it < 2) {
            for (int i = t; i < 1152; i += 256) {
                const uint4* up = (const uint4*)(uh + i * 16);
                union { uint4 q; unsigned short s[8]; } U0, U1;
                U0.q = up[0]; U1.q = up[1];
                float dot = 0.f;
#pragma unroll
                for (int o = 0; o < 8; ++o) dot += vsc[o] * bfu(U0.s[o]);
#pragma unroll
                for (int o = 0; o < 8; ++o) dot += vsc[8 + o] * bfu(U1.s[o]);
                barr[i] += dot;
            }
            __syncthreads();
        }
    }
}

// ---------------- reconstruction GEMM, latency-proof ----------------
__global__ __launch_bounds__(256) void rec_gemm_kernel(const float* __restrict__ A,
                                                       const float* __restrict__ W,
                                                       const float* __restrict__ bias,
                                                       float* __restrict__ out,
                                                       int K, int N, int act) {
    __shared__ __align__(16) float As[2][2048];
    int n0 = blockIdx.x * 64;
    int bch = blockIdx.y * 32;
    int t = threadIdx.x;
    int n_l = t & 63, bh = t >> 6;
    const float* Wc = W + n0 + n_l;
    float acc[8];
#pragma unroll
    for (int i = 0; i < 8; ++i) acc[i] = 0.f;
    int T = (K + 63) >> 6;

    auto stageA = [&](int tile, int buf) {
        int k0 = tile << 6;
        for (int idx = t; idx < 2048; idx += 256) {
            int bb = idx >> 6, kk = idx & 63;
            As[buf][idx] = (k0 + kk < K) ? A[(long)(bch + bb) * K + k0 + kk] : 0.f;
        }
    };
    auto ldW = [&](int tile, float* w) {
        int k0 = tile << 6;
#pragma unroll
        for (int j = 0; j < 64; ++j) {
            int kr = k0 + j;
            if (kr >= K) kr = K - 1;
            w[j] = Wc[(long)kr * N];
        }
    };
    auto compute = [&](const float* w, int buf) {
#pragma unroll
        for (int bb = 0; bb < 8; ++bb) {
            const float4* ap = (const float4*)&As[buf][(bh * 8 + bb) * 64];
            float s = 0.f;
#pragma unroll
            for (int q = 0; q < 16; ++q) {
                float4 a = ap[q];
                s += a.x * w[q * 4] + a.y * w[q * 4 + 1] + a.z * w[q * 4 + 2] + a.w * w[q * 4 + 3];
            }
            acc[bb] += s;
        }
    };

    float wA[64], wB[64];
    ldW(0, wA);
    stageA(0, 0);
    __syncthreads();
    for (int tile = 0; tile < T; tile += 2) {
        if (tile + 1 < T) { ldW(tile + 1, wB); stageA(tile + 1, 1); }
        compute(wA, 0);
        __syncthreads();
        if (tile + 1 < T) {
            if (tile + 2 < T) { ldW(tile + 2, wA); stageA(tile + 2, 0); }
            compute(wB, 1);
            __syncthreads();
        }
    }

    float bs = bias[n0 + n_l];
#pragma unroll
    for (int bb = 0; bb < 8; ++bb) {
        float x = acc[bb] + bs;
        float r;
        if (act == 0) r = x > 0.f ? x : 0.f;
        else r = 1.f / (1.f + __expf(-x));
        out[(long)(bch + bh * 8 + bb) * N + n0 + n_l] = r;
    }
}

extern "C" void kernel_launch(void* const* d_in, const int* in_sizes, int n_in,
                              void* d_out, int out_size, void* d_ws, size_t ws_size,
                              hipStream_t stream) {
    const float* x   = (const float*)d_in[0];
    const float* c1w = (const float*)d_in[1];
    const float* c1b = (const float*)d_in[2];
    const float* c2w = (const float*)d_in[3];
    const float* c2b = (const float*)d_in[4];
    const float* pw  = (const float*)d_in[5];
    const float* pb  = (const float*)d_in[6];
    const float* Wd  = (const float*)d_in[7];
    const float* bd  = (const float*)d_in[8];
    const float* rw1 = (const float*)d_in[9];
    const float* rb1 = (const float*)d_in[10];
    const float* rw2 = (const float*)d_in[11];
    const float* rb2 = (const float*)d_in[12];
    const float* rw3 = (const float*)d_in[13];
    const float* rb3 = (const float*)d_in[14];
    float* outp = (float*)d_out;

    char* ws = (char*)d_ws;
    size_t off = 0;
    auto alloc = [&](size_t bytes) {
        char* p = ws + off;
        off += (bytes + 255) & ~(size_t)255;
        return p;
    };
    unsigned char* c1f8  = (unsigned char*)alloc(75497472UL);   // [128][48][48][256] fp8 (x16)
    __hip_bfloat16* c2out = (__hip_bfloat16*)alloc(26214400UL); // [128][20][20][256] bf16
    __hip_bfloat16* c3out = (__hip_bfloat16*)alloc(2359296UL);
    __hip_bfloat16* w3p   = (__hip_bfloat16*)alloc(10616832UL);
    unsigned char* wq2    = (unsigned char*)alloc(5505024UL);   // [8][21][2][128][128] fp8 (x64)
    __hip_bfloat16* xb    = (__hip_bfloat16*)alloc(802816UL);
    __hip_bfloat16* wb    = (__hip_bfloat16*)alloc(49152UL);
    float* uT    = (float*)alloc(4718592UL);
    __hip_bfloat16* uhat = (__hip_bfloat16*)alloc(47185920UL);
    float* vws   = (float*)alloc(81920UL);
    float* rec1  = (float*)alloc(262144UL);
    float* rec2  = (float*)alloc(524288UL);

    __hip_bfloat16* c3part = (__hip_bfloat16*)uhat;

    prep_w_kernel<<<1417, 256, 0, stream>>>(pw, w3p, c1w, wb, x, xb, c2w, wq2);
    conv1_mfma_kernel<<<3072, 256, 0, stream>>>(xb, wb, c1b, c1f8);
    conv2_fp8_kernel<<<256, 512, 0, stream>>>(c1f8, wq2, c2b, c2out);
    conv_mfma_kernel<<<dim3(36, 2, 9), 256, 0, stream>>>(c2out, w3p, pb, c3out, c3part,
                                                         20, 20 * 20 * 256, 36, 6, 9, 4608, 1);
    reduce_parts_kernel<<<4608, 256, 0, stream>>>(c3part, pb, c3out);
    squash_caps_kernel<<<576, 256, 0, stream>>>(c3out, uT);
    uhat_kernel<<<1152, 256, 0, stream>>>(uT, Wd, uhat);
    routing_kernel<<<1280, 256, 0, stream>>>(uhat, bd, outp, vws);
    rec_gemm_kernel<<<dim3(8, 4), 256, 0, stream>>>(vws, rw1, rb1, rec1, 160, 512, 0);
    rec_gemm_kernel<<<dim3(16, 4), 256, 0, stream>>>(rec1, rw2, rb2, rec2, 512, 1024, 0);
    rec_gemm_kernel<<<dim3(49, 4), 256, 0, stream>>>(rec2, rw3, rb3, outp + 20480, 1024, 3136, 1);
}

// Round 19
// 760.472 us; speedup vs baseline: 2.0527x; 1.0203x over previous
//
#include <hip/hip_runtime.h>
#include <hip/hip_bf16.h>

typedef float f32x4 __attribute__((ext_vector_type(4)));
typedef __bf16 bf16x8 __attribute__((ext_vector_type(8)));
typedef __bf16 bf16x4 __attribute__((ext_vector_type(4)));
typedef int i32x8 __attribute__((ext_vector_type(8)));

#define AS1 __attribute__((address_space(1)))
#define AS3 __attribute__((address_space(3)))

__device__ __forceinline__ void gload16(const void* g, void* l) {
    __builtin_amdgcn_global_load_lds((AS1 unsigned int*)g, (AS3 unsigned int*)l, 16, 0, 0);
}

__device__ __forceinline__ float bfu(unsigned short u) {
    return __uint_as_float((unsigned)u << 16);
}

// float -> fp8 e4m3 (OCP), truncating, signed, flush-to-zero below 2^-6, clamp 448
__device__ __forceinline__ unsigned char f2e4m3s(float f) {
    unsigned u = __float_as_uint(f);
    unsigned s = (u >> 24) & 0x80;
    unsigned ua = u & 0x7fffffffu;
    int e = (int)(ua >> 23) - 127;
    unsigned m = (ua >> 20) & 7;
    if (e < -6) return (unsigned char)s;
    if (e > 8 || (e == 8 && m > 6)) return (unsigned char)(s | 0x7e);
    return (unsigned char)(s | ((unsigned)(e + 7) << 3) | m);
}

// ---------------- prep: [0,512) conv3 w -> bf16 table; 512: conv1 wb; [513,905) x->bf16;
// [905,1417) conv2 w -> fp8 table [icg][21 ks][nblk][128 oc][128 kb] (x64, coalesced via LDS) ----------------
__global__ __launch_bounds__(256) void prep_w_kernel(const float* __restrict__ pw,
                                                     __hip_bfloat16* __restrict__ w3p,
                                                     const float* __restrict__ c1w,
                                                     __hip_bfloat16* __restrict__ wb,
                                                     const float* __restrict__ x,
                                                     __hip_bfloat16* __restrict__ xb,
                                                     const float* __restrict__ c2w,
                                                     unsigned char* __restrict__ wq2) {
    int bid = blockIdx.x;
    int t = threadIdx.x;
    if (bid == 512) {  // conv1 weight table
        float tmp[81];
#pragma unroll
        for (int k = 0; k < 81; ++k) tmp[k] = c1w[t * 81 + k];
#pragma unroll
        for (int ks = 0; ks < 9; ++ks)
#pragma unroll
            for (int e = 0; e < 8; ++e)
                wb[(ks * 256 + t) * 8 + e] = __float2bfloat16(tmp[ks * 9 + e]);
#pragma unroll
        for (int e = 0; e < 8; ++e)
            wb[(9 * 256 + t) * 8 + e] = __float2bfloat16(tmp[e * 9 + 8]);
        wb[(10 * 256 + t) * 8 + 0] = __float2bfloat16(tmp[80]);
#pragma unroll
        for (int e = 1; e < 8; ++e) wb[(10 * 256 + t) * 8 + e] = __float2bfloat16(0.f);
#pragma unroll
        for (int e = 0; e < 8; ++e) wb[(11 * 256 + t) * 8 + e] = __float2bfloat16(0.f);
        return;
    }
    if (bid >= 513 && bid < 905) {  // x -> bf16
        long i4 = (long)(bid - 513) * 1024 + t * 4;
        float4 v = *(const float4*)(x + i4);
        bf16x4 o = {(__bf16)v.x, (__bf16)v.y, (__bf16)v.z, (__bf16)v.w};
        *(bf16x4*)((__bf16*)xb + i4) = o;
        return;
    }
    if (bid >= 905) {  // conv2 fp8 table, coalesced via LDS
        __shared__ float wl[4 * 2592];  // [4 oc][32 ic][81 kyx]
        int b2 = bid - 905;
        int icg = b2 & 7;
        int oc4 = (b2 >> 3) & 31;
        int nblk = b2 >> 8;
        for (int f = t; f < 4 * 2592; f += 256) {
            int o = f / 2592;
            int rest = f - o * 2592;
            wl[f] = c2w[(long)(nblk * 128 + oc4 * 4 + o) * 20736 + icg * 2592 + rest];
        }
        __syncthreads();
        long base = (long)icg * 688128 + (long)nblk * 16384 + (oc4 * 4) * 128;
        for (int idx = t; idx < 4 * 21 * 128; idx += 256) {
            int o = idx / 2688;
            int rem = idx - o * 2688;
            int ks = rem >> 7, kb = rem & 127;
            int kq = kb >> 5, icl = kb & 31;
            int kyx = ks * 4 + kq;
            float v = (kyx < 81) ? wl[o * 2592 + icl * 81 + kyx] * 64.f : 0.f;
            wq2[base + (long)ks * 32768 + o * 128 + kb] = f2e4m3s(v);
        }
        return;
    }
    // conv3 weights -> bf16 [kyx][icg][nblk][oc128][ic32]
    __shared__ float wl3[4 * 32 * 81];
    int icg = bid & 7;
    int oc4 = (bid >> 3) & 31;
    int nblk = bid >> 8;
    int ocg0 = nblk * 128 + oc4 * 4;
    int ic0 = icg * 32;
    for (int f = t; f < 4 * 2592; f += 256) {
        int o = f / 2592;
        int rest = f - o * 2592;
        wl3[f] = pw[(ocg0 + o) * 20736 + ic0 * 81 + rest];
    }
    __syncthreads();
    for (int idx = t; idx < 81 * 128; idx += 256) {
        int kyx = idx >> 7;
        int o = (idx >> 5) & 3;
        int i = idx & 31;
        long dst = (long)(((kyx * 8 + icg) * 2 + nblk) * 128 + (oc4 * 4 + o)) * 32 + i;
        w3p[dst] = __float2bfloat16(wl3[o * 2592 + i * 81 + kyx]);
    }
}

// ---------------- conv1 as bf16 MFMA implicit-GEMM, writes fp8 (x16 pre-scale) ----------------
__global__ __launch_bounds__(256) void conv1_mfma_kernel(const __hip_bfloat16* __restrict__ xb,
                                                         const __hip_bfloat16* __restrict__ wb,
                                                         const float* __restrict__ bias,
                                                         unsigned char* __restrict__ out) {
    __shared__ __bf16 Asl[640];  // [10 rows][64 cols]
    int bid = blockIdx.x;
    int b = bid / 24, mb2 = bid - b * 24;
    int oy0 = mb2 * 2;
    int t = threadIdx.x;
    int lane = t & 63, wc = t >> 6;
    int q = lane >> 4;

    const __bf16* src = (const __bf16*)xb + b * 3136 + oy0 * 56;
    for (int idx = t; idx < 640; idx += 256) {
        int iy = idx >> 6, col = idx & 63;
        Asl[idx] = (col < 56) ? src[iy * 56 + col] : (__bf16)0.f;
    }

    bf16x8 Bf[3][4];
#pragma unroll
    for (int s = 0; s < 3; ++s)
#pragma unroll
        for (int ni = 0; ni < 4; ++ni) {
            int col = wc * 64 + ni * 16 + (lane & 15);
            Bf[s][ni] = *(const bf16x8*)(wb + ((s * 4 + q) * 256 + col) * 8);
        }

    f32x4 acc[6][4];
#pragma unroll
    for (int i = 0; i < 6; ++i)
#pragma unroll
        for (int j = 0; j < 4; ++j) acc[i][j] = (f32x4){0.f, 0.f, 0.f, 0.f};

    __syncthreads();

#pragma unroll
    for (int s = 0; s < 3; ++s) {
        int ks = s * 4 + q;
        bf16x8 af[6];
#pragma unroll
        for (int mi = 0; mi < 6; ++mi) {
            int r = mi * 16 + (lane & 15);
            int oyl = (r >= 48) ? 1 : 0;
            int ox = r - 48 * oyl;
            bf16x8 v;
            if (ks < 9) {
                __builtin_memcpy(&v, &Asl[(oyl + ks) * 64 + ox], 16);
            } else if (ks == 9) {
#pragma unroll
                for (int e = 0; e < 8; ++e) v[e] = Asl[(oyl + e) * 64 + ox + 8];
            } else if (ks == 10) {
#pragma unroll
                for (int e = 0; e < 8; ++e) v[e] = (__bf16)0.f;
                v[0] = Asl[(oyl + 8) * 64 + ox + 8];
            } else {
#pragma unroll
                for (int e = 0; e < 8; ++e) v[e] = (__bf16)0.f;
            }
            af[mi] = v;
        }
#pragma unroll
        for (int mi = 0; mi < 6; ++mi)
#pragma unroll
            for (int ni = 0; ni < 4; ++ni)
                acc[mi][ni] = __builtin_amdgcn_mfma_f32_16x16x32_bf16(af[mi], Bf[s][ni], acc[mi][ni], 0, 0, 0);
    }

    long m0 = (long)b * 2304 + mb2 * 96;
#pragma unroll
    for (int mi = 0; mi < 6; ++mi)
#pragma unroll
        for (int ni = 0; ni < 4; ++ni) {
            int col = wc * 64 + ni * 16 + (lane & 15);
            float bs = bias[col];
#pragma unroll
            for (int r2 = 0; r2 < 4; ++r2) {
                int row = mi * 16 + q * 4 + r2;
                float vv = acc[mi][ni][r2] + bs;
                vv = vv > 0.f ? vv : 0.f;
                out[(m0 + row) * 256 + col] = f2e4m3s(vv * 16.f);
            }
        }
}

// ---------------- conv2: MX-fp8 (K=128), parity-split LDS im2col [2 plane][48 iy][24 col][32 ch]
// (stride-2 conv -> lane stride 32B within plane = 2-way/free), barrier-free K-loop ----------------
__global__ __launch_bounds__(512, 2) void conv2_fp8_kernel(const unsigned char* __restrict__ in,
                                                           const unsigned char* __restrict__ wq,
                                                           const float* __restrict__ bias,
                                                           __hip_bfloat16* __restrict__ out) {
    __shared__ unsigned char Ald[73728];   // 2 planes x [48][24][32]
    int bid = blockIdx.x;
    int wg = (bid & 7) * 32 + (bid >> 3);  // XCD-chunk
    int b = wg >> 1, nblk = wg & 1;
    int t = threadIdx.x;
    int lane = t & 63, wid = t >> 6;
    int wr = wid >> 1, wc = wid & 1;       // 4 M x 2 N waves
    int kq = lane >> 4;

    const unsigned char* imgbase = in + (long)b * (48 * 48 * 256);
    const unsigned char* wqn = wq + ((long)(nblk * 128 + wc * 64 + (lane & 15))) * 128 + kq * 32;

    int qbase[7];  // within-plane byte offset of output pixel (iy=2*oy, col=ox)
#pragma unroll
    for (int mi = 0; mi < 7; ++mi) {
        int ml = wr * 96 + mi * 16 + (lane & 15);
        int oy = ml / 20, ox = ml - oy * 20;
        qbase[mi] = (2 * oy * 24 + ox) * 32;
    }

    f32x4 acc[7][4];
#pragma unroll
    for (int i = 0; i < 7; ++i)
#pragma unroll
        for (int j = 0; j < 4; ++j) acc[i][j] = (f32x4){0.f, 0.f, 0.f, 0.f};

    auto stageA = [&](int icg) {
#pragma unroll 3
        for (int j = 0; j < 9; ++j) {
            int gi = t + j * 512;                 // 16B-slot over [48][48][2]
            int p = gi >> 1, half = gi & 1;
            int iy = p / 48, ix = p - iy * 48;
            uint4 v = *(const uint4*)(imgbase + ((long)p * 256 + icg * 32 + half * 16));
            int plane = ix & 1, col = ix >> 1;
            *(uint4*)(Ald + plane * 36864 + (iy * 24 + col) * 32 + half * 16) = v;
        }
    };

    union U8 { uint4 q[2]; i32x8 v; };
    i32x8 Be[4], Bo[4];
    auto loadB = [&](i32x8* dst, int icg, int ks) {
        const unsigned char* p = wqn + (long)icg * 688128 + (long)ks * 32768;
        uint4* d = (uint4*)dst;
#pragma unroll
        for (int ni = 0; ni < 4; ++ni) {
            d[ni * 2]     = *(const uint4*)(p + ni * 2048);
            d[ni * 2 + 1] = *(const uint4*)(p + ni * 2048 + 16);
        }
    };

    auto step = [&](int icg, int ks, i32x8* Bcur, i32x8* Bnxt) {
        if (ks + 1 < 21) loadB(Bnxt, icg, ks + 1);
        int kyx = ks * 4 + kq;
        int ky = kyx / 9, kx = kyx - ky * 9;
        int sdel = ((kx & 1) ? 36864 : 0) + (ky * 24 + (kx >> 1)) * 32;
        __builtin_amdgcn_s_setprio(1);
#pragma unroll
        for (int mi = 0; mi < 7; ++mi) {
            const unsigned char* ap = Ald + qbase[mi] + sdel;
            U8 a;
            a.q[0] = *(const uint4*)ap;
            a.q[1] = *(const uint4*)(ap + 16);
#pragma unroll
            for (int ni = 0; ni < 4; ++ni)
                acc[mi][ni] = __builtin_amdgcn_mfma_scale_f32_16x16x128_f8f6f4(
                    a.v, Bcur[ni], acc[mi][ni],
                    0, 0,                      // cbsz, blgp = fp8-e4m3
                    0, 0x7F7F7F7F,             // opsel_a, scale_a (127 -> 2^0)
                    0, 0x7F7F7F7F);            // opsel_b, scale_b
        }
        __builtin_amdgcn_s_setprio(0);
    };

    for (int icg = 0; icg < 8; ++icg) {
        if (icg) __builtin_amdgcn_s_barrier();   // all waves done reading old A
        loadB(Be, icg, 0);
        stageA(icg);
        asm volatile("s_waitcnt lgkmcnt(0)" ::: "memory");
        __builtin_amdgcn_s_barrier();
        if (wid >= 4) asm volatile("s_sleep 4");  // de-phase co-resident waves
        for (int kk = 0; kk < 10; ++kk) {
            step(icg, 2 * kk, Be, Bo);
            step(icg, 2 * kk + 1, Bo, Be);
        }
        step(icg, 20, Be, Bo);
    }

    int colbase = nblk * 128 + wc * 64 + (lane & 15);
    const float inv = 1.f / 1024.f;  // A x16, B x64
#pragma unroll
    for (int mi = 0; mi < 7; ++mi) {
#pragma unroll
        for (int ni = 0; ni < 4; ++ni) {
            int col = colbase + ni * 16;
            float bs = bias[col];
#pragma unroll
            for (int r = 0; r < 4; ++r) {
                int ml = wr * 96 + mi * 16 + (lane >> 4) * 4 + r;
                float v = acc[mi][ni][r] * inv + bs;
                v = v > 0.f ? v : 0.f;
                out[((long)b * 400 + ml) * 256 + col] = __float2bfloat16(v);
            }
        }
    }
}

// ---------------- conv3: implicit-GEMM 128x128 (split-K), ring-3, counted vmcnt, bf16 partials ----------------
__global__ __launch_bounds__(256) void conv_mfma_kernel(const __hip_bfloat16* __restrict__ in,
                                                        const __hip_bfloat16* __restrict__ wp,
                                                        const float* __restrict__ bias,
                                                        __hip_bfloat16* __restrict__ out,
                                                        __hip_bfloat16* __restrict__ part,
                                                        int Win, int imgStride, int HWout, int Wout,
                                                        int nkyx, int Mtot, int mode) {
    __shared__ __hip_bfloat16 Ald[3 * 4096];
    __shared__ __hip_bfloat16 Bld[3 * 4096];
    int mblk = blockIdx.x, nblk = blockIdx.y;
    int kyx0 = blockIdx.z * nkyx;
    int t = threadIdx.x;
    int lane = t & 63, wid = t >> 6;
    int swz = ((t & 3) ^ ((t >> 3) & 3)) * 8;
    int icsrc = swz;
    long bsrc = (t >> 2) * 32 + swz;

    long base0, base1;
    {
        int m = mblk * 128 + (t >> 2);
        int b = m / HWout; int rem = m - b * HWout;
        int oyy = rem / Wout; int oxx = rem - oyy * Wout;
        base0 = (long)b * imgStride + (long)(2 * oyy * Win + 2 * oxx) * 256;
        m += 64;
        b = m / HWout; rem = m - b * HWout;
        oyy = rem / Wout; oxx = rem - oyy * Wout;
        base1 = (long)b * imgStride + (long)(2 * oyy * Win + 2 * oxx) * 256;
    }

    f32x4 acc[4][4];
#pragma unroll
    for (int i = 0; i < 4; ++i)
#pragma unroll
        for (int j2 = 0; j2 < 4; ++j2) acc[i][j2] = (f32x4){0.f, 0.f, 0.f, 0.f};

    int wr = wid >> 1, wc = wid & 1;
    int slot8 = (((lane >> 4) ^ ((lane >> 1) & 3))) * 8;
    int a_off = ((wr * 64 + (lane & 15)) * 32 + slot8) * 2;
    int b_off = ((wc * 64 + (lane & 15)) * 32 + slot8) * 2;

    auto stage = [&](int s, int buf) {
        int kyx = kyx0 + (s >> 3);
        int icg = s & 7;
        int ky = kyx / 9, kx = kyx - ky * 9;
        long offA = (long)(ky * Win + kx) * 256 + icg * 32 + icsrc;
        long btb = (long)((kyx * 8 + icg) * 2 + nblk) * 4096 + bsrc;
        char* a0 = (char*)Ald + buf * 8192 + wid * 1024;
        char* b0 = (char*)Bld + buf * 8192 + wid * 1024;
        gload16(in + base0 + offA, a0);
        gload16(in + base1 + offA, a0 + 4096);
        gload16(wp + btb, b0);
        gload16(wp + btb + 2048, b0 + 4096);
    };

    int nsteps = nkyx * 8;
    stage(0, 0);
    stage(1, 1);
    stage(2, 2);
    int cur = 0;
    for (int s = 0; s < nsteps; ++s) {
        int rem = nsteps - 1 - s;
        if (rem >= 2) {
            asm volatile("s_waitcnt vmcnt(8)" ::: "memory");
        } else if (rem == 1) {
            asm volatile("s_waitcnt vmcnt(4)" ::: "memory");
        } else {
            asm volatile("s_waitcnt vmcnt(0)" ::: "memory");
        }
        __builtin_amdgcn_s_barrier();
        __builtin_amdgcn_sched_barrier(0);
        const char* Ac = (const char*)Ald + cur * 8192;
        const char* Bc = (const char*)Bld + cur * 8192;
        bf16x8 af[4], bfr[4];
#pragma unroll
        for (int i = 0; i < 4; ++i) af[i] = *(const bf16x8*)(Ac + a_off + i * 1024);
#pragma unroll
        for (int i = 0; i < 4; ++i) bfr[i] = *(const bf16x8*)(Bc + b_off + i * 1024);
#pragma unroll
        for (int mi = 0; mi < 4; ++mi)
#pragma unroll
            for (int ni = 0; ni < 4; ++ni)
                acc[mi][ni] = __builtin_amdgcn_mfma_f32_16x16x32_bf16(af[mi], bfr[ni], acc[mi][ni], 0, 0, 0);
        if (s + 3 < nsteps) {
            asm volatile("s_waitcnt lgkmcnt(0)" ::: "memory");
            __builtin_amdgcn_s_barrier();
            stage(s + 3, cur);
        }
        cur = (cur == 2) ? 0 : cur + 1;
    }

    int colbase = nblk * 128 + wc * 64 + (lane & 15);
    long mrowbase = (long)mblk * 128 + wr * 64 + (lane >> 4) * 4;
    if (mode == 0) {
#pragma unroll
        for (int mi = 0; mi < 4; ++mi) {
#pragma unroll
            for (int ni = 0; ni < 4; ++ni) {
                int col = colbase + ni * 16;
                float bs = bias[col];
#pragma unroll
                for (int r = 0; r < 4; ++r) {
                    long mrow = mrowbase + mi * 16 + r;
                    float v = acc[mi][ni][r] + bs;
                    v = v > 0.f ? v : 0.f;
                    out[mrow * 256 + col] = __float2bfloat16(v);
                }
            }
        }
    } else {
        __hip_bfloat16* pp = part + (long)blockIdx.z * Mtot * 256;
#pragma unroll
        for (int mi = 0; mi < 4; ++mi) {
#pragma unroll
            for (int ni = 0; ni < 4; ++ni) {
                int col = colbase + ni * 16;
#pragma unroll
                for (int r = 0; r < 4; ++r) {
                    long mrow = mrowbase + mi * 16 + r;
                    pp[mrow * 256 + col] = __float2bfloat16(acc[mi][ni][r]);
                }
            }
        }
    }
}

// ---------------- split-K reduce ----------------
__global__ __launch_bounds__(256) void reduce_parts_kernel(const __hip_bfloat16* __restrict__ part,
                                                           const float* __restrict__ bias,
                                                           __hip_bfloat16* __restrict__ out) {
    int idx = blockIdx.x * 256 + threadIdx.x;
    float s = 0.f;
#pragma unroll
    for (int p = 0; p < 9; ++p) s += __bfloat162float(part[(long)p * 1179648 + idx]);
    s += bias[idx & 255];
    s = s > 0.f ? s : 0.f;
    out[idx] = __float2bfloat16(s);
}

// ---------------- primary capsule squash ----------------
__global__ __launch_bounds__(256) void squash_caps_kernel(const __hip_bfloat16* __restrict__ c3,
                                                          float* __restrict__ uT) {
    int g = blockIdx.x * 256 + threadIdx.x;
    int i = g >> 7, b = g & 127;
    float val[8];
    float sn = 0.f;
#pragma unroll
    for (int d = 0; d < 8; ++d) {
        int flat = i * 8 + d;
        int c = flat / 36; int rem = flat - c * 36;
        int y = rem / 6; int xx = rem - y * 6;
        float vv = __bfloat162float(c3[((b * 6 + y) * 6 + xx) * 256 + c]);
        val[d] = vv;
        sn += vv * vv;
    }
    float sc = (sn / (1.f + sn)) / sqrtf(sn + 1e-8f);
#pragma unroll
    for (int d = 0; d < 8; ++d) uT[(long)g * 8 + d] = val[d] * sc;
}

// ---------------- u_hat ----------------
__global__ __launch_bounds__(256) void uhat_kernel(const float* __restrict__ uT,
                                                   const float* __restrict__ Wd,
                                                   __hip_bfloat16* __restrict__ uhat) {
    __shared__ float Wl2[1600];
    __shared__ float ul[1024];
    int i = blockIdx.x, t = threadIdx.x;
    for (int idx = t; idx < 1280; idx += 256) {
        int j = idx >> 7, rest = idx & 127;
        int d = rest >> 4, o = rest & 15;
        Wl2[(j * 16 + o) * 10 + d] = Wd[((long)j * 1152 + i) * 128 + rest];
    }
    {
        const float4* usrc = (const float4*)(uT + (long)i * 1024);
        float4* ud = (float4*)ul;
        ud[t] = usrc[t];
    }
    __syncthreads();
    int b = (t >= 160) ? 1 : 0;
    int jo = (t >= 160) ? t - 160 : t;
    for (int rr = 0; rr < 80; ++rr) {
        const float* up = &ul[b * 8];
        const float* wq = &Wl2[jo * 10];
        float a = 0.f;
#pragma unroll
        for (int d = 0; d < 8; ++d) a += up[d] * wq[d];
        int j = jo >> 4, o = jo & 15;
        uhat[(((long)b * 10 + j) * 1152 + i) * 16 + o] = __float2bfloat16(a);
        jo += 96; b += 1;
        if (jo >= 160) { jo -= 160; b += 1; }
    }
}

// ---------------- fused dynamic routing ----------------
__global__ __launch_bounds__(256) void routing_kernel(const __hip_bfloat16* __restrict__ uhat,
                                                      const float* __restrict__ bdig,
                                                      float* __restrict__ vout,
                                                      float* __restrict__ vws) {
    __shared__ __hip_bfloat16 uh[1152 * 16];
    __shared__ float barr[1152];
    __shared__ float red[16];
    __shared__ float accb[16 * 256];
    __shared__ float svec[16];
    __shared__ float vsc[16];
    int bid = blockIdx.x;
    int j = bid % 10;
    int t = threadIdx.x;
    int wid = t >> 6;
    const uint4* srcp = (const uint4*)(uhat + (long)bid * 18432);
    uint4* dstp = (uint4*)uh;
    for (int idx = t; idx < 2304; idx += 256) dstp[idx] = srcp[idx];
    for (int idx = t; idx < 1152; idx += 256) barr[idx] = 0.f;
    __syncthreads();
    for (int it = 0; it < 3; ++it) {
        float lm = -1e30f;
        for (int i = t; i < 1152; i += 256) lm = fmaxf(lm, barr[i]);
#pragma unroll
        for (int m2 = 32; m2; m2 >>= 1) lm = fmaxf(lm, __shfl_xor(lm, m2));
        if ((t & 63) == 0) red[wid] = lm;
        __syncthreads();
        float mx = fmaxf(fmaxf(red[0], red[1]), fmaxf(red[2], red[3]));
        float le = 0.f;
        float a16[16];
#pragma unroll
        for (int o = 0; o < 16; ++o) a16[o] = 0.f;
        for (int i = t; i < 1152; i += 256) {
            float e = __expf(barr[i] - mx);
            le += e;
            const uint4* up = (const uint4*)(uh + i * 16);
            union { uint4 q; unsigned short s[8]; } U0, U1;
            U0.q = up[0]; U1.q = up[1];
#pragma unroll
            for (int o = 0; o < 8; ++o) a16[o] += e * bfu(U0.s[o]);
#pragma unroll
            for (int o = 0; o < 8; ++o) a16[8 + o] += e * bfu(U1.s[o]);
        }
#pragma unroll
        for (int m2 = 32; m2; m2 >>= 1) le += __shfl_xor(le, m2);
        if ((t & 63) == 0) red[4 + wid] = le;
#pragma unroll
        for (int o = 0; o < 16; ++o) accb[o * 256 + t] = a16[o];
        __syncthreads();
        float sume = red[4] + red[5] + red[6] + red[7];
        int g = t >> 4, tin = t & 15;
        float s = 0.f;
#pragma unroll
        for (int k = 0; k < 16; ++k) s += accb[g * 256 + tin + 16 * k];
#pragma unroll
        for (int m2 = 8; m2; m2 >>= 1) s += __shfl_xor(s, m2);
        if (tin == 0) svec[g] = s / sume + bdig[j * 16 + g];
        __syncthreads();
        if (t < 16) {
            float sv = svec[t];
            float sn = sv * sv;
#pragma unroll
            for (int m2 = 8; m2; m2 >>= 1) sn += __shfl_xor(sn, m2);
            float sc = (sn / (1.f + sn)) / sqrtf(sn + 1e-8f);
            float v = sv * sc;
            vsc[t] = v;
            if (it == 2) { vout[bid * 16 + t] = v; vws[bid * 16 + t] = v; }
        }
        __syncthreads();
        if (it < 2) {
            for (int i = t; i < 1152; i += 256) {
                const uint4* up = (const uint4*)(uh + i * 16);
                union { uint4 q; unsigned short s[8]; } U0, U1;
                U0.q = up[0]; U1.q = up[1];
                float dot = 0.f;
#pragma unroll
                for (int o = 0; o < 8; ++o) dot += vsc[o] * bfu(U0.s[o]);
#pragma unroll
                for (int o = 0; o < 8; ++o) dot += vsc[8 + o] * bfu(U1.s[o]);
                barr[i] += dot;
            }
            __syncthreads();
        }
    }
}

// ---------------- reconstruction GEMM, latency-proof ----------------
__global__ __launch_bounds__(256) void rec_gemm_kernel(const float* __restrict__ A,
                                                       const float* __restrict__ W,
                                                       const float* __restrict__ bias,
                                                       float* __restrict__ out,
                                                       int K, int N, int act) {
    __shared__ __align__(16) float As[2][2048];
    int n0 = blockIdx.x * 64;
    int bch = blockIdx.y * 32;
    int t = threadIdx.x;
    int n_l = t & 63, bh = t >> 6;
    const float* Wc = W + n0 + n_l;
    float acc[8];
#pragma unroll
    for (int i = 0; i < 8; ++i) acc[i] = 0.f;
    int T = (K + 63) >> 6;

    auto stageA = [&](int tile, int buf) {
        int k0 = tile << 6;
        for (int idx = t; idx < 2048; idx += 256) {
            int bb = idx >> 6, kk = idx & 63;
            As[buf][idx] = (k0 + kk < K) ? A[(long)(bch + bb) * K + k0 + kk] : 0.f;
        }
    };
    auto ldW = [&](int tile, float* w) {
        int k0 = tile << 6;
#pragma unroll
        for (int j = 0; j < 64; ++j) {
            int kr = k0 + j;
            if (kr >= K) kr = K - 1;
            w[j] = Wc[(long)kr * N];
        }
    };
    auto compute = [&](const float* w, int buf) {
#pragma unroll
        for (int bb = 0; bb < 8; ++bb) {
            const float4* ap = (const float4*)&As[buf][(bh * 8 + bb) * 64];
            float s = 0.f;
#pragma unroll
            for (int q = 0; q < 16; ++q) {
                float4 a = ap[q];
                s += a.x * w[q * 4] + a.y * w[q * 4 + 1] + a.z * w[q * 4 + 2] + a.w * w[q * 4 + 3];
            }
            acc[bb] += s;
        }
    };

    float wA[64], wB[64];
    ldW(0, wA);
    stageA(0, 0);
    __syncthreads();
    for (int tile = 0; tile < T; tile += 2) {
        if (tile + 1 < T) { ldW(tile + 1, wB); stageA(tile + 1, 1); }
        compute(wA, 0);
        __syncthreads();
        if (tile + 1 < T) {
            if (tile + 2 < T) { ldW(tile + 2, wA); stageA(tile + 2, 0); }
            compute(wB, 1);
            __syncthreads();
        }
    }

    float bs = bias[n0 + n_l];
#pragma unroll
    for (int bb = 0; bb < 8; ++bb) {
        float x = acc[bb] + bs;
        float r;
        if (act == 0) r = x > 0.f ? x : 0.f;
        else r = 1.f / (1.f + __expf(-x));
        out[(long)(bch + bh * 8 + bb) * N + n0 + n_l] = r;
    }
}

extern "C" void kernel_launch(void* const* d_in, const int* in_sizes, int n_in,
                              void* d_out, int out_size, void* d_ws, size_t ws_size,
                              hipStream_t stream) {
    const float* x   = (const float*)d_in[0];
    const float* c1w = (const float*)d_in[1];
    const float* c1b = (const float*)d_in[2];
    const float* c2w = (const float*)d_in[3];
    const float* c2b = (const float*)d_in[4];
    const float* pw  = (const float*)d_in[5];
    const float* pb  = (const float*)d_in[6];
    const float* Wd  = (const float*)d_in[7];
    const float* bd  = (const float*)d_in[8];
    const float* rw1 = (const float*)d_in[9];
    const float* rb1 = (const float*)d_in[10];
    const float* rw2 = (const float*)d_in[11];
    const float* rb2 = (const float*)d_in[12];
    const float* rw3 = (const float*)d_in[13];
    const float* rb3 = (const float*)d_in[14];
    float* outp = (float*)d_out;

    char* ws = (char*)d_ws;
    size_t off = 0;
    auto alloc = [&](size_t bytes) {
        char* p = ws + off;
        off += (bytes + 255) & ~(size_t)255;
        return p;
    };
    unsigned char* c1f8  = (unsigned char*)alloc(75497472UL);   // [128][48][48][256] fp8 (x16)
    __hip_bfloat16* c2out = (__hip_bfloat16*)alloc(26214400UL); // [128][20][20][256] bf16
    __hip_bfloat16* c3out = (__hip_bfloat16*)alloc(2359296UL);
    __hip_bfloat16* w3p   = (__hip_bfloat16*)alloc(10616832UL);
    unsigned char* wq2    = (unsigned char*)alloc(5505024UL);   // [8][21][2][128][128] fp8 (x64)
    __hip_bfloat16* xb    = (__hip_bfloat16*)alloc(802816UL);
    __hip_bfloat16* wb    = (__hip_bfloat16*)alloc(49152UL);
    float* uT    = (float*)alloc(4718592UL);
    __hip_bfloat16* uhat = (__hip_bfloat16*)alloc(47185920UL);
    float* vws   = (float*)alloc(81920UL);
    float* rec1  = (float*)alloc(262144UL);
    float* rec2  = (float*)alloc(524288UL);

    __hip_bfloat16* c3part = (__hip_bfloat16*)uhat;

    prep_w_kernel<<<1417, 256, 0, stream>>>(pw, w3p, c1w, wb, x, xb, c2w, wq2);
    conv1_mfma_kernel<<<3072, 256, 0, stream>>>(xb, wb, c1b, c1f8);
    conv2_fp8_kernel<<<256, 512, 0, stream>>>(c1f8, wq2, c2b, c2out);
    conv_mfma_kernel<<<dim3(36, 2, 9), 256, 0, stream>>>(c2out, w3p, pb, c3out, c3part,
                                                         20, 20 * 20 * 256, 36, 6, 9, 4608, 1);
    reduce_parts_kernel<<<4608, 256, 0, stream>>>(c3part, pb, c3out);
    squash_caps_kernel<<<576, 256, 0, stream>>>(c3out, uT);
    uhat_kernel<<<1152, 256, 0, stream>>>(uT, Wd, uhat);
    routing_kernel<<<1280, 256, 0, stream>>>(uhat, bd, outp, vws);
    rec_gemm_kernel<<<dim3(8, 4), 256, 0, stream>>>(vws, rw1, rb1, rec1, 160, 512, 0);
    rec_gemm_kernel<<<dim3(16, 4), 256, 0, stream>>>(rec1, rw2, rb2, rec2, 512, 1024, 0);
    rec_gemm_kernel<<<dim3(49, 4), 256, 0, stream>>>(rec2, rw3, rb3, outp + 20480, 1024, 3136, 1);
}

// Round 20
// 758.010 us; speedup vs baseline: 2.0594x; 1.0032x over previous
//
#include <hip/hip_runtime.h>
#include <hip/hip_bf16.h>

typedef float f32x4 __attribute__((ext_vector_type(4)));
typedef __bf16 bf16x8 __attribute__((ext_vector_type(8)));
typedef __bf16 bf16x4 __attribute__((ext_vector_type(4)));
typedef int i32x8 __attribute__((ext_vector_type(8)));

#define AS1 __attribute__((address_space(1)))
#define AS3 __attribute__((address_space(3)))

__device__ __forceinline__ void gload16(const void* g, void* l) {
    __builtin_amdgcn_global_load_lds((AS1 unsigned int*)g, (AS3 unsigned int*)l, 16, 0, 0);
}

__device__ __forceinline__ float bfu(unsigned short u) {
    return __uint_as_float((unsigned)u << 16);
}

// float -> fp8 e4m3 (OCP), truncating, signed, flush-to-zero below 2^-6, clamp 448
__device__ __forceinline__ unsigned char f2e4m3s(float f) {
    unsigned u = __float_as_uint(f);
    unsigned s = (u >> 24) & 0x80;
    unsigned ua = u & 0x7fffffffu;
    int e = (int)(ua >> 23) - 127;
    unsigned m = (ua >> 20) & 7;
    if (e < -6) return (unsigned char)s;
    if (e > 8 || (e == 8 && m > 6)) return (unsigned char)(s | 0x7e);
    return (unsigned char)(s | ((unsigned)(e + 7) << 3) | m);
}

// ---------------- prep: [0,512) conv3 w -> bf16 table; 512: conv1 wb; [513,905) x->bf16;
// [905,1417) conv2 w -> fp8 table [icg][21 ks][nblk][128 oc][128 kb] (x64, coalesced via LDS) ----------------
__global__ __launch_bounds__(256) void prep_w_kernel(const float* __restrict__ pw,
                                                     __hip_bfloat16* __restrict__ w3p,
                                                     const float* __restrict__ c1w,
                                                     __hip_bfloat16* __restrict__ wb,
                                                     const float* __restrict__ x,
                                                     __hip_bfloat16* __restrict__ xb,
                                                     const float* __restrict__ c2w,
                                                     unsigned char* __restrict__ wq2) {
    int bid = blockIdx.x;
    int t = threadIdx.x;
    if (bid == 512) {  // conv1 weight table
        float tmp[81];
#pragma unroll
        for (int k = 0; k < 81; ++k) tmp[k] = c1w[t * 81 + k];
#pragma unroll
        for (int ks = 0; ks < 9; ++ks)
#pragma unroll
            for (int e = 0; e < 8; ++e)
                wb[(ks * 256 + t) * 8 + e] = __float2bfloat16(tmp[ks * 9 + e]);
#pragma unroll
        for (int e = 0; e < 8; ++e)
            wb[(9 * 256 + t) * 8 + e] = __float2bfloat16(tmp[e * 9 + 8]);
        wb[(10 * 256 + t) * 8 + 0] = __float2bfloat16(tmp[80]);
#pragma unroll
        for (int e = 1; e < 8; ++e) wb[(10 * 256 + t) * 8 + e] = __float2bfloat16(0.f);
#pragma unroll
        for (int e = 0; e < 8; ++e) wb[(11 * 256 + t) * 8 + e] = __float2bfloat16(0.f);
        return;
    }
    if (bid >= 513 && bid < 905) {  // x -> bf16
        long i4 = (long)(bid - 513) * 1024 + t * 4;
        float4 v = *(const float4*)(x + i4);
        bf16x4 o = {(__bf16)v.x, (__bf16)v.y, (__bf16)v.z, (__bf16)v.w};
        *(bf16x4*)((__bf16*)xb + i4) = o;
        return;
    }
    if (bid >= 905) {  // conv2 fp8 table, coalesced via LDS
        __shared__ float wl[4 * 2592];  // [4 oc][32 ic][81 kyx]
        int b2 = bid - 905;
        int icg = b2 & 7;
        int oc4 = (b2 >> 3) & 31;
        int nblk = b2 >> 8;
        for (int f = t; f < 4 * 2592; f += 256) {
            int o = f / 2592;
            int rest = f - o * 2592;
            wl[f] = c2w[(long)(nblk * 128 + oc4 * 4 + o) * 20736 + icg * 2592 + rest];
        }
        __syncthreads();
        long base = (long)icg * 688128 + (long)nblk * 16384 + (oc4 * 4) * 128;
        for (int idx = t; idx < 4 * 21 * 128; idx += 256) {
            int o = idx / 2688;
            int rem = idx - o * 2688;
            int ks = rem >> 7, kb = rem & 127;
            int kq = kb >> 5, icl = kb & 31;
            int kyx = ks * 4 + kq;
            float v = (kyx < 81) ? wl[o * 2592 + icl * 81 + kyx] * 64.f : 0.f;
            wq2[base + (long)ks * 32768 + o * 128 + kb] = f2e4m3s(v);
        }
        return;
    }
    // conv3 weights -> bf16 [kyx][icg][nblk][oc128][ic32]
    __shared__ float wl3[4 * 32 * 81];
    int icg = bid & 7;
    int oc4 = (bid >> 3) & 31;
    int nblk = bid >> 8;
    int ocg0 = nblk * 128 + oc4 * 4;
    int ic0 = icg * 32;
    for (int f = t; f < 4 * 2592; f += 256) {
        int o = f / 2592;
        int rest = f - o * 2592;
        wl3[f] = pw[(ocg0 + o) * 20736 + ic0 * 81 + rest];
    }
    __syncthreads();
    for (int idx = t; idx < 81 * 128; idx += 256) {
        int kyx = idx >> 7;
        int o = (idx >> 5) & 3;
        int i = idx & 31;
        long dst = (long)(((kyx * 8 + icg) * 2 + nblk) * 128 + (oc4 * 4 + o)) * 32 + i;
        w3p[dst] = __float2bfloat16(wl3[o * 2592 + i * 81 + kyx]);
    }
}

// ---------------- conv1 as bf16 MFMA implicit-GEMM, writes fp8 (x16 pre-scale) ----------------
__global__ __launch_bounds__(256) void conv1_mfma_kernel(const __hip_bfloat16* __restrict__ xb,
                                                         const __hip_bfloat16* __restrict__ wb,
                                                         const float* __restrict__ bias,
                                                         unsigned char* __restrict__ out) {
    __shared__ __bf16 Asl[640];  // [10 rows][64 cols]
    int bid = blockIdx.x;
    int b = bid / 24, mb2 = bid - b * 24;
    int oy0 = mb2 * 2;
    int t = threadIdx.x;
    int lane = t & 63, wc = t >> 6;
    int q = lane >> 4;

    const __bf16* src = (const __bf16*)xb + b * 3136 + oy0 * 56;
    for (int idx = t; idx < 640; idx += 256) {
        int iy = idx >> 6, col = idx & 63;
        Asl[idx] = (col < 56) ? src[iy * 56 + col] : (__bf16)0.f;
    }

    bf16x8 Bf[3][4];
#pragma unroll
    for (int s = 0; s < 3; ++s)
#pragma unroll
        for (int ni = 0; ni < 4; ++ni) {
            int col = wc * 64 + ni * 16 + (lane & 15);
            Bf[s][ni] = *(const bf16x8*)(wb + ((s * 4 + q) * 256 + col) * 8);
        }

    f32x4 acc[6][4];
#pragma unroll
    for (int i = 0; i < 6; ++i)
#pragma unroll
        for (int j = 0; j < 4; ++j) acc[i][j] = (f32x4){0.f, 0.f, 0.f, 0.f};

    __syncthreads();

#pragma unroll
    for (int s = 0; s < 3; ++s) {
        int ks = s * 4 + q;
        bf16x8 af[6];
#pragma unroll
        for (int mi = 0; mi < 6; ++mi) {
            int r = mi * 16 + (lane & 15);
            int oyl = (r >= 48) ? 1 : 0;
            int ox = r - 48 * oyl;
            bf16x8 v;
            if (ks < 9) {
                __builtin_memcpy(&v, &Asl[(oyl + ks) * 64 + ox], 16);
            } else if (ks == 9) {
#pragma unroll
                for (int e = 0; e < 8; ++e) v[e] = Asl[(oyl + e) * 64 + ox + 8];
            } else if (ks == 10) {
#pragma unroll
                for (int e = 0; e < 8; ++e) v[e] = (__bf16)0.f;
                v[0] = Asl[(oyl + 8) * 64 + ox + 8];
            } else {
#pragma unroll
                for (int e = 0; e < 8; ++e) v[e] = (__bf16)0.f;
            }
            af[mi] = v;
        }
#pragma unroll
        for (int mi = 0; mi < 6; ++mi)
#pragma unroll
            for (int ni = 0; ni < 4; ++ni)
                acc[mi][ni] = __builtin_amdgcn_mfma_f32_16x16x32_bf16(af[mi], Bf[s][ni], acc[mi][ni], 0, 0, 0);
    }

    long m0 = (long)b * 2304 + mb2 * 96;
#pragma unroll
    for (int mi = 0; mi < 6; ++mi)
#pragma unroll
        for (int ni = 0; ni < 4; ++ni) {
            int col = wc * 64 + ni * 16 + (lane & 15);
            float bs = bias[col];
#pragma unroll
            for (int r2 = 0; r2 < 4; ++r2) {
                int row = mi * 16 + q * 4 + r2;
                float vv = acc[mi][ni][r2] + bs;
                vv = vv > 0.f ? vv : 0.f;
                out[(m0 + row) * 256 + col] = f2e4m3s(vv * 16.f);
            }
        }
}

// ---------------- conv2: MX-fp8 (K=128), parity-split LDS im2col [2 plane][48 iy][24 col][32 ch],
// depth-1 A-fragment register pipeline (1 exposed ds_read latency/step), barrier-free K-loop ----------------
__global__ __launch_bounds__(512, 2) void conv2_fp8_kernel(const unsigned char* __restrict__ in,
                                                           const unsigned char* __restrict__ wq,
                                                           const float* __restrict__ bias,
                                                           __hip_bfloat16* __restrict__ out) {
    __shared__ unsigned char Ald[73728];   // 2 planes x [48][24][32]
    int bid = blockIdx.x;
    int wg = (bid & 7) * 32 + (bid >> 3);  // XCD-chunk
    int b = wg >> 1, nblk = wg & 1;
    int t = threadIdx.x;
    int lane = t & 63, wid = t >> 6;
    int wr = wid >> 1, wc = wid & 1;       // 4 M x 2 N waves
    int kq = lane >> 4;

    const unsigned char* imgbase = in + (long)b * (48 * 48 * 256);
    const unsigned char* wqn = wq + ((long)(nblk * 128 + wc * 64 + (lane & 15))) * 128 + kq * 32;

    int qbase[7];  // within-plane byte offset of output pixel (iy=2*oy, col=ox)
#pragma unroll
    for (int mi = 0; mi < 7; ++mi) {
        int ml = wr * 96 + mi * 16 + (lane & 15);
        int oy = ml / 20, ox = ml - oy * 20;
        qbase[mi] = (2 * oy * 24 + ox) * 32;
    }

    f32x4 acc[7][4];
#pragma unroll
    for (int i = 0; i < 7; ++i)
#pragma unroll
        for (int j = 0; j < 4; ++j) acc[i][j] = (f32x4){0.f, 0.f, 0.f, 0.f};

    auto stageA = [&](int icg) {
#pragma unroll 3
        for (int j = 0; j < 9; ++j) {
            int gi = t + j * 512;                 // 16B-slot over [48][48][2]
            int p = gi >> 1, half = gi & 1;
            int iy = p / 48, ix = p - iy * 48;
            uint4 v = *(const uint4*)(imgbase + ((long)p * 256 + icg * 32 + half * 16));
            int plane = ix & 1, col = ix >> 1;
            *(uint4*)(Ald + plane * 36864 + (iy * 24 + col) * 32 + half * 16) = v;
        }
    };

    union U8 { uint4 q[2]; i32x8 v; };
    i32x8 Be[4], Bo[4];
    auto loadB = [&](i32x8* dst, int icg, int ks) {
        const unsigned char* p = wqn + (long)icg * 688128 + (long)ks * 32768;
        uint4* d = (uint4*)dst;
#pragma unroll
        for (int ni = 0; ni < 4; ++ni) {
            d[ni * 2]     = *(const uint4*)(p + ni * 2048);
            d[ni * 2 + 1] = *(const uint4*)(p + ni * 2048 + 16);
        }
    };

    auto step = [&](int icg, int ks, i32x8* Bcur, i32x8* Bnxt) {
        if (ks + 1 < 21) loadB(Bnxt, icg, ks + 1);
        int kyx = ks * 4 + kq;
        int ky = kyx / 9, kx = kyx - ky * 9;
        int sdel = ((kx & 1) ? 36864 : 0) + (ky * 24 + (kx >> 1)) * 32;
        U8 a0, a1;
        {   // prime mi=0
            const unsigned char* ap = Ald + qbase[0] + sdel;
            a0.q[0] = *(const uint4*)ap;
            a0.q[1] = *(const uint4*)(ap + 16);
        }
        __builtin_amdgcn_s_setprio(1);
#pragma unroll
        for (int mi = 0; mi < 7; ++mi) {
            if (mi < 6) {  // prefetch next fragment into the other buffer (static index under unroll)
                const unsigned char* ap = Ald + qbase[mi + 1] + sdel;
                if (mi & 1) {
                    a0.q[0] = *(const uint4*)ap;
                    a0.q[1] = *(const uint4*)(ap + 16);
                } else {
                    a1.q[0] = *(const uint4*)ap;
                    a1.q[1] = *(const uint4*)(ap + 16);
                }
            }
            const U8& cur = (mi & 1) ? a1 : a0;
#pragma unroll
            for (int ni = 0; ni < 4; ++ni)
                acc[mi][ni] = __builtin_amdgcn_mfma_scale_f32_16x16x128_f8f6f4(
                    cur.v, Bcur[ni], acc[mi][ni],
                    0, 0,                      // cbsz, blgp = fp8-e4m3
                    0, 0x7F7F7F7F,             // opsel_a, scale_a (127 -> 2^0)
                    0, 0x7F7F7F7F);            // opsel_b, scale_b
        }
        __builtin_amdgcn_s_setprio(0);
    };

    for (int icg = 0; icg < 8; ++icg) {
        if (icg) __builtin_amdgcn_s_barrier();   // all waves done reading old A
        loadB(Be, icg, 0);
        stageA(icg);
        asm volatile("s_waitcnt lgkmcnt(0)" ::: "memory");
        __builtin_amdgcn_s_barrier();
        if (wid >= 4) asm volatile("s_sleep 4");  // de-phase co-resident waves
        for (int kk = 0; kk < 10; ++kk) {
            step(icg, 2 * kk, Be, Bo);
            step(icg, 2 * kk + 1, Bo, Be);
        }
        step(icg, 20, Be, Bo);
    }

    int colbase = nblk * 128 + wc * 64 + (lane & 15);
    const float inv = 1.f / 1024.f;  // A x16, B x64
#pragma unroll
    for (int mi = 0; mi < 7; ++mi) {
#pragma unroll
        for (int ni = 0; ni < 4; ++ni) {
            int col = colbase + ni * 16;
            float bs = bias[col];
#pragma unroll
            for (int r = 0; r < 4; ++r) {
                int ml = wr * 96 + mi * 16 + (lane >> 4) * 4 + r;
                float v = acc[mi][ni][r] * inv + bs;
                v = v > 0.f ? v : 0.f;
                out[((long)b * 400 + ml) * 256 + col] = __float2bfloat16(v);
            }
        }
    }
}

// ---------------- conv3: implicit-GEMM 128x128 (split-K), ring-3, counted vmcnt, bf16 partials ----------------
__global__ __launch_bounds__(256) void conv_mfma_kernel(const __hip_bfloat16* __restrict__ in,
                                                        const __hip_bfloat16* __restrict__ wp,
                                                        const float* __restrict__ bias,
                                                        __hip_bfloat16* __restrict__ out,
                                                        __hip_bfloat16* __restrict__ part,
                                                        int Win, int imgStride, int HWout, int Wout,
                                                        int nkyx, int Mtot, int mode) {
    __shared__ __hip_bfloat16 Ald[3 * 4096];
    __shared__ __hip_bfloat16 Bld[3 * 4096];
    int mblk = blockIdx.x, nblk = blockIdx.y;
    int kyx0 = blockIdx.z * nkyx;
    int t = threadIdx.x;
    int lane = t & 63, wid = t >> 6;
    int swz = ((t & 3) ^ ((t >> 3) & 3)) * 8;
    int icsrc = swz;
    long bsrc = (t >> 2) * 32 + swz;

    long base0, base1;
    {
        int m = mblk * 128 + (t >> 2);
        int b = m / HWout; int rem = m - b * HWout;
        int oyy = rem / Wout; int oxx = rem - oyy * Wout;
        base0 = (long)b * imgStride + (long)(2 * oyy * Win + 2 * oxx) * 256;
        m += 64;
        b = m / HWout; rem = m - b * HWout;
        oyy = rem / Wout; oxx = rem - oyy * Wout;
        base1 = (long)b * imgStride + (long)(2 * oyy * Win + 2 * oxx) * 256;
    }

    f32x4 acc[4][4];
#pragma unroll
    for (int i = 0; i < 4; ++i)
#pragma unroll
        for (int j2 = 0; j2 < 4; ++j2) acc[i][j2] = (f32x4){0.f, 0.f, 0.f, 0.f};

    int wr = wid >> 1, wc = wid & 1;
    int slot8 = (((lane >> 4) ^ ((lane >> 1) & 3))) * 8;
    int a_off = ((wr * 64 + (lane & 15)) * 32 + slot8) * 2;
    int b_off = ((wc * 64 + (lane & 15)) * 32 + slot8) * 2;

    auto stage = [&](int s, int buf) {
        int kyx = kyx0 + (s >> 3);
        int icg = s & 7;
        int ky = kyx / 9, kx = kyx - ky * 9;
        long offA = (long)(ky * Win + kx) * 256 + icg * 32 + icsrc;
        long btb = (long)((kyx * 8 + icg) * 2 + nblk) * 4096 + bsrc;
        char* a0 = (char*)Ald + buf * 8192 + wid * 1024;
        char* b0 = (char*)Bld + buf * 8192 + wid * 1024;
        gload16(in + base0 + offA, a0);
        gload16(in + base1 + offA, a0 + 4096);
        gload16(wp + btb, b0);
        gload16(wp + btb + 2048, b0 + 4096);
    };

    int nsteps = nkyx * 8;
    stage(0, 0);
    stage(1, 1);
    stage(2, 2);
    int cur = 0;
    for (int s = 0; s < nsteps; ++s) {
        int rem = nsteps - 1 - s;
        if (rem >= 2) {
            asm volatile("s_waitcnt vmcnt(8)" ::: "memory");
        } else if (rem == 1) {
            asm volatile("s_waitcnt vmcnt(4)" ::: "memory");
        } else {
            asm volatile("s_waitcnt vmcnt(0)" ::: "memory");
        }
        __builtin_amdgcn_s_barrier();
        __builtin_amdgcn_sched_barrier(0);
        const char* Ac = (const char*)Ald + cur * 8192;
        const char* Bc = (const char*)Bld + cur * 8192;
        bf16x8 af[4], bfr[4];
#pragma unroll
        for (int i = 0; i < 4; ++i) af[i] = *(const bf16x8*)(Ac + a_off + i * 1024);
#pragma unroll
        for (int i = 0; i < 4; ++i) bfr[i] = *(const bf16x8*)(Bc + b_off + i * 1024);
#pragma unroll
        for (int mi = 0; mi < 4; ++mi)
#pragma unroll
            for (int ni = 0; ni < 4; ++ni)
                acc[mi][ni] = __builtin_amdgcn_mfma_f32_16x16x32_bf16(af[mi], bfr[ni], acc[mi][ni], 0, 0, 0);
        if (s + 3 < nsteps) {
            asm volatile("s_waitcnt lgkmcnt(0)" ::: "memory");
            __builtin_amdgcn_s_barrier();
            stage(s + 3, cur);
        }
        cur = (cur == 2) ? 0 : cur + 1;
    }

    int colbase = nblk * 128 + wc * 64 + (lane & 15);
    long mrowbase = (long)mblk * 128 + wr * 64 + (lane >> 4) * 4;
    if (mode == 0) {
#pragma unroll
        for (int mi = 0; mi < 4; ++mi) {
#pragma unroll
            for (int ni = 0; ni < 4; ++ni) {
                int col = colbase + ni * 16;
                float bs = bias[col];
#pragma unroll
                for (int r = 0; r < 4; ++r) {
                    long mrow = mrowbase + mi * 16 + r;
                    float v = acc[mi][ni][r] + bs;
                    v = v > 0.f ? v : 0.f;
                    out[mrow * 256 + col] = __float2bfloat16(v);
                }
            }
        }
    } else {
        __hip_bfloat16* pp = part + (long)blockIdx.z * Mtot * 256;
#pragma unroll
        for (int mi = 0; mi < 4; ++mi) {
#pragma unroll
            for (int ni = 0; ni < 4; ++ni) {
                int col = colbase + ni * 16;
#pragma unroll
                for (int r = 0; r < 4; ++r) {
                    long mrow = mrowbase + mi * 16 + r;
                    pp[mrow * 256 + col] = __float2bfloat16(acc[mi][ni][r]);
                }
            }
        }
    }
}

// ---------------- split-K reduce ----------------
__global__ __launch_bounds__(256) void reduce_parts_kernel(const __hip_bfloat16* __restrict__ part,
                                                           const float* __restrict__ bias,
                                                           __hip_bfloat16* __restrict__ out) {
    int idx = blockIdx.x * 256 + threadIdx.x;
    float s = 0.f;
#pragma unroll
    for (int p = 0; p < 9; ++p) s += __bfloat162float(part[(long)p * 1179648 + idx]);
    s += bias[idx & 255];
    s = s > 0.f ? s : 0.f;
    out[idx] = __float2bfloat16(s);
}

// ---------------- primary capsule squash ----------------
__global__ __launch_bounds__(256) void squash_caps_kernel(const __hip_bfloat16* __restrict__ c3,
                                                          float* __restrict__ uT) {
    int g = blockIdx.x * 256 + threadIdx.x;
    int i = g >> 7, b = g & 127;
    float val[8];
    float sn = 0.f;
#pragma unroll
    for (int d = 0; d < 8; ++d) {
        int flat = i * 8 + d;
        int c = flat / 36; int rem = flat - c * 36;
        int y = rem / 6; int xx = rem - y * 6;
        float vv = __bfloat162float(c3[((b * 6 + y) * 6 + xx) * 256 + c]);
        val[d] = vv;
        sn += vv * vv;
    }
    float sc = (sn / (1.f + sn)) / sqrtf(sn + 1e-8f);
#pragma unroll
    for (int d = 0; d < 8; ++d) uT[(long)g * 8 + d] = val[d] * sc;
}

// ---------------- u_hat ----------------
__global__ __launch_bounds__(256) void uhat_kernel(const float* __restrict__ uT,
                                                   const float* __restrict__ Wd,
                                                   __hip_bfloat16* __restrict__ uhat) {
    __shared__ float Wl2[1600];
    __shared__ float ul[1024];
    int i = blockIdx.x, t = threadIdx.x;
    for (int idx = t; idx < 1280; idx += 256) {
        int j = idx >> 7, rest = idx & 127;
        int d = rest >> 4, o = rest & 15;
        Wl2[(j * 16 + o) * 10 + d] = Wd[((long)j * 1152 + i) * 128 + rest];
    }
    {
        const float4* usrc = (const float4*)(uT + (long)i * 1024);
        float4* ud = (float4*)ul;
        ud[t] = usrc[t];
    }
    __syncthreads();
    int b = (t >= 160) ? 1 : 0;
    int jo = (t >= 160) ? t - 160 : t;
    for (int rr = 0; rr < 80; ++rr) {
        const float* up = &ul[b * 8];
        const float* wq = &Wl2[jo * 10];
        float a = 0.f;
#pragma unroll
        for (int d = 0; d < 8; ++d) a += up[d] * wq[d];
        int j = jo >> 4, o = jo & 15;
        uhat[(((long)b * 10 + j) * 1152 + i) * 16 + o] = __float2bfloat16(a);
        jo += 96; b += 1;
        if (jo >= 160) { jo -= 160; b += 1; }
    }
}

// ---------------- fused dynamic routing ----------------
__global__ __launch_bounds__(256) void routing_kernel(const __hip_bfloat16* __restrict__ uhat,
                                                      const float* __restrict__ bdig,
                                                      float* __restrict__ vout,
                                                      float* __restrict__ vws) {
    __shared__ __hip_bfloat16 uh[1152 * 16];
    __shared__ float barr[1152];
    __shared__ float red[16];
    __shared__ float accb[16 * 256];
    __shared__ float svec[16];
    __shared__ float vsc[16];
    int bid = blockIdx.x;
    int j = bid % 10;
    int t = threadIdx.x;
    int wid = t >> 6;
    const uint4* srcp = (const uint4*)(uhat + (long)bid * 18432);
    uint4* dstp = (uint4*)uh;
    for (int idx = t; idx < 2304; idx += 256) dstp[idx] = srcp[idx];
    for (int idx = t; idx < 1152; idx += 256) barr[idx] = 0.f;
    __syncthreads();
    for (int it = 0; it < 3; ++it) {
        float lm = -1e30f;
        for (int i = t; i < 1152; i += 256) lm = fmaxf(lm, barr[i]);
#pragma unroll
        for (int m2 = 32; m2; m2 >>= 1) lm = fmaxf(lm, __shfl_xor(lm, m2));
        if ((t & 63) == 0) red[wid] = lm;
        __syncthreads();
        float mx = fmaxf(fmaxf(red[0], red[1]), fmaxf(red[2], red[3]));
        float le = 0.f;
        float a16[16];
#pragma unroll
        for (int o = 0; o < 16; ++o) a16[o] = 0.f;
        for (int i = t; i < 1152; i += 256) {
            float e = __expf(barr[i] - mx);
            le += e;
            const uint4* up = (const uint4*)(uh + i * 16);
            union { uint4 q; unsigned short s[8]; } U0, U1;
            U0.q = up[0]; U1.q = up[1];
#pragma unroll
            for (int o = 0; o < 8; ++o) a16[o] += e * bfu(U0.s[o]);
#pragma unroll
            for (int o = 0; o < 8; ++o) a16[8 + o] += e * bfu(U1.s[o]);
        }
#pragma unroll
        for (int m2 = 32; m2; m2 >>= 1) le += __shfl_xor(le, m2);
        if ((t & 63) == 0) red[4 + wid] = le;
#pragma unroll
        for (int o = 0; o < 16; ++o) accb[o * 256 + t] = a16[o];
        __syncthreads();
        float sume = red[4] + red[5] + red[6] + red[7];
        int g = t >> 4, tin = t & 15;
        float s = 0.f;
#pragma unroll
        for (int k = 0; k < 16; ++k) s += accb[g * 256 + tin + 16 * k];
#pragma unroll
        for (int m2 = 8; m2; m2 >>= 1) s += __shfl_xor(s, m2);
        if (tin == 0) svec[g] = s / sume + bdig[j * 16 + g];
        __syncthreads();
        if (t < 16) {
            float sv = svec[t];
            float sn = sv * sv;
#pragma unroll
            for (int m2 = 8; m2; m2 >>= 1) sn += __shfl_xor(sn, m2);
            float sc = (sn / (1.f + sn)) / sqrtf(sn + 1e-8f);
            float v = sv * sc;
            vsc[t] = v;
            if (it == 2) { vout[bid * 16 + t] = v; vws[bid * 16 + t] = v; }
        }
        __syncthreads();
        if (it < 2) {
            for (int i = t; i < 1152; i += 256) {
                const uint4* up = (const uint4*)(uh + i * 16);
                union { uint4 q; unsigned short s[8]; } U0, U1;
                U0.q = up[0]; U1.q = up[1];
                float dot = 0.f;
#pragma unroll
                for (int o = 0; o < 8; ++o) dot += vsc[o] * bfu(U0.s[o]);
#pragma unroll
                for (int o = 0; o < 8; ++o) dot += vsc[8 + o] * bfu(U1.s[o]);
                barr[i] += dot;
            }
            __syncthreads();
        }
    }
}

// ---------------- reconstruction GEMM, latency-proof ----------------
__global__ __launch_bounds__(256) void rec_gemm_kernel(const float* __restrict__ A,
                                                       const float* __restrict__ W,
                                                       const float* __restrict__ bias,
                                                       float* __restrict__ out,
                                                       int K, int N, int act) {
    __shared__ __align__(16) float As[2][2048];
    int n0 = blockIdx.x * 64;
    int bch = blockIdx.y * 32;
    int t = threadIdx.x;
    int n_l = t & 63, bh = t >> 6;
    const float* Wc = W + n0 + n_l;
    float acc[8];
#pragma unroll
    for (int i = 0; i < 8; ++i) acc[i] = 0.f;
    int T = (K + 63) >> 6;

    auto stageA = [&](int tile, int buf) {
        int k0 = tile << 6;
        for (int idx = t; idx < 2048; idx += 256) {
            int bb = idx >> 6, kk = idx & 63;
            As[buf][idx] = (k0 + kk < K) ? A[(long)(bch + bb) * K + k0 + kk] : 0.f;
        }
    };
    auto ldW = [&](int tile, float* w) {
        int k0 = tile << 6;
#pragma unroll
        for (int j = 0; j < 64; ++j) {
            int kr = k0 + j;
            if (kr >= K) kr = K - 1;
            w[j] = Wc[(long)kr * N];
        }
    };
    auto compute = [&](const float* w, int buf) {
#pragma unroll
        for (int bb = 0; bb < 8; ++bb) {
            const float4* ap = (const float4*)&As[buf][(bh * 8 + bb) * 64];
            float s = 0.f;
#pragma unroll
            for (int q = 0; q < 16; ++q) {
                float4 a = ap[q];
                s += a.x * w[q * 4] + a.y * w[q * 4 + 1] + a.z * w[q * 4 + 2] + a.w * w[q * 4 + 3];
            }
            acc[bb] += s;
        }
    };

    float wA[64], wB[64];
    ldW(0, wA);
    stageA(0, 0);
    __syncthreads();
    for (int tile = 0; tile < T; tile += 2) {
        if (tile + 1 < T) { ldW(tile + 1, wB); stageA(tile + 1, 1); }
        compute(wA, 0);
        __syncthreads();
        if (tile + 1 < T) {
            if (tile + 2 < T) { ldW(tile + 2, wA); stageA(tile + 2, 0); }
            compute(wB, 1);
            __syncthreads();
        }
    }

    float bs = bias[n0 + n_l];
#pragma unroll
    for (int bb = 0; bb < 8; ++bb) {
        float x = acc[bb] + bs;
        float r;
        if (act == 0) r = x > 0.f ? x : 0.f;
        else r = 1.f / (1.f + __expf(-x));
        out[(long)(bch + bh * 8 + bb) * N + n0 + n_l] = r;
    }
}

extern "C" void kernel_launch(void* const* d_in, const int* in_sizes, int n_in,
                              void* d_out, int out_size, void* d_ws, size_t ws_size,
                              hipStream_t stream) {
    const float* x   = (const float*)d_in[0];
    const float* c1w = (const float*)d_in[1];
    const float* c1b = (const float*)d_in[2];
    const float* c2w = (const float*)d_in[3];
    const float* c2b = (const float*)d_in[4];
    const float* pw  = (const float*)d_in[5];
    const float* pb  = (const float*)d_in[6];
    const float* Wd  = (const float*)d_in[7];
    const float* bd  = (const float*)d_in[8];
    const float* rw1 = (const float*)d_in[9];
    const float* rb1 = (const float*)d_in[10];
    const float* rw2 = (const float*)d_in[11];
    const float* rb2 = (const float*)d_in[12];
    const float* rw3 = (const float*)d_in[13];
    const float* rb3 = (const float*)d_in[14];
    float* outp = (float*)d_out;

    char* ws = (char*)d_ws;
    size_t off = 0;
    auto alloc = [&](size_t bytes) {
        char* p = ws + off;
        off += (bytes + 255) & ~(size_t)255;
        return p;
    };
    unsigned char* c1f8  = (unsigned char*)alloc(75497472UL);   // [128][48][48][256] fp8 (x16)
    __hip_bfloat16* c2out = (__hip_bfloat16*)alloc(26214400UL); // [128][20][20][256] bf16
    __hip_bfloat16* c3out = (__hip_bfloat16*)alloc(2359296UL);
    __hip_bfloat16* w3p   = (__hip_bfloat16*)alloc(10616832UL);
    unsigned char* wq2    = (unsigned char*)alloc(5505024UL);   // [8][21][2][128][128] fp8 (x64)
    __hip_bfloat16* xb    = (__hip_bfloat16*)alloc(802816UL);
    __hip_bfloat16* wb    = (__hip_bfloat16*)alloc(49152UL);
    float* uT    = (float*)alloc(4718592UL);
    __hip_bfloat16* uhat = (__hip_bfloat16*)alloc(47185920UL);
    float* vws   = (float*)alloc(81920UL);
    float* rec1  = (float*)alloc(262144UL);
    float* rec2  = (float*)alloc(524288UL);

    __hip_bfloat16* c3part = (__hip_bfloat16*)uhat;

    prep_w_kernel<<<1417, 256, 0, stream>>>(pw, w3p, c1w, wb, x, xb, c2w, wq2);
    conv1_mfma_kernel<<<3072, 256, 0, stream>>>(xb, wb, c1b, c1f8);
    conv2_fp8_kernel<<<256, 512, 0, stream>>>(c1f8, wq2, c2b, c2out);
    conv_mfma_kernel<<<dim3(36, 2, 9), 256, 0, stream>>>(c2out, w3p, pb, c3out, c3part,
                                                         20, 20 * 20 * 256, 36, 6, 9, 4608, 1);
    reduce_parts_kernel<<<4608, 256, 0, stream>>>(c3part, pb, c3out);
    squash_caps_kernel<<<576, 256, 0, stream>>>(c3out, uT);
    uhat_kernel<<<1152, 256, 0, stream>>>(uT, Wd, uhat);
    routing_kernel<<<1280, 256, 0, stream>>>(uhat, bd, outp, vws);
    rec_gemm_kernel<<<dim3(8, 4), 256, 0, stream>>>(vws, rw1, rb1, rec1, 160, 512, 0);
    rec_gemm_kernel<<<dim3(16, 4), 256, 0, stream>>>(rec1, rw2, rb2, rec2, 512, 1024, 0);
    rec_gemm_kernel<<<dim3(49, 4), 256, 0, stream>>>(rec2, rw3, rb3, outp + 20480, 1024, 3136, 1);
}